// Round 1
// 987.147 us; speedup vs baseline: 1.2257x; 1.2257x over previous
//
#include <hip/hip_runtime.h>

typedef unsigned short u16;
typedef short short8 __attribute__((ext_vector_type(8)));
typedef u16 u16x4 __attribute__((ext_vector_type(4)));
typedef float float4v __attribute__((ext_vector_type(4)));

#define NEG_SLOPE 0.2f

static __device__ __forceinline__ float b2f(u16 u) {
    union { unsigned int i; float f; } x; x.i = ((unsigned int)u) << 16; return x.f;
}
static __device__ __forceinline__ u16 f2b(float f) {
    unsigned int u = __float_as_uint(f);
    unsigned int r = (u + 0x7fffu + ((u >> 16) & 1u)) >> 16;
    return (u16)r;
}

// ---------------------------------------------------------------------------
// diagnostics: code 32 = CSR inconsistent; 1000+ = ws too small
// ---------------------------------------------------------------------------
__global__ void k_diag(float* out, int n, float val)
{
    int i = blockIdx.x * 256 + threadIdx.x;
    if (i < n) out[i] = val;
}

__global__ void scan_csr(const int* off, const int* srcs, int N, int E,
                         int* flag, int bit)
{
    int i = blockIdx.x * 256 + threadIdx.x;
    if (i < N) {
        int a = off[i], b = off[i + 1];
        if (a < 0 || b < a || b > E) atomicOr(flag, bit);
    }
    if (i == 0 && off[N] != E) atomicOr(flag, bit);
    if (i < E) {
        if ((unsigned)srcs[i] >= (unsigned)N) atomicOr(flag, bit);
    }
}

__global__ void k_final_diag(const int* flag, float* out, int n)
{
    int f = *flag;
    if (f == 0) return;
    int b = __ffs(f) - 1;
    float val = 32.0f * (b + 1);
    int i = blockIdx.x * 256 + threadIdx.x;
    if (i < n) out[i] = val;
}

// ---------------------------------------------------------------------------
// edge_index dtype probe + canonical int32 extraction
// ---------------------------------------------------------------------------
__global__ void k_detect(const int* ei, int E, int* flag64)
{
    __shared__ int zc;
    if (threadIdx.x == 0) zc = 0;
    __syncthreads();
    int idx = 1 + 2 * (int)threadIdx.x;
    int z = (idx < 2 * E && ei[idx] == 0) ? 1 : 0;
    atomicAdd(&zc, z);
    __syncthreads();
    if (threadIdx.x == 0) *flag64 = (zc >= 200) ? 1 : 0;
}

__global__ void k_extract(const int* ei, int E, const int* flag64,
                          int* src, int* dst)
{
    int e = blockIdx.x * 256 + threadIdx.x;
    if (e >= E) return;
    if (*flag64) {
        src[e] = ei[2 * e];
        dst[e] = ei[2 * E + 2 * e];
    } else {
        src[e] = ei[e];
        dst[e] = ei[E + e];
    }
}

// ---------------------------------------------------------------------------
// CSR construction (bound-checked)
// ---------------------------------------------------------------------------
__global__ void k_count(const int* dst, int* deg, int E, int N)
{
    int e = blockIdx.x * 256 + threadIdx.x;
    if (e < E) {
        int d = dst[e];
        if ((unsigned)d < (unsigned)N) atomicAdd(&deg[d], 1);
    }
}

__global__ __launch_bounds__(1024)
void k_scan(const int* deg, int* off, int* cursor, int N, int E)
{
    __shared__ int sd[1024];
    __shared__ int running;
    int tid = threadIdx.x;
    if (tid == 0) running = 0;
    __syncthreads();
    for (int base = 0; base < N; base += 1024) {
        int i = base + tid;
        int v = (i < N) ? deg[i] : 0;
        sd[tid] = v;
        __syncthreads();
        for (int s = 1; s < 1024; s <<= 1) {
            int t = (tid >= s) ? sd[tid - s] : 0;
            __syncthreads();
            sd[tid] += t;
            __syncthreads();
        }
        int excl = sd[tid] - v + running;
        if (i < N) { off[i] = excl; cursor[i] = excl; }
        int total = sd[1023];
        __syncthreads();
        if (tid == 0) running += total;
        __syncthreads();
    }
    if (tid == 0) off[N] = E;
}

__global__ void k_scatter(const int* src, const int* dst, int* cursor,
                          int* srcs, int E, int N)
{
    int e = blockIdx.x * 256 + threadIdx.x;
    if (e < E) {
        int d = dst[e];
        if ((unsigned)d < (unsigned)N) {
            int p = atomicAdd(&cursor[d], 1);
            if ((unsigned)p < (unsigned)E) srcs[p] = src[e];
        }
    }
}

// ---------------------------------------------------------------------------
// fp32 -> bf16 bulk cast (8 elems/thread)
// ---------------------------------------------------------------------------
__global__ __launch_bounds__(256)
void k_f2b8(const float* __restrict__ in, u16* __restrict__ out, int n8)
{
    int i = blockIdx.x * 256 + threadIdx.x;
    if (i >= n8) return;
    const float4* p = (const float4*)in + (size_t)i * 2;
    float4 v0 = p[0], v1 = p[1];
    int4 w;
    w.x = (int)f2b(v0.x) | ((int)f2b(v0.y) << 16);
    w.y = (int)f2b(v0.z) | ((int)f2b(v0.w) << 16);
    w.z = (int)f2b(v1.x) | ((int)f2b(v1.y) << 16);
    w.w = (int)f2b(v1.z) | ((int)f2b(v1.w) << 16);
    *(int4*)(out + (size_t)i * 8) = w;
}

// ---------------------------------------------------------------------------
// fp32 row-dot against two fp32 vectors — one wave per row, float4 lanes
// ---------------------------------------------------------------------------
__global__ __launch_bounds__(256)
void k_rowdot2f(const float* __restrict__ A, int ld, int H,
                const float* __restrict__ vs, const float* __restrict__ vd,
                float* a_s, float* a_d, int N)
{
    int wave = threadIdx.x >> 6, lane = threadIdx.x & 63;
    int n = blockIdx.x * 4 + wave;
    if (n >= N) return;
    const float* ar = A + (size_t)n * ld;
    float ss = 0.f, sd = 0.f;
    for (int i = lane * 4; i < H; i += 256) {
        float4 v  = *(const float4*)(ar + i);
        float4 s4 = *(const float4*)(vs + i);
        float4 d4 = *(const float4*)(vd + i);
        ss += v.x * s4.x + v.y * s4.y + v.z * s4.z + v.w * s4.w;
        sd += v.x * d4.x + v.y * d4.y + v.z * d4.z + v.w * d4.w;
    }
    #pragma unroll
    for (int m = 32; m; m >>= 1) {
        ss += __shfl_xor(ss, m, 64);
        sd += __shfl_xor(sd, m, 64);
    }
    if (lane == 0) { a_s[n] = ss; a_d[n] = sd; }
}

// ---------------------------------------------------------------------------
// bf16 row-dot (for layer-2 h2) — one wave per node
// ---------------------------------------------------------------------------
__global__ __launch_bounds__(256)
void k_rowdot2(const u16* h, int ld, int H, const float* vs, const float* vd,
               float* a_s, float* a_d, int N)
{
    int wave = threadIdx.x >> 6, lane = threadIdx.x & 63;
    int n = blockIdx.x * 4 + wave;
    if (n >= N) return;
    const u16* hr = h + (size_t)n * ld;
    float ss = 0.f, sd = 0.f;
    for (int i = lane; i < H; i += 64) {
        float v = b2f(hr[i]);
        ss += v * vs[i];
        sd += v * vd[i];
    }
    #pragma unroll
    for (int m = 32; m; m >>= 1) {
        ss += __shfl_xor(ss, m, 64);
        sd += __shfl_xor(sd, m, 64);
    }
    if (lane == 0) { a_s[n] = ss; a_d[n] = sd; }
}

// ---------------------------------------------------------------------------
// per-dst softmax stats + normalized per-edge alpha (3-pass, wave per node)
// ---------------------------------------------------------------------------
__global__ __launch_bounds__(256)
void k_alpha(const int* __restrict__ off, const int* __restrict__ srcs,
             const float* __restrict__ a_s, const float* __restrict__ a_d,
             float* __restrict__ alpha, int N)
{
    int wave = threadIdx.x >> 6, lane = threadIdx.x & 63;
    int n = blockIdx.x * 4 + wave;
    if (n >= N) return;
    int base = off[n], end = off[n + 1];
    float adn = a_d[n];
    float m = -1e30f;
    for (int p = base + lane; p < end; p += 64) {
        int s = srcs[p];
        s = ((unsigned)s < (unsigned)N) ? s : 0;
        float z = a_s[s] + adn;
        z = z > 0.f ? z : NEG_SLOPE * z;
        m = fmaxf(m, z);
    }
    #pragma unroll
    for (int s = 32; s; s >>= 1) m = fmaxf(m, __shfl_xor(m, s, 64));
    float sum = 0.f;
    for (int p = base + lane; p < end; p += 64) {
        int s = srcs[p];
        s = ((unsigned)s < (unsigned)N) ? s : 0;
        float z = a_s[s] + adn;
        z = z > 0.f ? z : NEG_SLOPE * z;
        sum += __expf(z - m);
    }
    #pragma unroll
    for (int s = 32; s; s >>= 1) sum += __shfl_xor(sum, s, 64);
    float inv = 1.f / (sum + 1e-16f);
    for (int p = base + lane; p < end; p += 64) {
        int s = srcs[p];
        s = ((unsigned)s < (unsigned)N) ? s : 0;
        float z = a_s[s] + adn;
        z = z > 0.f ? z : NEG_SLOPE * z;
        alpha[p] = __expf(z - m) * inv;
    }
}

// ---------------------------------------------------------------------------
// weighted gather-aggregate over 256-ch bf16 rows: one wave per node,
// 8B/lane gathers, precomputed normalized alpha, optional bf16 addend.
// out[n] = sum_e alpha[e] * rows[srcs[e]]  (+ add[n])
// ---------------------------------------------------------------------------
__global__ __launch_bounds__(256)
void k_aggw(const u16* __restrict__ rows, const int* __restrict__ off,
            const int* __restrict__ srcs, const float* __restrict__ alpha,
            const u16* __restrict__ add, u16* __restrict__ out, int N)
{
    int wave = threadIdx.x >> 6, lane = threadIdx.x & 63;
    int n = blockIdx.x * 4 + wave;
    if (n >= N) return;
    int base = off[n], end = off[n + 1];
    int c4 = lane * 4;
    float a0 = 0.f, a1 = 0.f, a2 = 0.f, a3 = 0.f;
    int p = base;
    for (; p + 1 < end; p += 2) {
        int s0 = srcs[p];     s0 = ((unsigned)s0 < (unsigned)N) ? s0 : 0;
        int s1 = srcs[p + 1]; s1 = ((unsigned)s1 < (unsigned)N) ? s1 : 0;
        float w0 = alpha[p], w1 = alpha[p + 1];
        u16x4 v0 = *(const u16x4*)(rows + (size_t)s0 * 256 + c4);
        u16x4 v1 = *(const u16x4*)(rows + (size_t)s1 * 256 + c4);
        a0 += w0 * b2f(v0[0]) + w1 * b2f(v1[0]);
        a1 += w0 * b2f(v0[1]) + w1 * b2f(v1[1]);
        a2 += w0 * b2f(v0[2]) + w1 * b2f(v1[2]);
        a3 += w0 * b2f(v0[3]) + w1 * b2f(v1[3]);
    }
    if (p < end) {
        int s0 = srcs[p]; s0 = ((unsigned)s0 < (unsigned)N) ? s0 : 0;
        float w0 = alpha[p];
        u16x4 v0 = *(const u16x4*)(rows + (size_t)s0 * 256 + c4);
        a0 += w0 * b2f(v0[0]);
        a1 += w0 * b2f(v0[1]);
        a2 += w0 * b2f(v0[2]);
        a3 += w0 * b2f(v0[3]);
    }
    size_t ob = (size_t)n * 256 + c4;
    if (add) {
        a0 += b2f(add[ob]);     a1 += b2f(add[ob + 1]);
        a2 += b2f(add[ob + 2]); a3 += b2f(add[ob + 3]);
    }
    u16x4 o;
    o[0] = f2b(a0); o[1] = f2b(a1); o[2] = f2b(a2); o[3] = f2b(a3);
    *(u16x4*)(out + ob) = o;
}

// ---------------------------------------------------------------------------
// MFMA GEMM, 64x64 tile, BK=32. A: fp32 (AF32) or bf16; B: fp32 weights.
// Both converted to bf16 during LDS staging. C bf16 [M,NC] (+fp32 biases,
// optional bf16 addend matrix Cadd — safe with Cadd==C, optional relu).
// ---------------------------------------------------------------------------
template<bool AF32>
__global__ __launch_bounds__(256)
void gemm64(const void* Ap, const float* B, const float* bias1, const float* bias2,
            const u16* Cadd, u16* C, int M, int K, int NC, int relu)
{
    __shared__ u16 As[64][40];
    __shared__ u16 Bs[64][40];   // transposed: Bs[n][k]

    const int tid  = threadIdx.x;
    const int wave = tid >> 6;
    const int lane = tid & 63;
    const int rowBase = blockIdx.x * 64;
    const int colBase = blockIdx.y * 64;

    float4v acc[4] = {};
    const int ar = tid >> 2;          // 0..63
    const int ac = (tid & 3) * 8;     // 0,8,16,24
    const int bk = tid >> 3;          // 0..31
    const int bn = (tid & 7) * 8;     // 0..56
    const int m16 = lane & 15;
    const int q = lane >> 4;

    for (int k0 = 0; k0 < K; k0 += 32) {
        __syncthreads();
        {   // stage A 64x32
            int grow = rowBase + ar;
            if (AF32) {
                const float* Af = (const float*)Ap;
                float4 v0 = {0,0,0,0}, v1 = {0,0,0,0};
                if (grow < M) {
                    const float* p = Af + (size_t)grow * K + k0 + ac;
                    v0 = *(const float4*)p;
                    v1 = *(const float4*)(p + 4);
                }
                u16* d = &As[ar][ac];
                d[0]=f2b(v0.x); d[1]=f2b(v0.y); d[2]=f2b(v0.z); d[3]=f2b(v0.w);
                d[4]=f2b(v1.x); d[5]=f2b(v1.y); d[6]=f2b(v1.z); d[7]=f2b(v1.w);
            } else {
                const u16* Ab = (const u16*)Ap;
                int4 v = {0, 0, 0, 0};
                if (grow < M) v = *(const int4*)(Ab + (size_t)grow * K + k0 + ac);
                *(int4*)&As[ar][ac] = v;
            }
        }
        {   // stage B 32x64 fp32 -> bf16, transposed
            const float* bp = B + (size_t)(k0 + bk) * NC + colBase + bn;
            float4 w0 = *(const float4*)bp;
            float4 w1 = *(const float4*)(bp + 4);
            u16 t[8] = {f2b(w0.x), f2b(w0.y), f2b(w0.z), f2b(w0.w),
                        f2b(w1.x), f2b(w1.y), f2b(w1.z), f2b(w1.w)};
            #pragma unroll
            for (int j = 0; j < 8; ++j) Bs[bn + j][bk] = t[j];
        }
        __syncthreads();

        short8 aF = *(const short8*)&As[wave * 16 + m16][q * 8];
        #pragma unroll
        for (int c = 0; c < 4; ++c) {
            short8 bF = *(const short8*)&Bs[c * 16 + m16][q * 8];
            acc[c] = __builtin_amdgcn_mfma_f32_16x16x32_bf16(aF, bF, acc[c], 0, 0, 0);
        }
    }

    #pragma unroll
    for (int c = 0; c < 4; ++c) {
        int gcol = colBase + c * 16 + m16;
        float bv = (bias1 ? bias1[gcol] : 0.f) + (bias2 ? bias2[gcol] : 0.f);
        #pragma unroll
        for (int i = 0; i < 4; ++i) {
            int grow = rowBase + wave * 16 + q * 4 + i;
            if (grow < M) {
                float v = acc[c][i] + bv;
                if (Cadd) v += b2f(Cadd[(size_t)grow * NC + gcol]);
                if (relu) v = fmaxf(v, 0.f);
                C[(size_t)grow * NC + gcol] = f2b(v);
            }
        }
    }
}

// ---------------------------------------------------------------------------
// MFMA full-row-width GEMM (BM=64, K=NC=256), in-place safe (C==A):
// one block owns 64 rows entirely; A bf16, B fp32 (staged->bf16), bias fp32.
// ---------------------------------------------------------------------------
__global__ __launch_bounds__(256)
void rowfull256(const u16* A, const float* B, const float* bias,
                u16* C, int M, int relu)
{
    __shared__ u16 As[64][40];
    __shared__ u16 Bs[256][40];

    const int tid  = threadIdx.x;
    const int wave = tid >> 6;
    const int lane = tid & 63;
    const int rowBase = blockIdx.x * 64;
    const int m16 = lane & 15;
    const int q = lane >> 4;

    float4v acc[16] = {};
    const int ar = tid >> 2, ac = (tid & 3) * 8;
    const int bk = tid >> 3, bn0 = (tid & 7) * 8;

    for (int k0 = 0; k0 < 256; k0 += 32) {
        __syncthreads();
        {
            int grow = rowBase + ar;
            int4 v = {0, 0, 0, 0};
            if (grow < M) v = *(const int4*)(A + (size_t)grow * 256 + k0 + ac);
            *(int4*)&As[ar][ac] = v;
        }
        #pragma unroll
        for (int j8 = 0; j8 < 4; ++j8) {
            int bn = bn0 + j8 * 64;
            const float* bp = B + (size_t)(k0 + bk) * 256 + bn;
            float4 w0 = *(const float4*)bp;
            float4 w1 = *(const float4*)(bp + 4);
            u16 t[8] = {f2b(w0.x), f2b(w0.y), f2b(w0.z), f2b(w0.w),
                        f2b(w1.x), f2b(w1.y), f2b(w1.z), f2b(w1.w)};
            #pragma unroll
            for (int j = 0; j < 8; ++j) Bs[bn + j][bk] = t[j];
        }
        __syncthreads();

        short8 aF = *(const short8*)&As[wave * 16 + m16][q * 8];
        #pragma unroll
        for (int c = 0; c < 16; ++c) {
            short8 bF = *(const short8*)&Bs[c * 16 + m16][q * 8];
            acc[c] = __builtin_amdgcn_mfma_f32_16x16x32_bf16(aF, bF, acc[c], 0, 0, 0);
        }
    }

    #pragma unroll
    for (int c = 0; c < 16; ++c) {
        int col = c * 16 + m16;
        float bv = bias ? bias[col] : 0.f;
        #pragma unroll
        for (int i = 0; i < 4; ++i) {
            int grow = rowBase + wave * 16 + q * 4 + i;
            if (grow < M) {
                float v = acc[c][i] + bv;
                if (relu) v = fmaxf(v, 0.f);
                C[(size_t)grow * 256 + col] = f2b(v);
            }
        }
    }
}

// ---------------------------------------------------------------------------
// classifier + softmax: one wave per node, 256 -> 5, fp32 output
// ---------------------------------------------------------------------------
__global__ __launch_bounds__(64)
void k_fc_softmax(const u16* hin, const float* fcw, const float* fcb,
                  float* out, int N)
{
    int n = blockIdx.x;
    int lane = threadIdx.x;
    const u16* hr = hin + (size_t)n * 256;
    int k0 = lane * 4;
    float hv[4];
    float p[5] = {0.f, 0.f, 0.f, 0.f, 0.f};
    #pragma unroll
    for (int j = 0; j < 4; ++j) hv[j] = b2f(hr[k0 + j]);
    #pragma unroll
    for (int j = 0; j < 4; ++j) {
        const float* wr = fcw + (size_t)(k0 + j) * 5;
        #pragma unroll
        for (int c = 0; c < 5; ++c) p[c] += hv[j] * wr[c];
    }
    #pragma unroll
    for (int c = 0; c < 5; ++c) {
        #pragma unroll
        for (int s = 32; s; s >>= 1) p[c] += __shfl_xor(p[c], s, 64);
    }
    if (lane == 0) {
        float m = -1e30f;
        #pragma unroll
        for (int c = 0; c < 5; ++c) { p[c] += fcb[c]; m = fmaxf(m, p[c]); }
        float s = 0.f, e[5];
        #pragma unroll
        for (int c = 0; c < 5; ++c) { e[c] = __expf(p[c] - m); s += e[c]; }
        float inv = 1.f / s;
        #pragma unroll
        for (int c = 0; c < 5; ++c) out[(size_t)n * 5 + c] = e[c] * inv;
    }
}

// ---------------------------------------------------------------------------
extern "C" void kernel_launch(void* const* d_in, const int* in_sizes, int n_in,
                              void* d_out, int out_size, void* d_ws, size_t ws_size,
                              hipStream_t stream)
{
    const float* x    = (const float*)d_in[0];
    const int*   ei   = (const int*)  d_in[1];
    const float* W1   = (const float*)d_in[2];
    const float* as1  = (const float*)d_in[3];
    const float* ad1  = (const float*)d_in[4];
    const float* bc1  = (const float*)d_in[5];
    const float* A1w  = (const float*)d_in[6];
    const float* b1   = (const float*)d_in[7];
    const float* W2   = (const float*)d_in[8];
    const float* as2  = (const float*)d_in[9];
    const float* ad2  = (const float*)d_in[10];
    const float* bc2  = (const float*)d_in[11];
    const float* A2w  = (const float*)d_in[12];
    const float* b2   = (const float*)d_in[13];
    const float* Hw1  = (const float*)d_in[14];
    const float* Hb1  = (const float*)d_in[15];
    const float* Hw2  = (const float*)d_in[16];
    const float* Hb2  = (const float*)d_in[17];
    const float* Hw3  = (const float*)d_in[18];
    const float* Hb3  = (const float*)d_in[19];
    const float* fcw  = (const float*)d_in[20];
    const float* fcb  = (const float*)d_in[21];
    float* out = (float*)d_out;

    const int D = 256;
    const int N = in_sizes[0] / D;
    const int E = in_sizes[1] / 2;

    char* w = (char*)d_ws;
    auto alloc = [&](size_t bytes) {
        char* p = w;
        w += (bytes + 255) & ~(size_t)255;
        return p;
    };
    int*   flag   = (int*)  alloc(256);
    int*   flag64 = (int*)  alloc(256);
    float* a_s    = (float*)alloc((size_t)N * 4);
    float* a_d    = (float*)alloc((size_t)N * 4);
    float* vs1    = (float*)alloc(1024);                 // W1 @ att_src1  [256]
    float* vd1    = (float*)alloc(1024);                 // W1 @ att_dst1  [256]
    int*   deg    = (int*)  alloc((size_t)N * 4);
    int*   cursor = (int*)  alloc((size_t)N * 4);
    int*   offA   = (int*)  alloc((size_t)(N + 1) * 4);
    int*   srcs   = (int*)  alloc((size_t)E * 4);
    float* alpha  = (float*)alloc((size_t)E * 4);        // normalized edge weights
    u16*   BUF1   = (u16*)  alloc((size_t)N * 512 * 2);  // xb|aggx -> h2|res2
    u16*   BUF2   = (u16*)  alloc((size_t)N * 512 * 2);  // pre/hl1 -> out2/MLP

    // src32/dst32 alias BUF1 (dead before xb is written)
    int* src32 = (int*)BUF1;
    int* dst32 = src32 + E;

    size_t need = (size_t)(w - (char*)d_ws);             // ~110 MB
    if (ws_size < need) {
        float code = 1000.0f + (float)(ws_size >> 20);
        k_diag<<<(out_size + 255) / 256, 256, 0, stream>>>(out, out_size, code);
        return;
    }

    const int EB  = (E + 255) / 256;
    const int NB4 = (N + 3) / 4;
    const int OB  = (out_size + 255) / 256;
    const int NE  = (N > E ? N : E);
    const int RB64 = (N + 63) / 64;
    const size_t NH2 = (size_t)N * 256;
    u16* XB   = BUF1;            // bf16 cast of x      [N,256]
    u16* AGGX = BUF1 + NH2;      // alpha-aggregated x  [N,256]

    hipMemsetAsync(flag, 0, 4, stream);

    // ---- edge extraction + CSR by destination ----
    k_detect <<<1, 256, 0, stream>>>(ei, E, flag64);
    k_extract<<<EB, 256, 0, stream>>>(ei, E, flag64, src32, dst32);
    hipMemsetAsync(deg, 0, (size_t)N * 4, stream);
    k_count  <<<EB, 256, 0, stream>>>(dst32, deg, E, N);
    k_scan   <<<1, 1024, 0, stream>>>(deg, offA, cursor, N, E);
    k_scatter<<<EB, 256, 0, stream>>>(src32, dst32, cursor, srcs, E, N);
    scan_csr <<<(NE + 255) / 256, 256, 0, stream>>>(offA, srcs, N, E, flag, 1);

    // ---- xb = bf16(x) (overwrites src32/dst32 region, already dead) ----
    k_f2b8<<<(N * 32 + 255) / 256, 256, 0, stream>>>(x, XB, N * 32);

    // ---- attention: a_s = x·(W1@att_src1), a_d = x·(W1@att_dst1) ----
    k_rowdot2f<<<64, 256, 0, stream>>>(W1, 512, 512, as1, ad1, vs1, vd1, 256);
    k_rowdot2f<<<NB4, 256, 0, stream>>>(x, 256, 256, vs1, vd1, a_s, a_d, N);
    k_alpha<<<NB4, 256, 0, stream>>>(offA, srcs, a_s, a_d, alpha, N);

    // ---- aggx = sum_e alpha_e * xb[src_e]  (GAT linearity: agg before W1) ----
    k_aggw<<<NB4, 256, 0, stream>>>(XB, offA, srcs, alpha, nullptr, AGGX, N);

    // ---- pre = x@A1 + b1 + bc1 ; hl1 = relu(aggx@W1 + pre) in-place ----
    dim3 g512(RB64, 8);
    gemm64<true><<<g512, 256, 0, stream>>>(x, A1w, b1, bc1, nullptr,
                                           BUF2, N, 256, 512, 0);
    gemm64<false><<<g512, 256, 0, stream>>>(AGGX, W1, nullptr, nullptr, BUF2,
                                            BUF2, N, 256, 512, 1);

    // ---- layer 2: h2 = hl1@W2 ; res2 = hl1@A2 + b2 + bc2 ----
    dim3 g256(RB64, 4);
    gemm64<false><<<g256, 256, 0, stream>>>(BUF2, W2, nullptr, nullptr, nullptr,
                                            BUF1, N, 512, 256, 0);
    gemm64<false><<<g256, 256, 0, stream>>>(BUF2, A2w, b2, bc2, nullptr,
                                            BUF1 + NH2, N, 512, 256, 0);

    k_rowdot2<<<NB4, 256, 0, stream>>>(BUF1, 256, 256, as2, ad2, a_s, a_d, N);
    k_alpha<<<NB4, 256, 0, stream>>>(offA, srcs, a_s, a_d, alpha, N);
    k_aggw<<<NB4, 256, 0, stream>>>(BUF1, offA, srcs, alpha, BUF1 + NH2, BUF2, N);

    // ---- MLP 3x [256->256] relu, in-place in BUF2 (MFMA rowfull) ----
    rowfull256<<<RB64, 256, 0, stream>>>(BUF2, Hw1, Hb1, BUF2, N, 1);
    rowfull256<<<RB64, 256, 0, stream>>>(BUF2, Hw2, Hb2, BUF2, N, 1);
    rowfull256<<<RB64, 256, 0, stream>>>(BUF2, Hw3, Hb3, BUF2, N, 1);

    // ---- classifier + softmax (fp32 out) ----
    k_fc_softmax<<<N, 64, 0, stream>>>(BUF2, fcw, fcb, out, N);

    k_final_diag<<<OB, 256, 0, stream>>>(flag, out, out_size);
}

// Round 2
// 902.243 us; speedup vs baseline: 1.3411x; 1.0941x over previous
//
#include <hip/hip_runtime.h>

typedef unsigned short u16;
typedef short short8 __attribute__((ext_vector_type(8)));
typedef u16 u16x4 __attribute__((ext_vector_type(4)));
typedef float float4v __attribute__((ext_vector_type(4)));

#define NEG_SLOPE 0.2f

static __device__ __forceinline__ float b2f(u16 u) {
    union { unsigned int i; float f; } x; x.i = ((unsigned int)u) << 16; return x.f;
}
static __device__ __forceinline__ u16 f2b(float f) {
    unsigned int u = __float_as_uint(f);
    unsigned int r = (u + 0x7fffu + ((u >> 16) & 1u)) >> 16;
    return (u16)r;
}

// ---------------------------------------------------------------------------
// diagnostics: code 32 = CSR inconsistent; 1000+ = ws too small
// ---------------------------------------------------------------------------
__global__ void k_diag(float* out, int n, float val)
{
    int i = blockIdx.x * 256 + threadIdx.x;
    if (i < n) out[i] = val;
}

__global__ void scan_csr(const int* off, const int* srcs, int N, int E,
                         int* flag, int bit)
{
    int i = blockIdx.x * 256 + threadIdx.x;
    if (i < N) {
        int a = off[i], b = off[i + 1];
        if (a < 0 || b < a || b > E) atomicOr(flag, bit);
    }
    if (i == 0 && off[N] != E) atomicOr(flag, bit);
    if (i < E) {
        if ((unsigned)srcs[i] >= (unsigned)N) atomicOr(flag, bit);
    }
}

__global__ void k_final_diag(const int* flag, float* out, int n)
{
    int f = *flag;
    if (f == 0) return;
    int b = __ffs(f) - 1;
    float val = 32.0f * (b + 1);
    int i = blockIdx.x * 256 + threadIdx.x;
    if (i < n) out[i] = val;
}

// ---------------------------------------------------------------------------
// edge_index dtype probe + canonical int32 extraction
// ---------------------------------------------------------------------------
__global__ void k_detect(const int* ei, int E, int* flag64)
{
    __shared__ int zc;
    if (threadIdx.x == 0) zc = 0;
    __syncthreads();
    int idx = 1 + 2 * (int)threadIdx.x;
    int z = (idx < 2 * E && ei[idx] == 0) ? 1 : 0;
    atomicAdd(&zc, z);
    __syncthreads();
    if (threadIdx.x == 0) *flag64 = (zc >= 200) ? 1 : 0;
}

__global__ void k_extract(const int* ei, int E, const int* flag64,
                          int* src, int* dst)
{
    int e = blockIdx.x * 256 + threadIdx.x;
    if (e >= E) return;
    if (*flag64) {
        src[e] = ei[2 * e];
        dst[e] = ei[2 * E + 2 * e];
    } else {
        src[e] = ei[e];
        dst[e] = ei[E + e];
    }
}

// ---------------------------------------------------------------------------
// CSR construction (bound-checked)
// ---------------------------------------------------------------------------
__global__ void k_count(const int* dst, int* deg, int E, int N)
{
    int e = blockIdx.x * 256 + threadIdx.x;
    if (e < E) {
        int d = dst[e];
        if ((unsigned)d < (unsigned)N) atomicAdd(&deg[d], 1);
    }
}

// ---------------------------------------------------------------------------
// device-wide exclusive scan, 3-phase (1024 elems per block in phase A)
// ---------------------------------------------------------------------------
__global__ __launch_bounds__(256)
void k_scan_a(const int* __restrict__ deg, int* __restrict__ off,
              int* __restrict__ partial, int N)
{
    __shared__ int sd[256];
    int tid = threadIdx.x;
    int base = blockIdx.x * 1024;
    int i0 = base + tid * 4;
    int v0 = 0, v1 = 0, v2 = 0, v3 = 0;
    if (i0 < N)     v0 = deg[i0];
    if (i0 + 1 < N) v1 = deg[i0 + 1];
    if (i0 + 2 < N) v2 = deg[i0 + 2];
    if (i0 + 3 < N) v3 = deg[i0 + 3];
    int t = v0 + v1 + v2 + v3;
    sd[tid] = t;
    __syncthreads();
    #pragma unroll
    for (int s = 1; s < 256; s <<= 1) {
        int u = (tid >= s) ? sd[tid - s] : 0;
        __syncthreads();
        sd[tid] += u;
        __syncthreads();
    }
    int excl = sd[tid] - t;                 // exclusive within block
    if (i0 < N)     off[i0]     = excl;
    if (i0 + 1 < N) off[i0 + 1] = excl + v0;
    if (i0 + 2 < N) off[i0 + 2] = excl + v0 + v1;
    if (i0 + 3 < N) off[i0 + 3] = excl + v0 + v1 + v2;
    if (tid == 255) partial[blockIdx.x] = sd[255];
}

__global__ __launch_bounds__(1024)
void k_scan_b(int* partial, int nblk)
{
    __shared__ int sd[1024];
    __shared__ int running;
    int tid = threadIdx.x;
    if (tid == 0) running = 0;
    __syncthreads();
    for (int base = 0; base < nblk; base += 1024) {
        int i = base + tid;
        int v = (i < nblk) ? partial[i] : 0;
        sd[tid] = v;
        __syncthreads();
        for (int s = 1; s < 1024; s <<= 1) {
            int u = (tid >= s) ? sd[tid - s] : 0;
            __syncthreads();
            sd[tid] += u;
            __syncthreads();
        }
        if (i < nblk) partial[i] = sd[tid] - v + running;   // exclusive
        int total = sd[1023];
        __syncthreads();
        if (tid == 0) running += total;
        __syncthreads();
    }
}

__global__ __launch_bounds__(256)
void k_scan_c(int* __restrict__ off, int* __restrict__ cursor,
              const int* __restrict__ partial, int N, int E)
{
    int i = blockIdx.x * 256 + threadIdx.x;
    if (i < N) {
        int v = off[i] + partial[i >> 10];
        off[i] = v;
        cursor[i] = v;
    }
    if (i == 0) off[N] = E;
}

__global__ void k_scatter(const int* src, const int* dst, int* cursor,
                          int* srcs, int E, int N)
{
    int e = blockIdx.x * 256 + threadIdx.x;
    if (e < E) {
        int d = dst[e];
        if ((unsigned)d < (unsigned)N) {
            int p = atomicAdd(&cursor[d], 1);
            if ((unsigned)p < (unsigned)E) srcs[p] = src[e];
        }
    }
}

// ---------------------------------------------------------------------------
// fp32 -> bf16 bulk cast (8 elems/thread)
// ---------------------------------------------------------------------------
__global__ __launch_bounds__(256)
void k_f2b8(const float* __restrict__ in, u16* __restrict__ out, int n8)
{
    int i = blockIdx.x * 256 + threadIdx.x;
    if (i >= n8) return;
    const float4* p = (const float4*)in + (size_t)i * 2;
    float4 v0 = p[0], v1 = p[1];
    int4 w;
    w.x = (int)f2b(v0.x) | ((int)f2b(v0.y) << 16);
    w.y = (int)f2b(v0.z) | ((int)f2b(v0.w) << 16);
    w.z = (int)f2b(v1.x) | ((int)f2b(v1.y) << 16);
    w.w = (int)f2b(v1.z) | ((int)f2b(v1.w) << 16);
    *(int4*)(out + (size_t)i * 8) = w;
}

// ---------------------------------------------------------------------------
// fp32 row-dot against two fp32 vectors — one wave per row, float4 lanes
// ---------------------------------------------------------------------------
__global__ __launch_bounds__(256)
void k_rowdot2f(const float* __restrict__ A, int ld, int H,
                const float* __restrict__ vs, const float* __restrict__ vd,
                float* a_s, float* a_d, int N)
{
    int wave = threadIdx.x >> 6, lane = threadIdx.x & 63;
    int n = blockIdx.x * 4 + wave;
    if (n >= N) return;
    const float* ar = A + (size_t)n * ld;
    float ss = 0.f, sd = 0.f;
    for (int i = lane * 4; i < H; i += 256) {
        float4 v  = *(const float4*)(ar + i);
        float4 s4 = *(const float4*)(vs + i);
        float4 d4 = *(const float4*)(vd + i);
        ss += v.x * s4.x + v.y * s4.y + v.z * s4.z + v.w * s4.w;
        sd += v.x * d4.x + v.y * d4.y + v.z * d4.z + v.w * d4.w;
    }
    #pragma unroll
    for (int m = 32; m; m >>= 1) {
        ss += __shfl_xor(ss, m, 64);
        sd += __shfl_xor(sd, m, 64);
    }
    if (lane == 0) { a_s[n] = ss; a_d[n] = sd; }
}

// ---------------------------------------------------------------------------
// bf16 row-dot (for layer-2 h2) — one wave per node
// ---------------------------------------------------------------------------
__global__ __launch_bounds__(256)
void k_rowdot2(const u16* h, int ld, int H, const float* vs, const float* vd,
               float* a_s, float* a_d, int N)
{
    int wave = threadIdx.x >> 6, lane = threadIdx.x & 63;
    int n = blockIdx.x * 4 + wave;
    if (n >= N) return;
    const u16* hr = h + (size_t)n * ld;
    float ss = 0.f, sd = 0.f;
    for (int i = lane; i < H; i += 64) {
        float v = b2f(hr[i]);
        ss += v * vs[i];
        sd += v * vd[i];
    }
    #pragma unroll
    for (int m = 32; m; m >>= 1) {
        ss += __shfl_xor(ss, m, 64);
        sd += __shfl_xor(sd, m, 64);
    }
    if (lane == 0) { a_s[n] = ss; a_d[n] = sd; }
}

// ---------------------------------------------------------------------------
// per-dst softmax stats + normalized per-edge alpha (3-pass, wave per node)
// ---------------------------------------------------------------------------
__global__ __launch_bounds__(256)
void k_alpha(const int* __restrict__ off, const int* __restrict__ srcs,
             const float* __restrict__ a_s, const float* __restrict__ a_d,
             float* __restrict__ alpha, int N)
{
    int wave = threadIdx.x >> 6, lane = threadIdx.x & 63;
    int n = blockIdx.x * 4 + wave;
    if (n >= N) return;
    int base = off[n], end = off[n + 1];
    float adn = a_d[n];
    float m = -1e30f;
    for (int p = base + lane; p < end; p += 64) {
        int s = srcs[p];
        s = ((unsigned)s < (unsigned)N) ? s : 0;
        float z = a_s[s] + adn;
        z = z > 0.f ? z : NEG_SLOPE * z;
        m = fmaxf(m, z);
    }
    #pragma unroll
    for (int s = 32; s; s >>= 1) m = fmaxf(m, __shfl_xor(m, s, 64));
    float sum = 0.f;
    for (int p = base + lane; p < end; p += 64) {
        int s = srcs[p];
        s = ((unsigned)s < (unsigned)N) ? s : 0;
        float z = a_s[s] + adn;
        z = z > 0.f ? z : NEG_SLOPE * z;
        sum += __expf(z - m);
    }
    #pragma unroll
    for (int s = 32; s; s >>= 1) sum += __shfl_xor(sum, s, 64);
    float inv = 1.f / (sum + 1e-16f);
    for (int p = base + lane; p < end; p += 64) {
        int s = srcs[p];
        s = ((unsigned)s < (unsigned)N) ? s : 0;
        float z = a_s[s] + adn;
        z = z > 0.f ? z : NEG_SLOPE * z;
        alpha[p] = __expf(z - m) * inv;
    }
}

// ---------------------------------------------------------------------------
// weighted gather-aggregate over 256-ch bf16 rows: one wave per node,
// 8B/lane gathers, precomputed normalized alpha, optional bf16 addend.
// out[n] = sum_e alpha[e] * rows[srcs[e]]  (+ add[n])
// ---------------------------------------------------------------------------
__global__ __launch_bounds__(256)
void k_aggw(const u16* __restrict__ rows, const int* __restrict__ off,
            const int* __restrict__ srcs, const float* __restrict__ alpha,
            const u16* __restrict__ add, u16* __restrict__ out, int N)
{
    int wave = threadIdx.x >> 6, lane = threadIdx.x & 63;
    int n = blockIdx.x * 4 + wave;
    if (n >= N) return;
    int base = off[n], end = off[n + 1];
    int c4 = lane * 4;
    float a0 = 0.f, a1 = 0.f, a2 = 0.f, a3 = 0.f;
    int p = base;
    for (; p + 1 < end; p += 2) {
        int s0 = srcs[p];     s0 = ((unsigned)s0 < (unsigned)N) ? s0 : 0;
        int s1 = srcs[p + 1]; s1 = ((unsigned)s1 < (unsigned)N) ? s1 : 0;
        float w0 = alpha[p], w1 = alpha[p + 1];
        u16x4 v0 = *(const u16x4*)(rows + (size_t)s0 * 256 + c4);
        u16x4 v1 = *(const u16x4*)(rows + (size_t)s1 * 256 + c4);
        a0 += w0 * b2f(v0[0]) + w1 * b2f(v1[0]);
        a1 += w0 * b2f(v0[1]) + w1 * b2f(v1[1]);
        a2 += w0 * b2f(v0[2]) + w1 * b2f(v1[2]);
        a3 += w0 * b2f(v0[3]) + w1 * b2f(v1[3]);
    }
    if (p < end) {
        int s0 = srcs[p]; s0 = ((unsigned)s0 < (unsigned)N) ? s0 : 0;
        float w0 = alpha[p];
        u16x4 v0 = *(const u16x4*)(rows + (size_t)s0 * 256 + c4);
        a0 += w0 * b2f(v0[0]);
        a1 += w0 * b2f(v0[1]);
        a2 += w0 * b2f(v0[2]);
        a3 += w0 * b2f(v0[3]);
    }
    size_t ob = (size_t)n * 256 + c4;
    if (add) {
        a0 += b2f(add[ob]);     a1 += b2f(add[ob + 1]);
        a2 += b2f(add[ob + 2]); a3 += b2f(add[ob + 3]);
    }
    u16x4 o;
    o[0] = f2b(a0); o[1] = f2b(a1); o[2] = f2b(a2); o[3] = f2b(a3);
    *(u16x4*)(out + ob) = o;
}

// ---------------------------------------------------------------------------
// MFMA GEMM, 64x64 tile, BK=32. A: fp32 (AF32) or bf16; B: fp32 weights.
// Both converted to bf16 during LDS staging. C bf16 [M,NC] (+fp32 biases,
// optional bf16 addend matrix Cadd — safe with Cadd==C, optional relu).
// ---------------------------------------------------------------------------
template<bool AF32>
__global__ __launch_bounds__(256)
void gemm64(const void* Ap, const float* B, const float* bias1, const float* bias2,
            const u16* Cadd, u16* C, int M, int K, int NC, int relu)
{
    __shared__ u16 As[64][40];
    __shared__ u16 Bs[64][40];   // transposed: Bs[n][k]

    const int tid  = threadIdx.x;
    const int wave = tid >> 6;
    const int lane = tid & 63;
    const int rowBase = blockIdx.x * 64;
    const int colBase = blockIdx.y * 64;

    float4v acc[4] = {};
    const int ar = tid >> 2;          // 0..63
    const int ac = (tid & 3) * 8;     // 0,8,16,24
    const int bk = tid >> 3;          // 0..31
    const int bn = (tid & 7) * 8;     // 0..56
    const int m16 = lane & 15;
    const int q = lane >> 4;

    for (int k0 = 0; k0 < K; k0 += 32) {
        __syncthreads();
        {   // stage A 64x32
            int grow = rowBase + ar;
            if (AF32) {
                const float* Af = (const float*)Ap;
                float4 v0 = {0,0,0,0}, v1 = {0,0,0,0};
                if (grow < M) {
                    const float* p = Af + (size_t)grow * K + k0 + ac;
                    v0 = *(const float4*)p;
                    v1 = *(const float4*)(p + 4);
                }
                u16* d = &As[ar][ac];
                d[0]=f2b(v0.x); d[1]=f2b(v0.y); d[2]=f2b(v0.z); d[3]=f2b(v0.w);
                d[4]=f2b(v1.x); d[5]=f2b(v1.y); d[6]=f2b(v1.z); d[7]=f2b(v1.w);
            } else {
                const u16* Ab = (const u16*)Ap;
                int4 v = {0, 0, 0, 0};
                if (grow < M) v = *(const int4*)(Ab + (size_t)grow * K + k0 + ac);
                *(int4*)&As[ar][ac] = v;
            }
        }
        {   // stage B 32x64 fp32 -> bf16, transposed
            const float* bp = B + (size_t)(k0 + bk) * NC + colBase + bn;
            float4 w0 = *(const float4*)bp;
            float4 w1 = *(const float4*)(bp + 4);
            u16 t[8] = {f2b(w0.x), f2b(w0.y), f2b(w0.z), f2b(w0.w),
                        f2b(w1.x), f2b(w1.y), f2b(w1.z), f2b(w1.w)};
            #pragma unroll
            for (int j = 0; j < 8; ++j) Bs[bn + j][bk] = t[j];
        }
        __syncthreads();

        short8 aF = *(const short8*)&As[wave * 16 + m16][q * 8];
        #pragma unroll
        for (int c = 0; c < 4; ++c) {
            short8 bF = *(const short8*)&Bs[c * 16 + m16][q * 8];
            acc[c] = __builtin_amdgcn_mfma_f32_16x16x32_bf16(aF, bF, acc[c], 0, 0, 0);
        }
    }

    #pragma unroll
    for (int c = 0; c < 4; ++c) {
        int gcol = colBase + c * 16 + m16;
        float bv = (bias1 ? bias1[gcol] : 0.f) + (bias2 ? bias2[gcol] : 0.f);
        #pragma unroll
        for (int i = 0; i < 4; ++i) {
            int grow = rowBase + wave * 16 + q * 4 + i;
            if (grow < M) {
                float v = acc[c][i] + bv;
                if (Cadd) v += b2f(Cadd[(size_t)grow * NC + gcol]);
                if (relu) v = fmaxf(v, 0.f);
                C[(size_t)grow * NC + gcol] = f2b(v);
            }
        }
    }
}

// ---------------------------------------------------------------------------
// MFMA full-row-width GEMM (BM=64, K=NC=256), in-place safe (C==A):
// one block owns 64 rows entirely; A bf16, B fp32 (staged->bf16), bias fp32.
// ---------------------------------------------------------------------------
__global__ __launch_bounds__(256)
void rowfull256(const u16* A, const float* B, const float* bias,
                u16* C, int M, int relu)
{
    __shared__ u16 As[64][40];
    __shared__ u16 Bs[256][40];

    const int tid  = threadIdx.x;
    const int wave = tid >> 6;
    const int lane = tid & 63;
    const int rowBase = blockIdx.x * 64;
    const int m16 = lane & 15;
    const int q = lane >> 4;

    float4v acc[16] = {};
    const int ar = tid >> 2, ac = (tid & 3) * 8;
    const int bk = tid >> 3, bn0 = (tid & 7) * 8;

    for (int k0 = 0; k0 < 256; k0 += 32) {
        __syncthreads();
        {
            int grow = rowBase + ar;
            int4 v = {0, 0, 0, 0};
            if (grow < M) v = *(const int4*)(A + (size_t)grow * 256 + k0 + ac);
            *(int4*)&As[ar][ac] = v;
        }
        #pragma unroll
        for (int j8 = 0; j8 < 4; ++j8) {
            int bn = bn0 + j8 * 64;
            const float* bp = B + (size_t)(k0 + bk) * 256 + bn;
            float4 w0 = *(const float4*)bp;
            float4 w1 = *(const float4*)(bp + 4);
            u16 t[8] = {f2b(w0.x), f2b(w0.y), f2b(w0.z), f2b(w0.w),
                        f2b(w1.x), f2b(w1.y), f2b(w1.z), f2b(w1.w)};
            #pragma unroll
            for (int j = 0; j < 8; ++j) Bs[bn + j][bk] = t[j];
        }
        __syncthreads();

        short8 aF = *(const short8*)&As[wave * 16 + m16][q * 8];
        #pragma unroll
        for (int c = 0; c < 16; ++c) {
            short8 bF = *(const short8*)&Bs[c * 16 + m16][q * 8];
            acc[c] = __builtin_amdgcn_mfma_f32_16x16x32_bf16(aF, bF, acc[c], 0, 0, 0);
        }
    }

    #pragma unroll
    for (int c = 0; c < 16; ++c) {
        int col = c * 16 + m16;
        float bv = bias ? bias[col] : 0.f;
        #pragma unroll
        for (int i = 0; i < 4; ++i) {
            int grow = rowBase + wave * 16 + q * 4 + i;
            if (grow < M) {
                float v = acc[c][i] + bv;
                if (relu) v = fmaxf(v, 0.f);
                C[(size_t)grow * 256 + col] = f2b(v);
            }
        }
    }
}

// ---------------------------------------------------------------------------
// classifier + softmax: one wave per node, 256 -> 5, fp32 output
// ---------------------------------------------------------------------------
__global__ __launch_bounds__(64)
void k_fc_softmax(const u16* hin, const float* fcw, const float* fcb,
                  float* out, int N)
{
    int n = blockIdx.x;
    int lane = threadIdx.x;
    const u16* hr = hin + (size_t)n * 256;
    int k0 = lane * 4;
    float hv[4];
    float p[5] = {0.f, 0.f, 0.f, 0.f, 0.f};
    #pragma unroll
    for (int j = 0; j < 4; ++j) hv[j] = b2f(hr[k0 + j]);
    #pragma unroll
    for (int j = 0; j < 4; ++j) {
        const float* wr = fcw + (size_t)(k0 + j) * 5;
        #pragma unroll
        for (int c = 0; c < 5; ++c) p[c] += hv[j] * wr[c];
    }
    #pragma unroll
    for (int c = 0; c < 5; ++c) {
        #pragma unroll
        for (int s = 32; s; s >>= 1) p[c] += __shfl_xor(p[c], s, 64);
    }
    if (lane == 0) {
        float m = -1e30f;
        #pragma unroll
        for (int c = 0; c < 5; ++c) { p[c] += fcb[c]; m = fmaxf(m, p[c]); }
        float s = 0.f, e[5];
        #pragma unroll
        for (int c = 0; c < 5; ++c) { e[c] = __expf(p[c] - m); s += e[c]; }
        float inv = 1.f / s;
        #pragma unroll
        for (int c = 0; c < 5; ++c) out[(size_t)n * 5 + c] = e[c] * inv;
    }
}

// ---------------------------------------------------------------------------
extern "C" void kernel_launch(void* const* d_in, const int* in_sizes, int n_in,
                              void* d_out, int out_size, void* d_ws, size_t ws_size,
                              hipStream_t stream)
{
    const float* x    = (const float*)d_in[0];
    const int*   ei   = (const int*)  d_in[1];
    const float* W1   = (const float*)d_in[2];
    const float* as1  = (const float*)d_in[3];
    const float* ad1  = (const float*)d_in[4];
    const float* bc1  = (const float*)d_in[5];
    const float* A1w  = (const float*)d_in[6];
    const float* b1   = (const float*)d_in[7];
    const float* W2   = (const float*)d_in[8];
    const float* as2  = (const float*)d_in[9];
    const float* ad2  = (const float*)d_in[10];
    const float* bc2  = (const float*)d_in[11];
    const float* A2w  = (const float*)d_in[12];
    const float* b2   = (const float*)d_in[13];
    const float* Hw1  = (const float*)d_in[14];
    const float* Hb1  = (const float*)d_in[15];
    const float* Hw2  = (const float*)d_in[16];
    const float* Hb2  = (const float*)d_in[17];
    const float* Hw3  = (const float*)d_in[18];
    const float* Hb3  = (const float*)d_in[19];
    const float* fcw  = (const float*)d_in[20];
    const float* fcb  = (const float*)d_in[21];
    float* out = (float*)d_out;

    const int D = 256;
    const int N = in_sizes[0] / D;
    const int E = in_sizes[1] / 2;

    char* w = (char*)d_ws;
    auto alloc = [&](size_t bytes) {
        char* p = w;
        w += (bytes + 255) & ~(size_t)255;
        return p;
    };
    int*   flag   = (int*)  alloc(256);
    int*   flag64 = (int*)  alloc(256);
    float* a_s    = (float*)alloc((size_t)N * 4);
    float* a_d    = (float*)alloc((size_t)N * 4);
    float* vs1    = (float*)alloc(1024);                 // W1 @ att_src1  [256]
    float* vd1    = (float*)alloc(1024);                 // W1 @ att_dst1  [256]
    int*   deg    = (int*)  alloc((size_t)N * 4);
    int*   cursor = (int*)  alloc((size_t)N * 4);
    int*   offA   = (int*)  alloc((size_t)(N + 1) * 4);
    int*   part   = (int*)  alloc((size_t)((N + 1023) / 1024 + 1) * 4);
    int*   srcs   = (int*)  alloc((size_t)E * 4);
    float* alpha  = (float*)alloc((size_t)E * 4);        // normalized edge weights
    u16*   BUF1   = (u16*)  alloc((size_t)N * 512 * 2);  // xb|aggx -> h2|res2
    u16*   BUF2   = (u16*)  alloc((size_t)N * 512 * 2);  // pre/hl1 -> out2/MLP

    // src32/dst32 alias BUF1 (dead before xb is written)
    int* src32 = (int*)BUF1;
    int* dst32 = src32 + E;

    size_t need = (size_t)(w - (char*)d_ws);             // ~110 MB
    if (ws_size < need) {
        float code = 1000.0f + (float)(ws_size >> 20);
        k_diag<<<(out_size + 255) / 256, 256, 0, stream>>>(out, out_size, code);
        return;
    }

    const int EB  = (E + 255) / 256;
    const int NB4 = (N + 3) / 4;
    const int OB  = (out_size + 255) / 256;
    const int NE  = (N > E ? N : E);
    const int RB64 = (N + 63) / 64;
    const int NBLK = (N + 1023) / 1024;
    const size_t NH2 = (size_t)N * 256;
    u16* XB   = BUF1;            // bf16 cast of x      [N,256]
    u16* AGGX = BUF1 + NH2;      // alpha-aggregated x  [N,256]

    hipMemsetAsync(flag, 0, 4, stream);

    // ---- edge extraction + CSR by destination ----
    k_detect <<<1, 256, 0, stream>>>(ei, E, flag64);
    k_extract<<<EB, 256, 0, stream>>>(ei, E, flag64, src32, dst32);
    hipMemsetAsync(deg, 0, (size_t)N * 4, stream);
    k_count  <<<EB, 256, 0, stream>>>(dst32, deg, E, N);
    k_scan_a <<<NBLK, 256, 0, stream>>>(deg, offA, part, N);
    k_scan_b <<<1, 1024, 0, stream>>>(part, NBLK);
    k_scan_c <<<(N + 255) / 256, 256, 0, stream>>>(offA, cursor, part, N, E);
    k_scatter<<<EB, 256, 0, stream>>>(src32, dst32, cursor, srcs, E, N);
    scan_csr <<<(NE + 255) / 256, 256, 0, stream>>>(offA, srcs, N, E, flag, 1);

    // ---- xb = bf16(x) (overwrites src32/dst32 region, already dead) ----
    k_f2b8<<<(N * 32 + 255) / 256, 256, 0, stream>>>(x, XB, N * 32);

    // ---- attention: a_s = x·(W1@att_src1), a_d = x·(W1@att_dst1) ----
    k_rowdot2f<<<64, 256, 0, stream>>>(W1, 512, 512, as1, ad1, vs1, vd1, 256);
    k_rowdot2f<<<NB4, 256, 0, stream>>>(x, 256, 256, vs1, vd1, a_s, a_d, N);
    k_alpha<<<NB4, 256, 0, stream>>>(offA, srcs, a_s, a_d, alpha, N);

    // ---- aggx = sum_e alpha_e * xb[src_e]  (GAT linearity: agg before W1) ----
    k_aggw<<<NB4, 256, 0, stream>>>(XB, offA, srcs, alpha, nullptr, AGGX, N);

    // ---- pre = x@A1 + b1 + bc1 ; hl1 = relu(aggx@W1 + pre) in-place ----
    dim3 g512(RB64, 8);
    gemm64<true><<<g512, 256, 0, stream>>>(x, A1w, b1, bc1, nullptr,
                                           BUF2, N, 256, 512, 0);
    gemm64<false><<<g512, 256, 0, stream>>>(AGGX, W1, nullptr, nullptr, BUF2,
                                            BUF2, N, 256, 512, 1);

    // ---- layer 2: h2 = hl1@W2 ; res2 = hl1@A2 + b2 + bc2 ----
    dim3 g256(RB64, 4);
    gemm64<false><<<g256, 256, 0, stream>>>(BUF2, W2, nullptr, nullptr, nullptr,
                                            BUF1, N, 512, 256, 0);
    gemm64<false><<<g256, 256, 0, stream>>>(BUF2, A2w, b2, bc2, nullptr,
                                            BUF1 + NH2, N, 512, 256, 0);

    k_rowdot2<<<NB4, 256, 0, stream>>>(BUF1, 256, 256, as2, ad2, a_s, a_d, N);
    k_alpha<<<NB4, 256, 0, stream>>>(offA, srcs, a_s, a_d, alpha, N);
    k_aggw<<<NB4, 256, 0, stream>>>(BUF1, offA, srcs, alpha, BUF1 + NH2, BUF2, N);

    // ---- MLP 3x [256->256] relu, in-place in BUF2 (MFMA rowfull) ----
    rowfull256<<<RB64, 256, 0, stream>>>(BUF2, Hw1, Hb1, BUF2, N, 1);
    rowfull256<<<RB64, 256, 0, stream>>>(BUF2, Hw2, Hb2, BUF2, N, 1);
    rowfull256<<<RB64, 256, 0, stream>>>(BUF2, Hw3, Hb3, BUF2, N, 1);

    // ---- classifier + softmax (fp32 out) ----
    k_fc_softmax<<<N, 64, 0, stream>>>(BUF2, fcw, fcb, out, N);

    k_final_diag<<<OB, 256, 0, stream>>>(flag, out, out_size);
}

// Round 3
// 663.054 us; speedup vs baseline: 1.8248x; 1.3607x over previous
//
#include <hip/hip_runtime.h>

typedef unsigned short u16;
typedef short short8 __attribute__((ext_vector_type(8)));
typedef u16 u16x4 __attribute__((ext_vector_type(4)));
typedef float float4v __attribute__((ext_vector_type(4)));

#define NEG_SLOPE 0.2f

static __device__ __forceinline__ float b2f(u16 u) {
    union { unsigned int i; float f; } x; x.i = ((unsigned int)u) << 16; return x.f;
}
static __device__ __forceinline__ u16 f2b(float f) {
    unsigned int u = __float_as_uint(f);
    unsigned int r = (u + 0x7fffu + ((u >> 16) & 1u)) >> 16;
    return (u16)r;
}

// ---------------------------------------------------------------------------
// diagnostics: code 32 = CSR inconsistent; 1000+ = ws too small
// ---------------------------------------------------------------------------
__global__ void k_diag(float* out, int n, float val)
{
    int i = blockIdx.x * 256 + threadIdx.x;
    if (i < n) out[i] = val;
}

__global__ void scan_csr(const int* off, const int* srcs, int N, int E,
                         int* flag, int bit)
{
    int i = blockIdx.x * 256 + threadIdx.x;
    if (i < N) {
        int a = off[i], b = off[i + 1];
        if (a < 0 || b < a || b > E) atomicOr(flag, bit);
    }
    if (i == 0 && off[N] != E) atomicOr(flag, bit);
    if (i < E) {
        if ((unsigned)srcs[i] >= (unsigned)N) atomicOr(flag, bit);
    }
}

__global__ void k_final_diag(const int* flag, float* out, int n)
{
    int f = *flag;
    if (f == 0) return;
    int b = __ffs(f) - 1;
    float val = 32.0f * (b + 1);
    int i = blockIdx.x * 256 + threadIdx.x;
    if (i < n) out[i] = val;
}

// ---------------------------------------------------------------------------
// edge_index dtype probe + canonical int32 extraction
// ---------------------------------------------------------------------------
__global__ void k_detect(const int* ei, int E, int* flag64)
{
    __shared__ int zc;
    if (threadIdx.x == 0) zc = 0;
    __syncthreads();
    int idx = 1 + 2 * (int)threadIdx.x;
    int z = (idx < 2 * E && ei[idx] == 0) ? 1 : 0;
    atomicAdd(&zc, z);
    __syncthreads();
    if (threadIdx.x == 0) *flag64 = (zc >= 200) ? 1 : 0;
}

__global__ void k_extract(const int* ei, int E, const int* flag64,
                          int* src, int* dst)
{
    int e = blockIdx.x * 256 + threadIdx.x;
    if (e >= E) return;
    if (*flag64) {
        src[e] = ei[2 * e];
        dst[e] = ei[2 * E + 2 * e];
    } else {
        src[e] = ei[e];
        dst[e] = ei[E + e];
    }
}

// ---------------------------------------------------------------------------
// CSR construction (bound-checked)
// ---------------------------------------------------------------------------
__global__ void k_count(const int* dst, int* deg, int E, int N)
{
    int e = blockIdx.x * 256 + threadIdx.x;
    if (e < E) {
        int d = dst[e];
        if ((unsigned)d < (unsigned)N) atomicAdd(&deg[d], 1);
    }
}

// ---------------------------------------------------------------------------
// device-wide exclusive scan, 3-phase (1024 elems per block in phase A)
// ---------------------------------------------------------------------------
__global__ __launch_bounds__(256)
void k_scan_a(const int* __restrict__ deg, int* __restrict__ off,
              int* __restrict__ partial, int N)
{
    __shared__ int sd[256];
    int tid = threadIdx.x;
    int base = blockIdx.x * 1024;
    int i0 = base + tid * 4;
    int v0 = 0, v1 = 0, v2 = 0, v3 = 0;
    if (i0 < N)     v0 = deg[i0];
    if (i0 + 1 < N) v1 = deg[i0 + 1];
    if (i0 + 2 < N) v2 = deg[i0 + 2];
    if (i0 + 3 < N) v3 = deg[i0 + 3];
    int t = v0 + v1 + v2 + v3;
    sd[tid] = t;
    __syncthreads();
    #pragma unroll
    for (int s = 1; s < 256; s <<= 1) {
        int u = (tid >= s) ? sd[tid - s] : 0;
        __syncthreads();
        sd[tid] += u;
        __syncthreads();
    }
    int excl = sd[tid] - t;                 // exclusive within block
    if (i0 < N)     off[i0]     = excl;
    if (i0 + 1 < N) off[i0 + 1] = excl + v0;
    if (i0 + 2 < N) off[i0 + 2] = excl + v0 + v1;
    if (i0 + 3 < N) off[i0 + 3] = excl + v0 + v1 + v2;
    if (tid == 255) partial[blockIdx.x] = sd[255];
}

__global__ __launch_bounds__(1024)
void k_scan_b(int* partial, int nblk)
{
    __shared__ int sd[1024];
    __shared__ int running;
    int tid = threadIdx.x;
    if (tid == 0) running = 0;
    __syncthreads();
    for (int base = 0; base < nblk; base += 1024) {
        int i = base + tid;
        int v = (i < nblk) ? partial[i] : 0;
        sd[tid] = v;
        __syncthreads();
        for (int s = 1; s < 1024; s <<= 1) {
            int u = (tid >= s) ? sd[tid - s] : 0;
            __syncthreads();
            sd[tid] += u;
            __syncthreads();
        }
        if (i < nblk) partial[i] = sd[tid] - v + running;   // exclusive
        int total = sd[1023];
        __syncthreads();
        if (tid == 0) running += total;
        __syncthreads();
    }
}

__global__ __launch_bounds__(256)
void k_scan_c(int* __restrict__ off, int* __restrict__ cursor,
              const int* __restrict__ partial, int N, int E)
{
    int i = blockIdx.x * 256 + threadIdx.x;
    if (i < N) {
        int v = off[i] + partial[i >> 10];
        off[i] = v;
        cursor[i] = v;
    }
    if (i == 0) off[N] = E;
}

__global__ void k_scatter(const int* src, const int* dst, int* cursor,
                          int* srcs, int E, int N)
{
    int e = blockIdx.x * 256 + threadIdx.x;
    if (e < E) {
        int d = dst[e];
        if ((unsigned)d < (unsigned)N) {
            int p = atomicAdd(&cursor[d], 1);
            if ((unsigned)p < (unsigned)E) srcs[p] = src[e];
        }
    }
}

// ---------------------------------------------------------------------------
// fp32 -> bf16 bulk cast (8 elems/thread)
// ---------------------------------------------------------------------------
__global__ __launch_bounds__(256)
void k_f2b8(const float* __restrict__ in, u16* __restrict__ out, int n8)
{
    int i = blockIdx.x * 256 + threadIdx.x;
    if (i >= n8) return;
    const float4* p = (const float4*)in + (size_t)i * 2;
    float4 v0 = p[0], v1 = p[1];
    int4 w;
    w.x = (int)f2b(v0.x) | ((int)f2b(v0.y) << 16);
    w.y = (int)f2b(v0.z) | ((int)f2b(v0.w) << 16);
    w.z = (int)f2b(v1.x) | ((int)f2b(v1.y) << 16);
    w.w = (int)f2b(v1.z) | ((int)f2b(v1.w) << 16);
    *(int4*)(out + (size_t)i * 8) = w;
}

// ---------------------------------------------------------------------------
// transpose-pack fp32 weights into bf16 WT[col][k] (32x32 LDS tiles).
// optional two-source split on k (ksplit) or c (csplit); 0 = disabled.
// out[c][k] = f2b(in[k][c]) with source selection.
// ---------------------------------------------------------------------------
__global__ __launch_bounds__(256)
void k_packT(const float* in1, const float* in2, int ksplit, int csplit,
             int in_ld, u16* __restrict__ out, int ldout)
{
    __shared__ float t[32][33];
    int k0 = blockIdx.y * 32, c0 = blockIdx.x * 32;
    const float* src = in1;
    int kk0 = k0, cc0 = c0;
    if (ksplit > 0 && k0 >= ksplit) { src = in2; kk0 = k0 - ksplit; }
    if (csplit > 0 && c0 >= csplit) { src = in2; cc0 = c0 - csplit; }
    int tid = threadIdx.x;
    int kk = tid >> 3, cc4 = (tid & 7) * 4;
    float4 v = *(const float4*)(src + (size_t)(kk0 + kk) * in_ld + cc0 + cc4);
    t[kk][cc4] = v.x; t[kk][cc4 + 1] = v.y; t[kk][cc4 + 2] = v.z; t[kk][cc4 + 3] = v.w;
    __syncthreads();
    if (tid < 128) {
        int cc = tid >> 2, k8 = (tid & 3) * 8;
        u16 r[8];
        #pragma unroll
        for (int j = 0; j < 8; ++j) r[j] = f2b(t[k8 + j][cc]);
        *(int4*)(out + (size_t)(c0 + cc) * ldout + k0 + k8) = *(int4*)r;
    }
}

// ---------------------------------------------------------------------------
// fp32 row-dot against two fp32 vectors — one wave per row, float4 lanes
// ---------------------------------------------------------------------------
__global__ __launch_bounds__(256)
void k_rowdot2f(const float* __restrict__ A, int ld, int H,
                const float* __restrict__ vs, const float* __restrict__ vd,
                float* a_s, float* a_d, int N)
{
    int wave = threadIdx.x >> 6, lane = threadIdx.x & 63;
    int n = blockIdx.x * 4 + wave;
    if (n >= N) return;
    const float* ar = A + (size_t)n * ld;
    float ss = 0.f, sd = 0.f;
    for (int i = lane * 4; i < H; i += 256) {
        float4 v  = *(const float4*)(ar + i);
        float4 s4 = *(const float4*)(vs + i);
        float4 d4 = *(const float4*)(vd + i);
        ss += v.x * s4.x + v.y * s4.y + v.z * s4.z + v.w * s4.w;
        sd += v.x * d4.x + v.y * d4.y + v.z * d4.z + v.w * d4.w;
    }
    #pragma unroll
    for (int m = 32; m; m >>= 1) {
        ss += __shfl_xor(ss, m, 64);
        sd += __shfl_xor(sd, m, 64);
    }
    if (lane == 0) { a_s[n] = ss; a_d[n] = sd; }
}

// ---------------------------------------------------------------------------
// bf16 row-dot (for layer-2 h2) — one wave per node
// ---------------------------------------------------------------------------
__global__ __launch_bounds__(256)
void k_rowdot2(const u16* h, int ld, int H, const float* vs, const float* vd,
               float* a_s, float* a_d, int N)
{
    int wave = threadIdx.x >> 6, lane = threadIdx.x & 63;
    int n = blockIdx.x * 4 + wave;
    if (n >= N) return;
    const u16* hr = h + (size_t)n * ld;
    float ss = 0.f, sd = 0.f;
    for (int i = lane; i < H; i += 64) {
        float v = b2f(hr[i]);
        ss += v * vs[i];
        sd += v * vd[i];
    }
    #pragma unroll
    for (int m = 32; m; m >>= 1) {
        ss += __shfl_xor(ss, m, 64);
        sd += __shfl_xor(sd, m, 64);
    }
    if (lane == 0) { a_s[n] = ss; a_d[n] = sd; }
}

// ---------------------------------------------------------------------------
// per-dst softmax stats + normalized per-edge alpha (3-pass, wave per node)
// ---------------------------------------------------------------------------
__global__ __launch_bounds__(256)
void k_alpha(const int* __restrict__ off, const int* __restrict__ srcs,
             const float* __restrict__ a_s, const float* __restrict__ a_d,
             float* __restrict__ alpha, int N)
{
    int wave = threadIdx.x >> 6, lane = threadIdx.x & 63;
    int n = blockIdx.x * 4 + wave;
    if (n >= N) return;
    int base = off[n], end = off[n + 1];
    float adn = a_d[n];
    float m = -1e30f;
    for (int p = base + lane; p < end; p += 64) {
        int s = srcs[p];
        s = ((unsigned)s < (unsigned)N) ? s : 0;
        float z = a_s[s] + adn;
        z = z > 0.f ? z : NEG_SLOPE * z;
        m = fmaxf(m, z);
    }
    #pragma unroll
    for (int s = 32; s; s >>= 1) m = fmaxf(m, __shfl_xor(m, s, 64));
    float sum = 0.f;
    for (int p = base + lane; p < end; p += 64) {
        int s = srcs[p];
        s = ((unsigned)s < (unsigned)N) ? s : 0;
        float z = a_s[s] + adn;
        z = z > 0.f ? z : NEG_SLOPE * z;
        sum += __expf(z - m);
    }
    #pragma unroll
    for (int s = 32; s; s >>= 1) sum += __shfl_xor(sum, s, 64);
    float inv = 1.f / (sum + 1e-16f);
    for (int p = base + lane; p < end; p += 64) {
        int s = srcs[p];
        s = ((unsigned)s < (unsigned)N) ? s : 0;
        float z = a_s[s] + adn;
        z = z > 0.f ? z : NEG_SLOPE * z;
        alpha[p] = __expf(z - m) * inv;
    }
}

// ---------------------------------------------------------------------------
// weighted gather-aggregate over 256-ch bf16 rows: one wave per node,
// 8B/lane gathers, precomputed normalized alpha, optional bf16 addend.
// out[n] = sum_e alpha[e] * rows[srcs[e]]  (+ add[n])
// ---------------------------------------------------------------------------
__global__ __launch_bounds__(256)
void k_aggw(const u16* __restrict__ rows, const int* __restrict__ off,
            const int* __restrict__ srcs, const float* __restrict__ alpha,
            const u16* __restrict__ add, u16* __restrict__ out, int N)
{
    int wave = threadIdx.x >> 6, lane = threadIdx.x & 63;
    int n = blockIdx.x * 4 + wave;
    if (n >= N) return;
    int base = off[n], end = off[n + 1];
    int c4 = lane * 4;
    float a0 = 0.f, a1 = 0.f, a2 = 0.f, a3 = 0.f;
    int p = base;
    for (; p + 1 < end; p += 2) {
        int s0 = srcs[p];     s0 = ((unsigned)s0 < (unsigned)N) ? s0 : 0;
        int s1 = srcs[p + 1]; s1 = ((unsigned)s1 < (unsigned)N) ? s1 : 0;
        float w0 = alpha[p], w1 = alpha[p + 1];
        u16x4 v0 = *(const u16x4*)(rows + (size_t)s0 * 256 + c4);
        u16x4 v1 = *(const u16x4*)(rows + (size_t)s1 * 256 + c4);
        a0 += w0 * b2f(v0[0]) + w1 * b2f(v1[0]);
        a1 += w0 * b2f(v0[1]) + w1 * b2f(v1[1]);
        a2 += w0 * b2f(v0[2]) + w1 * b2f(v1[2]);
        a3 += w0 * b2f(v0[3]) + w1 * b2f(v1[3]);
    }
    if (p < end) {
        int s0 = srcs[p]; s0 = ((unsigned)s0 < (unsigned)N) ? s0 : 0;
        float w0 = alpha[p];
        u16x4 v0 = *(const u16x4*)(rows + (size_t)s0 * 256 + c4);
        a0 += w0 * b2f(v0[0]);
        a1 += w0 * b2f(v0[1]);
        a2 += w0 * b2f(v0[2]);
        a3 += w0 * b2f(v0[3]);
    }
    size_t ob = (size_t)n * 256 + c4;
    if (add) {
        a0 += b2f(add[ob]);     a1 += b2f(add[ob + 1]);
        a2 += b2f(add[ob + 2]); a3 += b2f(add[ob + 3]);
    }
    u16x4 o;
    o[0] = f2b(a0); o[1] = f2b(a1); o[2] = f2b(a2); o[3] = f2b(a3);
    *(u16x4*)(out + ob) = o;
}

// ---------------------------------------------------------------------------
// full-width fused MFMA GEMM: BM=64, K=512 (two bf16 A halves of 256 each),
// NC=512 from pre-packed transposed bf16 WT[col][k]. Output split at col 256
// into (C1, C2) with per-half fp32 bias pairs and relu flags. A read ONCE.
// 512 threads = 8 waves: wave = (rowgrp<<1)|colgrp; each wave 16 rows x 256 cols.
// ---------------------------------------------------------------------------
__global__ __launch_bounds__(512)
void bigfull(const u16* __restrict__ A1, int lda1,
             const u16* __restrict__ A2, int lda2,
             const u16* __restrict__ WT,
             const float* b0a, const float* b0b,
             const float* b1a, const float* b1b,
             u16* C1, int ldc1, u16* C2, int ldc2,
             int M, int relu0, int relu1)
{
    __shared__ u16 As[64][40];
    __shared__ u16 Bs[512][40];

    const int tid = threadIdx.x;
    const int wave = tid >> 6, lane = tid & 63;
    const int rowgrp = wave >> 1, colgrp = wave & 1;
    const int m16 = lane & 15, q = lane >> 4;
    const int rowBase = blockIdx.x * 64;

    float4v acc[16] = {};

    for (int k0 = 0; k0 < 512; k0 += 32) {
        __syncthreads();
        if (tid < 256) {   // stage A 64x32 (k-split across A1/A2)
            int ar = tid >> 2, ac = (tid & 3) * 8;
            int grow = rowBase + ar;
            int kk = k0 + ac;
            const u16* src = (kk < 256)
                ? A1 + (size_t)grow * lda1 + kk
                : A2 + (size_t)grow * lda2 + (kk - 256);
            int4 v = {0, 0, 0, 0};
            if (grow < M) v = *(const int4*)src;
            *(int4*)&As[ar][ac] = v;
        }
        {   // stage B 512x32 from WT (pure bf16 copy, b128 writes)
            int c = tid >> 2, j = tid & 3;
            #pragma unroll
            for (int cc = 0; cc < 4; ++cc) {
                int col = c + cc * 128;
                int4 v = *(const int4*)(WT + (size_t)col * 512 + k0 + j * 8);
                *(int4*)&Bs[col][j * 8] = v;
            }
        }
        __syncthreads();

        short8 aF = *(const short8*)&As[rowgrp * 16 + m16][q * 8];
        #pragma unroll
        for (int c = 0; c < 16; ++c) {
            short8 bF = *(const short8*)&Bs[colgrp * 256 + c * 16 + m16][q * 8];
            acc[c] = __builtin_amdgcn_mfma_f32_16x16x32_bf16(aF, bF, acc[c], 0, 0, 0);
        }
    }

    const float* ba = colgrp ? b1a : b0a;
    const float* bb = colgrp ? b1b : b0b;
    u16* C  = colgrp ? C2 : C1;
    int ldc = colgrp ? ldc2 : ldc1;
    int relu = colgrp ? relu1 : relu0;
    #pragma unroll
    for (int c = 0; c < 16; ++c) {
        int lc = c * 16 + m16;
        float bv = (ba ? ba[lc] : 0.f) + (bb ? bb[lc] : 0.f);
        #pragma unroll
        for (int i = 0; i < 4; ++i) {
            int grow = rowBase + rowgrp * 16 + q * 4 + i;
            if (grow < M) {
                float v = acc[c][i] + bv;
                if (relu) v = fmaxf(v, 0.f);
                C[(size_t)grow * ldc + lc] = f2b(v);
            }
        }
    }
}

// ---------------------------------------------------------------------------
// fused 3-layer MLP [256->256] relu, in-place: block owns 64 rows, keeps them
// resident in LDS across layers. WTH = 3 x [256][256] bf16 transposed packs.
// ---------------------------------------------------------------------------
__global__ __launch_bounds__(256)
void k_mlp3(const u16* __restrict__ WTH,
            const float* Hb1, const float* Hb2, const float* Hb3,
            u16* H, int M)
{
    __shared__ u16 As[64][264];   // full 64x256 activation panel (pad to 264)
    __shared__ u16 Bs[256][40];

    const int tid = threadIdx.x;
    const int wave = tid >> 6, lane = tid & 63;
    const int m16 = lane & 15, q = lane >> 4;
    const int rowBase = blockIdx.x * 64;

    for (int idx = tid; idx < 64 * 32; idx += 256) {
        int r = idx >> 5, k8 = (idx & 31) * 8;
        int grow = rowBase + r;
        int4 v = {0, 0, 0, 0};
        if (grow < M) v = *(const int4*)(H + (size_t)grow * 256 + k8);
        *(int4*)&As[r][k8] = v;
    }

    const float* biases[3] = {Hb1, Hb2, Hb3};
    for (int L = 0; L < 3; ++L) {
        const u16* WT = WTH + (size_t)L * 256 * 256;
        float4v acc[16] = {};
        for (int k0 = 0; k0 < 256; k0 += 32) {
            __syncthreads();
            {   // stage Bs 256x32
                int c = tid >> 2, j = tid & 3;
                #pragma unroll
                for (int cc = 0; cc < 4; ++cc) {
                    int col = c + cc * 64;
                    int4 v = *(const int4*)(WT + (size_t)col * 256 + k0 + j * 8);
                    *(int4*)&Bs[col][j * 8] = v;
                }
            }
            __syncthreads();
            short8 aF = *(const short8*)&As[wave * 16 + m16][k0 + q * 8];
            #pragma unroll
            for (int c = 0; c < 16; ++c) {
                short8 bF = *(const short8*)&Bs[c * 16 + m16][q * 8];
                acc[c] = __builtin_amdgcn_mfma_f32_16x16x32_bf16(aF, bF, acc[c], 0, 0, 0);
            }
        }
        const float* bias = biases[L];
        __syncthreads();
        if (L < 2) {
            #pragma unroll
            for (int c = 0; c < 16; ++c) {
                int col = c * 16 + m16;
                float bv = bias[col];
                #pragma unroll
                for (int i = 0; i < 4; ++i) {
                    int r = wave * 16 + q * 4 + i;
                    As[r][col] = f2b(fmaxf(acc[c][i] + bv, 0.f));
                }
            }
        } else {
            #pragma unroll
            for (int c = 0; c < 16; ++c) {
                int col = c * 16 + m16;
                float bv = bias[col];
                #pragma unroll
                for (int i = 0; i < 4; ++i) {
                    int grow = rowBase + wave * 16 + q * 4 + i;
                    if (grow < M)
                        H[(size_t)grow * 256 + col] = f2b(fmaxf(acc[c][i] + bv, 0.f));
                }
            }
        }
    }
}

// ---------------------------------------------------------------------------
// classifier + softmax: one wave per node (4 nodes/block), 256 -> 5, fp32 out
// ---------------------------------------------------------------------------
__global__ __launch_bounds__(256)
void k_fc_softmax(const u16* hin, const float* fcw, const float* fcb,
                  float* out, int N)
{
    int wave = threadIdx.x >> 6, lane = threadIdx.x & 63;
    int n = blockIdx.x * 4 + wave;
    if (n >= N) return;
    const u16* hr = hin + (size_t)n * 256;
    int k0 = lane * 4;
    float hv[4];
    float p[5] = {0.f, 0.f, 0.f, 0.f, 0.f};
    #pragma unroll
    for (int j = 0; j < 4; ++j) hv[j] = b2f(hr[k0 + j]);
    #pragma unroll
    for (int j = 0; j < 4; ++j) {
        const float* wr = fcw + (size_t)(k0 + j) * 5;
        #pragma unroll
        for (int c = 0; c < 5; ++c) p[c] += hv[j] * wr[c];
    }
    #pragma unroll
    for (int c = 0; c < 5; ++c) {
        #pragma unroll
        for (int s = 32; s; s >>= 1) p[c] += __shfl_xor(p[c], s, 64);
    }
    if (lane == 0) {
        float m = -1e30f;
        #pragma unroll
        for (int c = 0; c < 5; ++c) { p[c] += fcb[c]; m = fmaxf(m, p[c]); }
        float s = 0.f, e[5];
        #pragma unroll
        for (int c = 0; c < 5; ++c) { e[c] = __expf(p[c] - m); s += e[c]; }
        float inv = 1.f / s;
        #pragma unroll
        for (int c = 0; c < 5; ++c) out[(size_t)n * 5 + c] = e[c] * inv;
    }
}

// ---------------------------------------------------------------------------
extern "C" void kernel_launch(void* const* d_in, const int* in_sizes, int n_in,
                              void* d_out, int out_size, void* d_ws, size_t ws_size,
                              hipStream_t stream)
{
    const float* x    = (const float*)d_in[0];
    const int*   ei   = (const int*)  d_in[1];
    const float* W1   = (const float*)d_in[2];
    const float* as1  = (const float*)d_in[3];
    const float* ad1  = (const float*)d_in[4];
    const float* bc1  = (const float*)d_in[5];
    const float* A1w  = (const float*)d_in[6];
    const float* b1   = (const float*)d_in[7];
    const float* W2   = (const float*)d_in[8];
    const float* as2  = (const float*)d_in[9];
    const float* ad2  = (const float*)d_in[10];
    const float* bc2  = (const float*)d_in[11];
    const float* A2w  = (const float*)d_in[12];
    const float* b2   = (const float*)d_in[13];
    const float* Hw1  = (const float*)d_in[14];
    const float* Hb1  = (const float*)d_in[15];
    const float* Hw2  = (const float*)d_in[16];
    const float* Hb2  = (const float*)d_in[17];
    const float* Hw3  = (const float*)d_in[18];
    const float* Hb3  = (const float*)d_in[19];
    const float* fcw  = (const float*)d_in[20];
    const float* fcb  = (const float*)d_in[21];
    float* out = (float*)d_out;

    const int D = 256;
    const int N = in_sizes[0] / D;
    const int E = in_sizes[1] / 2;

    char* w = (char*)d_ws;
    auto alloc = [&](size_t bytes) {
        char* p = w;
        w += (bytes + 255) & ~(size_t)255;
        return p;
    };
    int*   flag   = (int*)  alloc(256);
    int*   flag64 = (int*)  alloc(256);
    float* a_s    = (float*)alloc((size_t)N * 4);
    float* a_d    = (float*)alloc((size_t)N * 4);
    float* vs1    = (float*)alloc(1024);                 // W1 @ att_src1  [256]
    float* vd1    = (float*)alloc(1024);                 // W1 @ att_dst1  [256]
    int*   deg    = (int*)  alloc((size_t)N * 4);
    int*   cursor = (int*)  alloc((size_t)N * 4);
    int*   offA   = (int*)  alloc((size_t)(N + 1) * 4);
    int*   part   = (int*)  alloc((size_t)((N + 1023) / 1024 + 1) * 4);
    int*   srcs   = (int*)  alloc((size_t)E * 4);
    float* alpha  = (float*)alloc((size_t)E * 4);        // normalized edge weights
    u16*   WT1    = (u16*)  alloc(512 * 512 * 2);        // [col][k]: k<256 A1w, else W1
    u16*   WT2    = (u16*)  alloc(512 * 512 * 2);        // [col][k]: col<256 W2, else A2w
    u16*   WTH    = (u16*)  alloc(3 * 256 * 256 * 2);    // 3x transposed MLP weights
    u16*   BUF1   = (u16*)  alloc((size_t)N * 512 * 2);  // xb|aggx -> h2|res2
    u16*   BUF2   = (u16*)  alloc((size_t)N * 512 * 2);  // hl1 -> out2/MLP

    // src32/dst32 alias BUF1 (dead before xb is written)
    int* src32 = (int*)BUF1;
    int* dst32 = src32 + E;

    size_t need = (size_t)(w - (char*)d_ws);             // ~112 MB
    if (ws_size < need) {
        float code = 1000.0f + (float)(ws_size >> 20);
        k_diag<<<(out_size + 255) / 256, 256, 0, stream>>>(out, out_size, code);
        return;
    }

    const int EB  = (E + 255) / 256;
    const int NB4 = (N + 3) / 4;
    const int OB  = (out_size + 255) / 256;
    const int NE  = (N > E ? N : E);
    const int RB64 = (N + 63) / 64;
    const int NBLK = (N + 1023) / 1024;
    const size_t NH2 = (size_t)N * 256;
    u16* XB   = BUF1;            // bf16 cast of x      [N,256]
    u16* AGGX = BUF1 + NH2;      // alpha-aggregated x  [N,256]

    hipMemsetAsync(flag, 0, 4, stream);

    // ---- edge extraction + CSR by destination ----
    k_detect <<<1, 256, 0, stream>>>(ei, E, flag64);
    k_extract<<<EB, 256, 0, stream>>>(ei, E, flag64, src32, dst32);
    hipMemsetAsync(deg, 0, (size_t)N * 4, stream);
    k_count  <<<EB, 256, 0, stream>>>(dst32, deg, E, N);
    k_scan_a <<<NBLK, 256, 0, stream>>>(deg, offA, part, N);
    k_scan_b <<<1, 1024, 0, stream>>>(part, NBLK);
    k_scan_c <<<(N + 255) / 256, 256, 0, stream>>>(offA, cursor, part, N, E);
    k_scatter<<<EB, 256, 0, stream>>>(src32, dst32, cursor, srcs, E, N);
    scan_csr <<<(NE + 255) / 256, 256, 0, stream>>>(offA, srcs, N, E, flag, 1);

    // ---- weight pre-pack (transposed bf16) ----
    k_packT<<<dim3(16, 16), 256, 0, stream>>>(A1w, W1, 256, 0, 512, WT1, 512);
    k_packT<<<dim3(16, 16), 256, 0, stream>>>(W2, A2w, 0, 256, 256, WT2, 512);
    k_packT<<<dim3(8, 8),   256, 0, stream>>>(Hw1, nullptr, 0, 0, 256, WTH,               256);
    k_packT<<<dim3(8, 8),   256, 0, stream>>>(Hw2, nullptr, 0, 0, 256, WTH + 256 * 256,   256);
    k_packT<<<dim3(8, 8),   256, 0, stream>>>(Hw3, nullptr, 0, 0, 256, WTH + 2 * 256 * 256, 256);

    // ---- xb = bf16(x) (overwrites src32/dst32 region, already dead) ----
    k_f2b8<<<(N * 32 + 255) / 256, 256, 0, stream>>>(x, XB, N * 32);

    // ---- attention: a_s = x·(W1@att_src1), a_d = x·(W1@att_dst1) ----
    k_rowdot2f<<<64, 256, 0, stream>>>(W1, 512, 512, as1, ad1, vs1, vd1, 256);
    k_rowdot2f<<<NB4, 256, 0, stream>>>(x, 256, 256, vs1, vd1, a_s, a_d, N);
    k_alpha<<<NB4, 256, 0, stream>>>(offA, srcs, a_s, a_d, alpha, N);

    // ---- aggx = sum_e alpha_e * xb[src_e]  (GAT linearity: agg before W1) ----
    k_aggw<<<NB4, 256, 0, stream>>>(XB, offA, srcs, alpha, nullptr, AGGX, N);

    // ---- layer 1 fused: hl1 = relu([XB|AGGX] @ [A1w;W1] + b1 + bc1) ----
    bigfull<<<RB64, 512, 0, stream>>>(XB, 256, AGGX, 256, WT1,
                                      b1, bc1, b1 + 256, bc1 + 256,
                                      BUF2, 512, BUF2 + 256, 512, N, 1, 1);

    // ---- layer 2 fused: [h2 | res2] = hl1 @ [W2 | A2w] (+b2+bc2 on res2) ----
    bigfull<<<RB64, 512, 0, stream>>>(BUF2, 512, BUF2 + 256, 512, WT2,
                                      nullptr, nullptr, b2, bc2,
                                      BUF1, 256, BUF1 + NH2, 256, N, 0, 0);

    k_rowdot2<<<NB4, 256, 0, stream>>>(BUF1, 256, 256, as2, ad2, a_s, a_d, N);
    k_alpha<<<NB4, 256, 0, stream>>>(offA, srcs, a_s, a_d, alpha, N);
    k_aggw<<<NB4, 256, 0, stream>>>(BUF1, offA, srcs, alpha, BUF1 + NH2, BUF2, N);

    // ---- fused 3-layer MLP (in-place in BUF2) ----
    k_mlp3<<<RB64, 256, 0, stream>>>(WTH, Hb1, Hb2, Hb3, BUF2, N);

    // ---- classifier + softmax (fp32 out) ----
    k_fc_softmax<<<NB4, 256, 0, stream>>>(BUF2, fcw, fcb, out, N);

    k_final_diag<<<OB, 256, 0, stream>>>(flag, out, out_size);
}

// Round 4
// 618.013 us; speedup vs baseline: 1.9578x; 1.0729x over previous
//
#include <hip/hip_runtime.h>

typedef unsigned short u16;
typedef short short8 __attribute__((ext_vector_type(8)));
typedef u16 u16x4 __attribute__((ext_vector_type(4)));
typedef float float4v __attribute__((ext_vector_type(4)));

#define NEG_SLOPE 0.2f

static __device__ __forceinline__ float b2f(u16 u) {
    union { unsigned int i; float f; } x; x.i = ((unsigned int)u) << 16; return x.f;
}
static __device__ __forceinline__ u16 f2b(float f) {
    unsigned int u = __float_as_uint(f);
    unsigned int r = (u + 0x7fffu + ((u >> 16) & 1u)) >> 16;
    return (u16)r;
}

// ---------------------------------------------------------------------------
// diagnostics: code 32 = CSR inconsistent; 1000+ = ws too small
// ---------------------------------------------------------------------------
__global__ void k_diag(float* out, int n, float val)
{
    int i = blockIdx.x * 256 + threadIdx.x;
    if (i < n) out[i] = val;
}

__global__ void scan_csr(const int* off, const int* srcs, int N, int E,
                         int* flag, int bit)
{
    int i = blockIdx.x * 256 + threadIdx.x;
    if (i < N) {
        int a = off[i], b = off[i + 1];
        if (a < 0 || b < a || b > E) atomicOr(flag, bit);
    }
    if (i == 0 && off[N] != E) atomicOr(flag, bit);
    if (i < E) {
        if ((unsigned)srcs[i] >= (unsigned)N) atomicOr(flag, bit);
    }
}

__global__ void k_final_diag(const int* flag, float* out, int n)
{
    int f = *flag;
    if (f == 0) return;
    int b = __ffs(f) - 1;
    float val = 32.0f * (b + 1);
    int i = blockIdx.x * 256 + threadIdx.x;
    if (i < n) out[i] = val;
}

// ---------------------------------------------------------------------------
// edge_index dtype probe + canonical int32 extraction
// ---------------------------------------------------------------------------
__global__ void k_detect(const int* ei, int E, int* flag64)
{
    __shared__ int zc;
    if (threadIdx.x == 0) zc = 0;
    __syncthreads();
    int idx = 1 + 2 * (int)threadIdx.x;
    int z = (idx < 2 * E && ei[idx] == 0) ? 1 : 0;
    atomicAdd(&zc, z);
    __syncthreads();
    if (threadIdx.x == 0) *flag64 = (zc >= 200) ? 1 : 0;
}

__global__ void k_extract(const int* ei, int E, const int* flag64,
                          int* src, int* dst)
{
    int e = blockIdx.x * 256 + threadIdx.x;
    if (e >= E) return;
    if (*flag64) {
        src[e] = ei[2 * e];
        dst[e] = ei[2 * E + 2 * e];
    } else {
        src[e] = ei[e];
        dst[e] = ei[E + e];
    }
}

// ---------------------------------------------------------------------------
// CSR construction (bound-checked)
// ---------------------------------------------------------------------------
__global__ void k_count(const int* dst, int* deg, int E, int N)
{
    int e = blockIdx.x * 256 + threadIdx.x;
    if (e < E) {
        int d = dst[e];
        if ((unsigned)d < (unsigned)N) atomicAdd(&deg[d], 1);
    }
}

// ---------------------------------------------------------------------------
// device-wide exclusive scan, 3-phase (1024 elems per block in phase A)
// ---------------------------------------------------------------------------
__global__ __launch_bounds__(256)
void k_scan_a(const int* __restrict__ deg, int* __restrict__ off,
              int* __restrict__ partial, int N)
{
    __shared__ int sd[256];
    int tid = threadIdx.x;
    int base = blockIdx.x * 1024;
    int i0 = base + tid * 4;
    int v0 = 0, v1 = 0, v2 = 0, v3 = 0;
    if (i0 < N)     v0 = deg[i0];
    if (i0 + 1 < N) v1 = deg[i0 + 1];
    if (i0 + 2 < N) v2 = deg[i0 + 2];
    if (i0 + 3 < N) v3 = deg[i0 + 3];
    int t = v0 + v1 + v2 + v3;
    sd[tid] = t;
    __syncthreads();
    #pragma unroll
    for (int s = 1; s < 256; s <<= 1) {
        int u = (tid >= s) ? sd[tid - s] : 0;
        __syncthreads();
        sd[tid] += u;
        __syncthreads();
    }
    int excl = sd[tid] - t;                 // exclusive within block
    if (i0 < N)     off[i0]     = excl;
    if (i0 + 1 < N) off[i0 + 1] = excl + v0;
    if (i0 + 2 < N) off[i0 + 2] = excl + v0 + v1;
    if (i0 + 3 < N) off[i0 + 3] = excl + v0 + v1 + v2;
    if (tid == 255) partial[blockIdx.x] = sd[255];
}

__global__ __launch_bounds__(1024)
void k_scan_b(int* partial, int nblk)
{
    __shared__ int sd[1024];
    __shared__ int running;
    int tid = threadIdx.x;
    if (tid == 0) running = 0;
    __syncthreads();
    for (int base = 0; base < nblk; base += 1024) {
        int i = base + tid;
        int v = (i < nblk) ? partial[i] : 0;
        sd[tid] = v;
        __syncthreads();
        for (int s = 1; s < 1024; s <<= 1) {
            int u = (tid >= s) ? sd[tid - s] : 0;
            __syncthreads();
            sd[tid] += u;
            __syncthreads();
        }
        if (i < nblk) partial[i] = sd[tid] - v + running;   // exclusive
        int total = sd[1023];
        __syncthreads();
        if (tid == 0) running += total;
        __syncthreads();
    }
}

__global__ __launch_bounds__(256)
void k_scan_c(int* __restrict__ off, int* __restrict__ cursor,
              const int* __restrict__ partial, int N, int E)
{
    int i = blockIdx.x * 256 + threadIdx.x;
    if (i < N) {
        int v = off[i] + partial[i >> 10];
        off[i] = v;
        cursor[i] = v;
    }
    if (i == 0) off[N] = E;
}

__global__ void k_scatter(const int* src, const int* dst, int* cursor,
                          int* srcs, int E, int N)
{
    int e = blockIdx.x * 256 + threadIdx.x;
    if (e < E) {
        int d = dst[e];
        if ((unsigned)d < (unsigned)N) {
            int p = atomicAdd(&cursor[d], 1);
            if ((unsigned)p < (unsigned)E) srcs[p] = src[e];
        }
    }
}

// ---------------------------------------------------------------------------
// fp32 -> bf16 bulk cast (8 elems/thread)
// ---------------------------------------------------------------------------
__global__ __launch_bounds__(256)
void k_f2b8(const float* __restrict__ in, u16* __restrict__ out, int n8)
{
    int i = blockIdx.x * 256 + threadIdx.x;
    if (i >= n8) return;
    const float4* p = (const float4*)in + (size_t)i * 2;
    float4 v0 = p[0], v1 = p[1];
    int4 w;
    w.x = (int)f2b(v0.x) | ((int)f2b(v0.y) << 16);
    w.y = (int)f2b(v0.z) | ((int)f2b(v0.w) << 16);
    w.z = (int)f2b(v1.x) | ((int)f2b(v1.y) << 16);
    w.w = (int)f2b(v1.z) | ((int)f2b(v1.w) << 16);
    *(int4*)(out + (size_t)i * 8) = w;
}

// ---------------------------------------------------------------------------
// fragment-major weight pack: out[(kt*NC16 + cf)*512 + l*8 + j] =
//   bf16( W[k = kt*32 + (l>>4)*8 + j][col = cf*16 + (l&15)] )
// i.e. exactly the MFMA B-operand layout, 1 KB per (ktile, colfrag).
// Optional two-source split on k (ksplit) or col (csplit); 0 = disabled.
// ---------------------------------------------------------------------------
__global__ __launch_bounds__(64)
void k_packF(const float* in1, const float* in2, int ksplit, int csplit,
             int in_ld, u16* __restrict__ out)
{
    int l = threadIdx.x;
    int cf = blockIdx.x, kt = blockIdx.y, NC16 = gridDim.x;
    int col = cf * 16 + (l & 15);
    int kbase = kt * 32 + (l >> 4) * 8;
    const float* src = in1;
    int cc = col, koff = 0;
    if (ksplit > 0 && kbase >= ksplit) { src = in2; koff = ksplit; }
    if (csplit > 0 && col >= csplit)   { src = in2; cc = col - csplit; }
    u16* o = out + ((size_t)(kt * NC16 + cf) * 512) + l * 8;
    #pragma unroll
    for (int j = 0; j < 8; ++j)
        o[j] = f2b(src[(size_t)(kbase - koff + j) * in_ld + cc]);
}

// ---------------------------------------------------------------------------
// fp32 row-dot against two fp32 vectors — one wave per row, float4 lanes
// ---------------------------------------------------------------------------
__global__ __launch_bounds__(256)
void k_rowdot2f(const float* __restrict__ A, int ld, int H,
                const float* __restrict__ vs, const float* __restrict__ vd,
                float* a_s, float* a_d, int N)
{
    int wave = threadIdx.x >> 6, lane = threadIdx.x & 63;
    int n = blockIdx.x * 4 + wave;
    if (n >= N) return;
    const float* ar = A + (size_t)n * ld;
    float ss = 0.f, sd = 0.f;
    for (int i = lane * 4; i < H; i += 256) {
        float4 v  = *(const float4*)(ar + i);
        float4 s4 = *(const float4*)(vs + i);
        float4 d4 = *(const float4*)(vd + i);
        ss += v.x * s4.x + v.y * s4.y + v.z * s4.z + v.w * s4.w;
        sd += v.x * d4.x + v.y * d4.y + v.z * d4.z + v.w * d4.w;
    }
    #pragma unroll
    for (int m = 32; m; m >>= 1) {
        ss += __shfl_xor(ss, m, 64);
        sd += __shfl_xor(sd, m, 64);
    }
    if (lane == 0) { a_s[n] = ss; a_d[n] = sd; }
}

// ---------------------------------------------------------------------------
// bf16 row-dot (for layer-2 h2) — one wave per node
// ---------------------------------------------------------------------------
__global__ __launch_bounds__(256)
void k_rowdot2(const u16* h, int ld, int H, const float* vs, const float* vd,
               float* a_s, float* a_d, int N)
{
    int wave = threadIdx.x >> 6, lane = threadIdx.x & 63;
    int n = blockIdx.x * 4 + wave;
    if (n >= N) return;
    const u16* hr = h + (size_t)n * ld;
    float ss = 0.f, sd = 0.f;
    for (int i = lane; i < H; i += 64) {
        float v = b2f(hr[i]);
        ss += v * vs[i];
        sd += v * vd[i];
    }
    #pragma unroll
    for (int m = 32; m; m >>= 1) {
        ss += __shfl_xor(ss, m, 64);
        sd += __shfl_xor(sd, m, 64);
    }
    if (lane == 0) { a_s[n] = ss; a_d[n] = sd; }
}

// ---------------------------------------------------------------------------
// per-dst softmax stats + normalized per-edge alpha (3-pass, wave per node)
// ---------------------------------------------------------------------------
__global__ __launch_bounds__(256)
void k_alpha(const int* __restrict__ off, const int* __restrict__ srcs,
             const float* __restrict__ a_s, const float* __restrict__ a_d,
             float* __restrict__ alpha, int N)
{
    int wave = threadIdx.x >> 6, lane = threadIdx.x & 63;
    int n = blockIdx.x * 4 + wave;
    if (n >= N) return;
    int base = off[n], end = off[n + 1];
    float adn = a_d[n];
    float m = -1e30f;
    for (int p = base + lane; p < end; p += 64) {
        int s = srcs[p];
        s = ((unsigned)s < (unsigned)N) ? s : 0;
        float z = a_s[s] + adn;
        z = z > 0.f ? z : NEG_SLOPE * z;
        m = fmaxf(m, z);
    }
    #pragma unroll
    for (int s = 32; s; s >>= 1) m = fmaxf(m, __shfl_xor(m, s, 64));
    float sum = 0.f;
    for (int p = base + lane; p < end; p += 64) {
        int s = srcs[p];
        s = ((unsigned)s < (unsigned)N) ? s : 0;
        float z = a_s[s] + adn;
        z = z > 0.f ? z : NEG_SLOPE * z;
        sum += __expf(z - m);
    }
    #pragma unroll
    for (int s = 32; s; s >>= 1) sum += __shfl_xor(sum, s, 64);
    float inv = 1.f / (sum + 1e-16f);
    for (int p = base + lane; p < end; p += 64) {
        int s = srcs[p];
        s = ((unsigned)s < (unsigned)N) ? s : 0;
        float z = a_s[s] + adn;
        z = z > 0.f ? z : NEG_SLOPE * z;
        alpha[p] = __expf(z - m) * inv;
    }
}

// ---------------------------------------------------------------------------
// weighted gather-aggregate over 256-ch bf16 rows: one wave per node,
// 8B/lane gathers, precomputed normalized alpha, optional bf16 addend.
// out[n] = sum_e alpha[e] * rows[srcs[e]]  (+ add[n])
// ---------------------------------------------------------------------------
__global__ __launch_bounds__(256)
void k_aggw(const u16* __restrict__ rows, const int* __restrict__ off,
            const int* __restrict__ srcs, const float* __restrict__ alpha,
            const u16* __restrict__ add, u16* __restrict__ out, int N)
{
    int wave = threadIdx.x >> 6, lane = threadIdx.x & 63;
    int n = blockIdx.x * 4 + wave;
    if (n >= N) return;
    int base = off[n], end = off[n + 1];
    int c4 = lane * 4;
    float a0 = 0.f, a1 = 0.f, a2 = 0.f, a3 = 0.f;
    int p = base;
    for (; p + 1 < end; p += 2) {
        int s0 = srcs[p];     s0 = ((unsigned)s0 < (unsigned)N) ? s0 : 0;
        int s1 = srcs[p + 1]; s1 = ((unsigned)s1 < (unsigned)N) ? s1 : 0;
        float w0 = alpha[p], w1 = alpha[p + 1];
        u16x4 v0 = *(const u16x4*)(rows + (size_t)s0 * 256 + c4);
        u16x4 v1 = *(const u16x4*)(rows + (size_t)s1 * 256 + c4);
        a0 += w0 * b2f(v0[0]) + w1 * b2f(v1[0]);
        a1 += w0 * b2f(v0[1]) + w1 * b2f(v1[1]);
        a2 += w0 * b2f(v0[2]) + w1 * b2f(v1[2]);
        a3 += w0 * b2f(v0[3]) + w1 * b2f(v1[3]);
    }
    if (p < end) {
        int s0 = srcs[p]; s0 = ((unsigned)s0 < (unsigned)N) ? s0 : 0;
        float w0 = alpha[p];
        u16x4 v0 = *(const u16x4*)(rows + (size_t)s0 * 256 + c4);
        a0 += w0 * b2f(v0[0]);
        a1 += w0 * b2f(v0[1]);
        a2 += w0 * b2f(v0[2]);
        a3 += w0 * b2f(v0[3]);
    }
    size_t ob = (size_t)n * 256 + c4;
    if (add) {
        a0 += b2f(add[ob]);     a1 += b2f(add[ob + 1]);
        a2 += b2f(add[ob + 2]); a3 += b2f(add[ob + 3]);
    }
    u16x4 o;
    o[0] = f2b(a0); o[1] = f2b(a1); o[2] = f2b(a2); o[3] = f2b(a3);
    *(u16x4*)(out + ob) = o;
}

// ---------------------------------------------------------------------------
// full-width fused MFMA GEMM: BM=64, K=512 (two bf16 A halves of 256 each),
// NC=512 from fragment-major pre-packed WTf. Output split at col 256 into
// (C1, C2) with per-half fp32 bias pairs and relu flags. A read ONCE from HBM.
// 8 waves, each owns a 64x64 tile (all rows x its 4 col-frags):
// per K-step = 4 A-frags + 4 B-frags per 16 MFMAs; all LDS reads are
// base + lane*16 (conflict-free); staging is linear int4 copy.
// ---------------------------------------------------------------------------
__global__ __launch_bounds__(512)
void bigfull(const u16* __restrict__ A1, int lda1,
             const u16* __restrict__ A2, int lda2,
             const u16* __restrict__ WTf,
             const float* b0a, const float* b0b,
             const float* b1a, const float* b1b,
             u16* C1, int ldc1, u16* C2, int ldc2,
             int M, int relu0, int relu1)
{
    __shared__ u16 As[64 * 32];      // frag-major: [rf][lane][8]   (4 KB)
    __shared__ u16 Bs[512 * 32];     // frag-major: [cf][lane][8]  (32 KB)

    const int tid = threadIdx.x;
    const int w = tid >> 6, lane = tid & 63;
    const int m16 = lane & 15, q = lane >> 4;
    const int rowBase = blockIdx.x * 64;

    float4v acc[16] = {};

    for (int k0 = 0; k0 < 512; k0 += 32) {
        const int kt = k0 >> 5;
        __syncthreads();
        if (tid < 256) {   // stage A 64x32 into fragment order
            int rf = tid >> 6, al = tid & 63;
            int grow = rowBase + rf * 16 + (al & 15);
            if (grow >= M) grow = M - 1;          // clamp; value unused
            int kk = k0 + (al >> 4) * 8;
            const u16* src = (kk < 256)
                ? A1 + (size_t)grow * lda1 + kk
                : A2 + (size_t)grow * lda2 + (kk - 256);
            *(int4*)&As[tid * 8] = *(const int4*)src;
        }
        {   // stage B 512x32: pure linear copy of pre-packed fragments
            const u16* wsrc = WTf + (size_t)kt * 16384;
            #pragma unroll
            for (int p = 0; p < 4; ++p) {
                int ch = p * 512 + tid;
                *(int4*)&Bs[ch * 8] = *(const int4*)(wsrc + (size_t)ch * 8);
            }
        }
        __syncthreads();

        short8 a[4], b[4];
        #pragma unroll
        for (int r = 0; r < 4; ++r)
            a[r] = *(const short8*)&As[r * 512 + lane * 8];
        #pragma unroll
        for (int c = 0; c < 4; ++c)
            b[c] = *(const short8*)&Bs[(w * 4 + c) * 512 + lane * 8];
        #pragma unroll
        for (int r = 0; r < 4; ++r)
            #pragma unroll
            for (int c = 0; c < 4; ++c)
                acc[r * 4 + c] = __builtin_amdgcn_mfma_f32_16x16x32_bf16(
                    a[r], b[c], acc[r * 4 + c], 0, 0, 0);
    }

    const int colgrp = w >> 2;
    const float* ba = colgrp ? b1a : b0a;
    const float* bb = colgrp ? b1b : b0b;
    u16* C  = colgrp ? C2 : C1;
    const int ldc  = colgrp ? ldc2 : ldc1;
    const int relu = colgrp ? relu1 : relu0;
    #pragma unroll
    for (int c = 0; c < 4; ++c) {
        int lc = ((w & 3) * 4 + c) * 16 + m16;
        float bv = (ba ? ba[lc] : 0.f) + (bb ? bb[lc] : 0.f);
        #pragma unroll
        for (int r = 0; r < 4; ++r)
            #pragma unroll
            for (int i = 0; i < 4; ++i) {
                int grow = rowBase + r * 16 + q * 4 + i;
                if (grow < M) {
                    float v = acc[r * 4 + c][i] + bv;
                    if (relu) v = fmaxf(v, 0.f);
                    C[(size_t)grow * ldc + lc] = f2b(v);
                }
            }
    }
}

// ---------------------------------------------------------------------------
// fused 3-layer MLP [256->256] relu, in-place: block owns 64 rows kept in a
// fragment-major LDS panel across layers; 4 waves each own 64x64.
// WTHf = 3 x fragment-major [256][256] packs.
// ---------------------------------------------------------------------------
__global__ __launch_bounds__(256)
void k_mlp3(const u16* __restrict__ WTHf,
            const float* Hb1, const float* Hb2, const float* Hb3,
            u16* H, int M)
{
    __shared__ u16 P[64 * 256];     // frag-major activation panel (32 KB)
    __shared__ u16 Bs[256 * 32];    // frag-major B K-slice        (16 KB)

    const int tid = threadIdx.x;
    const int w = tid >> 6, lane = tid & 63;
    const int m16 = lane & 15, q = lane >> 4;
    const int rowBase = blockIdx.x * 64;

    // load panel (global row-major -> fragment-major)
    #pragma unroll
    for (int p = 0; p < 8; ++p) {
        int ch = p * 256 + tid;          // 0..2047 16B-chunks
        int f = ch >> 6, l = ch & 63;    // frag f = kt*4+rf, lane-slot l
        int kt = f >> 2, rf = f & 3;
        int grow = rowBase + rf * 16 + (l & 15);
        if (grow >= M) grow = M - 1;
        int col = kt * 32 + (l >> 4) * 8;
        *(int4*)&P[ch * 8] = *(const int4*)(H + (size_t)grow * 256 + col);
    }

    const float* biases[3] = {Hb1, Hb2, Hb3};
    for (int L = 0; L < 3; ++L) {
        const u16* WTf = WTHf + (size_t)L * 65536;
        float4v acc[16] = {};
        for (int kt = 0; kt < 8; ++kt) {
            __syncthreads();
            {   // stage B 256x32: linear copy
                const u16* wsrc = WTf + (size_t)kt * 8192;
                #pragma unroll
                for (int p = 0; p < 4; ++p) {
                    int ch = p * 256 + tid;
                    *(int4*)&Bs[ch * 8] = *(const int4*)(wsrc + (size_t)ch * 8);
                }
            }
            __syncthreads();
            short8 a[4], b[4];
            #pragma unroll
            for (int r = 0; r < 4; ++r)
                a[r] = *(const short8*)&P[(kt * 4 + r) * 512 + lane * 8];
            #pragma unroll
            for (int c = 0; c < 4; ++c)
                b[c] = *(const short8*)&Bs[(w * 4 + c) * 512 + lane * 8];
            #pragma unroll
            for (int r = 0; r < 4; ++r)
                #pragma unroll
                for (int c = 0; c < 4; ++c)
                    acc[r * 4 + c] = __builtin_amdgcn_mfma_f32_16x16x32_bf16(
                        a[r], b[c], acc[r * 4 + c], 0, 0, 0);
        }
        const float* bias = biases[L];
        __syncthreads();    // all panel reads done before overwrite
        if (L < 2) {
            // writeback into fragment-major panel (out col -> next-layer k)
            #pragma unroll
            for (int c = 0; c < 4; ++c) {
                int col = w * 64 + c * 16 + m16;
                float bv = bias[col];
                int kt2 = col >> 5;
                int l2h = 16 * ((col & 31) >> 3);
                int j2 = col & 7;
                #pragma unroll
                for (int r = 0; r < 4; ++r)
                    #pragma unroll
                    for (int i = 0; i < 4; ++i) {
                        int l2 = (q * 4 + i) + l2h;
                        P[(size_t)(kt2 * 4 + r) * 512 + l2 * 8 + j2] =
                            f2b(fmaxf(acc[r * 4 + c][i] + bv, 0.f));
                    }
            }
        } else {
            #pragma unroll
            for (int c = 0; c < 4; ++c) {
                int col = w * 64 + c * 16 + m16;
                float bv = bias[col];
                #pragma unroll
                for (int r = 0; r < 4; ++r)
                    #pragma unroll
                    for (int i = 0; i < 4; ++i) {
                        int grow = rowBase + r * 16 + q * 4 + i;
                        if (grow < M)
                            H[(size_t)grow * 256 + col] =
                                f2b(fmaxf(acc[r * 4 + c][i] + bv, 0.f));
                    }
            }
        }
    }
}

// ---------------------------------------------------------------------------
// classifier + softmax: one wave per node (4 nodes/block), 256 -> 5, fp32 out
// ---------------------------------------------------------------------------
__global__ __launch_bounds__(256)
void k_fc_softmax(const u16* hin, const float* fcw, const float* fcb,
                  float* out, int N)
{
    int wave = threadIdx.x >> 6, lane = threadIdx.x & 63;
    int n = blockIdx.x * 4 + wave;
    if (n >= N) return;
    const u16* hr = hin + (size_t)n * 256;
    int k0 = lane * 4;
    float hv[4];
    float p[5] = {0.f, 0.f, 0.f, 0.f, 0.f};
    #pragma unroll
    for (int j = 0; j < 4; ++j) hv[j] = b2f(hr[k0 + j]);
    #pragma unroll
    for (int j = 0; j < 4; ++j) {
        const float* wr = fcw + (size_t)(k0 + j) * 5;
        #pragma unroll
        for (int c = 0; c < 5; ++c) p[c] += hv[j] * wr[c];
    }
    #pragma unroll
    for (int c = 0; c < 5; ++c) {
        #pragma unroll
        for (int s = 32; s; s >>= 1) p[c] += __shfl_xor(p[c], s, 64);
    }
    if (lane == 0) {
        float m = -1e30f;
        #pragma unroll
        for (int c = 0; c < 5; ++c) { p[c] += fcb[c]; m = fmaxf(m, p[c]); }
        float s = 0.f, e[5];
        #pragma unroll
        for (int c = 0; c < 5; ++c) { e[c] = __expf(p[c] - m); s += e[c]; }
        float inv = 1.f / s;
        #pragma unroll
        for (int c = 0; c < 5; ++c) out[(size_t)n * 5 + c] = e[c] * inv;
    }
}

// ---------------------------------------------------------------------------
extern "C" void kernel_launch(void* const* d_in, const int* in_sizes, int n_in,
                              void* d_out, int out_size, void* d_ws, size_t ws_size,
                              hipStream_t stream)
{
    const float* x    = (const float*)d_in[0];
    const int*   ei   = (const int*)  d_in[1];
    const float* W1   = (const float*)d_in[2];
    const float* as1  = (const float*)d_in[3];
    const float* ad1  = (const float*)d_in[4];
    const float* bc1  = (const float*)d_in[5];
    const float* A1w  = (const float*)d_in[6];
    const float* b1   = (const float*)d_in[7];
    const float* W2   = (const float*)d_in[8];
    const float* as2  = (const float*)d_in[9];
    const float* ad2  = (const float*)d_in[10];
    const float* bc2  = (const float*)d_in[11];
    const float* A2w  = (const float*)d_in[12];
    const float* b2   = (const float*)d_in[13];
    const float* Hw1  = (const float*)d_in[14];
    const float* Hb1  = (const float*)d_in[15];
    const float* Hw2  = (const float*)d_in[16];
    const float* Hb2  = (const float*)d_in[17];
    const float* Hw3  = (const float*)d_in[18];
    const float* Hb3  = (const float*)d_in[19];
    const float* fcw  = (const float*)d_in[20];
    const float* fcb  = (const float*)d_in[21];
    float* out = (float*)d_out;

    const int D = 256;
    const int N = in_sizes[0] / D;
    const int E = in_sizes[1] / 2;

    char* w = (char*)d_ws;
    auto alloc = [&](size_t bytes) {
        char* p = w;
        w += (bytes + 255) & ~(size_t)255;
        return p;
    };
    int*   flag   = (int*)  alloc(256);
    int*   flag64 = (int*)  alloc(256);
    float* a_s    = (float*)alloc((size_t)N * 4);
    float* a_d    = (float*)alloc((size_t)N * 4);
    float* vs1    = (float*)alloc(1024);                 // W1 @ att_src1  [256]
    float* vd1    = (float*)alloc(1024);                 // W1 @ att_dst1  [256]
    int*   deg    = (int*)  alloc((size_t)N * 4);
    int*   cursor = (int*)  alloc((size_t)N * 4);
    int*   offA   = (int*)  alloc((size_t)(N + 1) * 4);
    int*   part   = (int*)  alloc((size_t)((N + 1023) / 1024 + 1) * 4);
    int*   srcs   = (int*)  alloc((size_t)E * 4);
    float* alpha  = (float*)alloc((size_t)E * 4);        // normalized edge weights
    u16*   WT1    = (u16*)  alloc(512 * 512 * 2);        // frag-major [A1w;W1]
    u16*   WT2    = (u16*)  alloc(512 * 512 * 2);        // frag-major [W2|A2w]
    u16*   WTH    = (u16*)  alloc(3 * 256 * 256 * 2);    // frag-major MLP weights
    u16*   BUF1   = (u16*)  alloc((size_t)N * 512 * 2);  // xb|aggx -> h2|res2
    u16*   BUF2   = (u16*)  alloc((size_t)N * 512 * 2);  // hl1 -> out2/MLP

    // src32/dst32 alias BUF1 (dead before xb is written)
    int* src32 = (int*)BUF1;
    int* dst32 = src32 + E;

    size_t need = (size_t)(w - (char*)d_ws);             // ~112 MB
    if (ws_size < need) {
        float code = 1000.0f + (float)(ws_size >> 20);
        k_diag<<<(out_size + 255) / 256, 256, 0, stream>>>(out, out_size, code);
        return;
    }

    const int EB  = (E + 255) / 256;
    const int NB4 = (N + 3) / 4;
    const int OB  = (out_size + 255) / 256;
    const int NE  = (N > E ? N : E);
    const int RB64 = (N + 63) / 64;
    const int NBLK = (N + 1023) / 1024;
    const size_t NH2 = (size_t)N * 256;
    u16* XB   = BUF1;            // bf16 cast of x      [N,256]
    u16* AGGX = BUF1 + NH2;      // alpha-aggregated x  [N,256]

    hipMemsetAsync(flag, 0, 4, stream);

    // ---- edge extraction + CSR by destination ----
    k_detect <<<1, 256, 0, stream>>>(ei, E, flag64);
    k_extract<<<EB, 256, 0, stream>>>(ei, E, flag64, src32, dst32);
    hipMemsetAsync(deg, 0, (size_t)N * 4, stream);
    k_count  <<<EB, 256, 0, stream>>>(dst32, deg, E, N);
    k_scan_a <<<NBLK, 256, 0, stream>>>(deg, offA, part, N);
    k_scan_b <<<1, 1024, 0, stream>>>(part, NBLK);
    k_scan_c <<<(N + 255) / 256, 256, 0, stream>>>(offA, cursor, part, N, E);
    k_scatter<<<EB, 256, 0, stream>>>(src32, dst32, cursor, srcs, E, N);
    scan_csr <<<(NE + 255) / 256, 256, 0, stream>>>(offA, srcs, N, E, flag, 1);

    // ---- weight pre-pack (fragment-major bf16) ----
    k_packF<<<dim3(32, 16), 64, 0, stream>>>(A1w, W1, 256, 0, 512, WT1);
    k_packF<<<dim3(32, 16), 64, 0, stream>>>(W2, A2w, 0, 256, 256, WT2);
    k_packF<<<dim3(16, 8),  64, 0, stream>>>(Hw1, nullptr, 0, 0, 256, WTH);
    k_packF<<<dim3(16, 8),  64, 0, stream>>>(Hw2, nullptr, 0, 0, 256, WTH + 65536);
    k_packF<<<dim3(16, 8),  64, 0, stream>>>(Hw3, nullptr, 0, 0, 256, WTH + 131072);

    // ---- xb = bf16(x) (overwrites src32/dst32 region, already dead) ----
    k_f2b8<<<(N * 32 + 255) / 256, 256, 0, stream>>>(x, XB, N * 32);

    // ---- attention: a_s = x·(W1@att_src1), a_d = x·(W1@att_dst1) ----
    k_rowdot2f<<<64, 256, 0, stream>>>(W1, 512, 512, as1, ad1, vs1, vd1, 256);
    k_rowdot2f<<<NB4, 256, 0, stream>>>(x, 256, 256, vs1, vd1, a_s, a_d, N);
    k_alpha<<<NB4, 256, 0, stream>>>(offA, srcs, a_s, a_d, alpha, N);

    // ---- aggx = sum_e alpha_e * xb[src_e]  (GAT linearity: agg before W1) ----
    k_aggw<<<NB4, 256, 0, stream>>>(XB, offA, srcs, alpha, nullptr, AGGX, N);

    // ---- layer 1 fused: hl1 = relu([XB|AGGX] @ [A1w;W1] + b1 + bc1) ----
    bigfull<<<RB64, 512, 0, stream>>>(XB, 256, AGGX, 256, WT1,
                                      b1, bc1, b1 + 256, bc1 + 256,
                                      BUF2, 512, BUF2 + 256, 512, N, 1, 1);

    // ---- layer 2 fused: [h2 | res2] = hl1 @ [W2 | A2w] (+b2+bc2 on res2) ----
    bigfull<<<RB64, 512, 0, stream>>>(BUF2, 512, BUF2 + 256, 512, WT2,
                                      nullptr, nullptr, b2, bc2,
                                      BUF1, 256, BUF1 + NH2, 256, N, 0, 0);

    k_rowdot2<<<NB4, 256, 0, stream>>>(BUF1, 256, 256, as2, ad2, a_s, a_d, N);
    k_alpha<<<NB4, 256, 0, stream>>>(offA, srcs, a_s, a_d, alpha, N);
    k_aggw<<<NB4, 256, 0, stream>>>(BUF1, offA, srcs, alpha, BUF1 + NH2, BUF2, N);

    // ---- fused 3-layer MLP (in-place in BUF2) ----
    k_mlp3<<<RB64, 256, 0, stream>>>(WTH, Hb1, Hb2, Hb3, BUF2, N);

    // ---- classifier + softmax (fp32 out) ----
    k_fc_softmax<<<NB4, 256, 0, stream>>>(BUF2, fcw, fcb, out, N);

    k_final_diag<<<OB, 256, 0, stream>>>(flag, out, out_size);
}

// Round 5
// 587.068 us; speedup vs baseline: 2.0610x; 1.0527x over previous
//
#include <hip/hip_runtime.h>

typedef unsigned short u16;
typedef short short8 __attribute__((ext_vector_type(8)));
typedef u16 u16x4 __attribute__((ext_vector_type(4)));
typedef u16 u16x8 __attribute__((ext_vector_type(8)));
typedef float float4v __attribute__((ext_vector_type(4)));

#define NEG_SLOPE 0.2f

static __device__ __forceinline__ float b2f(u16 u) {
    union { unsigned int i; float f; } x; x.i = ((unsigned int)u) << 16; return x.f;
}
static __device__ __forceinline__ u16 f2b(float f) {
    unsigned int u = __float_as_uint(f);
    unsigned int r = (u + 0x7fffu + ((u >> 16) & 1u)) >> 16;
    return (u16)r;
}

// ---------------------------------------------------------------------------
// diagnostics: code 32 = CSR inconsistent; 1000+ = ws too small
// ---------------------------------------------------------------------------
__global__ void k_diag(float* out, int n, float val)
{
    int i = blockIdx.x * 256 + threadIdx.x;
    if (i < n) out[i] = val;
}

__global__ void scan_csr(const int* off, const int* srcs, int N, int E,
                         int* flag, int bit)
{
    int i = blockIdx.x * 256 + threadIdx.x;
    if (i < N) {
        int a = off[i], b = off[i + 1];
        if (a < 0 || b < a || b > E) atomicOr(flag, bit);
    }
    if (i == 0 && off[N] != E) atomicOr(flag, bit);
    if (i < E) {
        if ((unsigned)srcs[i] >= (unsigned)N) atomicOr(flag, bit);
    }
}

__global__ void k_final_diag(const int* flag, float* out, int n)
{
    int f = *flag;
    if (f == 0) return;
    int b = __ffs(f) - 1;
    float val = 32.0f * (b + 1);
    int i = blockIdx.x * 256 + threadIdx.x;
    if (i < n) out[i] = val;
}

// ---------------------------------------------------------------------------
// edge_index dtype probe + canonical int32 extraction (+ degree count fused)
// ---------------------------------------------------------------------------
__global__ void k_detect(const int* ei, int E, int* flag64)
{
    __shared__ int zc;
    if (threadIdx.x == 0) zc = 0;
    __syncthreads();
    int idx = 1 + 2 * (int)threadIdx.x;
    int z = (idx < 2 * E && ei[idx] == 0) ? 1 : 0;
    atomicAdd(&zc, z);
    __syncthreads();
    if (threadIdx.x == 0) *flag64 = (zc >= 200) ? 1 : 0;
}

__global__ void k_extract(const int* ei, int E, const int* flag64,
                          int* src, int* dst, int* deg, int N)
{
    int e = blockIdx.x * 256 + threadIdx.x;
    if (e >= E) return;
    int s, d;
    if (*flag64) {
        s = ei[2 * e];
        d = ei[2 * E + 2 * e];
    } else {
        s = ei[e];
        d = ei[E + e];
    }
    src[e] = s; dst[e] = d;
    if ((unsigned)d < (unsigned)N) atomicAdd(&deg[d], 1);
}

// ---------------------------------------------------------------------------
// device-wide exclusive scan, 3-phase (1024 elems per block in phase A)
// ---------------------------------------------------------------------------
__global__ __launch_bounds__(256)
void k_scan_a(const int* __restrict__ deg, int* __restrict__ off,
              int* __restrict__ partial, int N)
{
    __shared__ int sd[256];
    int tid = threadIdx.x;
    int base = blockIdx.x * 1024;
    int i0 = base + tid * 4;
    int v0 = 0, v1 = 0, v2 = 0, v3 = 0;
    if (i0 < N)     v0 = deg[i0];
    if (i0 + 1 < N) v1 = deg[i0 + 1];
    if (i0 + 2 < N) v2 = deg[i0 + 2];
    if (i0 + 3 < N) v3 = deg[i0 + 3];
    int t = v0 + v1 + v2 + v3;
    sd[tid] = t;
    __syncthreads();
    #pragma unroll
    for (int s = 1; s < 256; s <<= 1) {
        int u = (tid >= s) ? sd[tid - s] : 0;
        __syncthreads();
        sd[tid] += u;
        __syncthreads();
    }
    int excl = sd[tid] - t;                 // exclusive within block
    if (i0 < N)     off[i0]     = excl;
    if (i0 + 1 < N) off[i0 + 1] = excl + v0;
    if (i0 + 2 < N) off[i0 + 2] = excl + v0 + v1;
    if (i0 + 3 < N) off[i0 + 3] = excl + v0 + v1 + v2;
    if (tid == 255) partial[blockIdx.x] = sd[255];
}

__global__ __launch_bounds__(1024)
void k_scan_b(int* partial, int nblk)
{
    __shared__ int sd[1024];
    __shared__ int running;
    int tid = threadIdx.x;
    if (tid == 0) running = 0;
    __syncthreads();
    for (int base = 0; base < nblk; base += 1024) {
        int i = base + tid;
        int v = (i < nblk) ? partial[i] : 0;
        sd[tid] = v;
        __syncthreads();
        for (int s = 1; s < 1024; s <<= 1) {
            int u = (tid >= s) ? sd[tid - s] : 0;
            __syncthreads();
            sd[tid] += u;
            __syncthreads();
        }
        if (i < nblk) partial[i] = sd[tid] - v + running;   // exclusive
        int total = sd[1023];
        __syncthreads();
        if (tid == 0) running += total;
        __syncthreads();
    }
}

__global__ __launch_bounds__(256)
void k_scan_c(int* __restrict__ off, int* __restrict__ cursor,
              const int* __restrict__ partial, int N, int E)
{
    int i = blockIdx.x * 256 + threadIdx.x;
    if (i < N) {
        int v = off[i] + partial[i >> 10];
        off[i] = v;
        cursor[i] = v;
    }
    if (i == 0) off[N] = E;
}

__global__ void k_scatter(const int* src, const int* dst, int* cursor,
                          int* srcs, int E, int N)
{
    int e = blockIdx.x * 256 + threadIdx.x;
    if (e < E) {
        int d = dst[e];
        if ((unsigned)d < (unsigned)N) {
            int p = atomicAdd(&cursor[d], 1);
            if ((unsigned)p < (unsigned)E) srcs[p] = src[e];
        }
    }
}

// ---------------------------------------------------------------------------
// fused fp32->bf16 cast + row dots vs (vs,vd): 8 rows/block, 32 lanes/row.
// Writes xb (bf16) and a_s/a_d per row.
// ---------------------------------------------------------------------------
__global__ __launch_bounds__(256)
void k_castdot(const float* __restrict__ x, const float* __restrict__ vs,
               const float* __restrict__ vd, u16* __restrict__ xb,
               float* __restrict__ a_s, float* __restrict__ a_d, int N)
{
    int tid = threadIdx.x;
    int rowb = tid >> 5;                // 0..7
    int col8 = (tid & 31) * 8;
    int n = blockIdx.x * 8 + rowb;
    if (n >= N) return;
    const float* xr = x + (size_t)n * 256 + col8;
    float4 v0 = *(const float4*)xr;
    float4 v1 = *(const float4*)(xr + 4);
    int4 w;
    w.x = (int)f2b(v0.x) | ((int)f2b(v0.y) << 16);
    w.y = (int)f2b(v0.z) | ((int)f2b(v0.w) << 16);
    w.z = (int)f2b(v1.x) | ((int)f2b(v1.y) << 16);
    w.w = (int)f2b(v1.z) | ((int)f2b(v1.w) << 16);
    *(int4*)(xb + (size_t)n * 256 + col8) = w;

    float4 s0 = *(const float4*)(vs + col8);
    float4 s1 = *(const float4*)(vs + col8 + 4);
    float4 d0 = *(const float4*)(vd + col8);
    float4 d1 = *(const float4*)(vd + col8 + 4);
    float ss = v0.x*s0.x + v0.y*s0.y + v0.z*s0.z + v0.w*s0.w
             + v1.x*s1.x + v1.y*s1.y + v1.z*s1.z + v1.w*s1.w;
    float sd = v0.x*d0.x + v0.y*d0.y + v0.z*d0.z + v0.w*d0.w
             + v1.x*d1.x + v1.y*d1.y + v1.z*d1.z + v1.w*d1.w;
    #pragma unroll
    for (int m = 16; m; m >>= 1) {
        ss += __shfl_xor(ss, m, 64);
        sd += __shfl_xor(sd, m, 64);
    }
    if ((tid & 31) == 0) { a_s[n] = ss; a_d[n] = sd; }
}

// ---------------------------------------------------------------------------
// fragment-major weight pack, all weights in one launch (blockIdx.z selects)
// out[(kt*NC16 + cf)*512 + l*8 + j] = bf16( W[kt*32+(l>>4)*8+j][cf*16+(l&15)] )
// ---------------------------------------------------------------------------
__global__ __launch_bounds__(64)
void k_packAll(const float* A1w, const float* W1, const float* W2, const float* A2w,
               const float* Hw1, const float* Hw2, const float* Hw3,
               u16* WT1, u16* WT2, u16* WTH)
{
    int z = blockIdx.z;
    const float *in1, *in2; int ksplit, csplit, in_ld, NC16; u16* out;
    if (z == 0)      { in1 = A1w; in2 = W1;  ksplit = 256; csplit = 0;   in_ld = 512; out = WT1; NC16 = 32; }
    else if (z == 1) { in1 = W2;  in2 = A2w; ksplit = 0;   csplit = 256; in_ld = 256; out = WT2; NC16 = 32; }
    else {
        if (blockIdx.x >= 16 || blockIdx.y >= 8) return;
        in1 = (z == 2) ? Hw1 : (z == 3) ? Hw2 : Hw3;
        in2 = nullptr; ksplit = 0; csplit = 0; in_ld = 256; NC16 = 16;
        out = WTH + (size_t)(z - 2) * 65536;
    }
    int l = threadIdx.x;
    int cf = blockIdx.x, kt = blockIdx.y;
    int col = cf * 16 + (l & 15);
    int kbase = kt * 32 + (l >> 4) * 8;
    const float* src = in1;
    int cc = col, koff = 0;
    if (ksplit > 0 && kbase >= ksplit) { src = in2; koff = ksplit; }
    if (csplit > 0 && col >= csplit)   { src = in2; cc = col - csplit; }
    u16* o = out + ((size_t)(kt * NC16 + cf) * 512) + l * 8;
    #pragma unroll
    for (int j = 0; j < 8; ++j)
        o[j] = f2b(src[(size_t)(kbase - koff + j) * in_ld + cc]);
}

// ---------------------------------------------------------------------------
// fp32 row-dot against two fp32 vectors — one wave per row, float4 lanes
// (used only for the 256-row W1 pre-dot)
// ---------------------------------------------------------------------------
__global__ __launch_bounds__(256)
void k_rowdot2f(const float* __restrict__ A, int ld, int H,
                const float* __restrict__ vs, const float* __restrict__ vd,
                float* a_s, float* a_d, int N)
{
    int wave = threadIdx.x >> 6, lane = threadIdx.x & 63;
    int n = blockIdx.x * 4 + wave;
    if (n >= N) return;
    const float* ar = A + (size_t)n * ld;
    float ss = 0.f, sd = 0.f;
    for (int i = lane * 4; i < H; i += 256) {
        float4 v  = *(const float4*)(ar + i);
        float4 s4 = *(const float4*)(vs + i);
        float4 d4 = *(const float4*)(vd + i);
        ss += v.x * s4.x + v.y * s4.y + v.z * s4.z + v.w * s4.w;
        sd += v.x * d4.x + v.y * d4.y + v.z * d4.z + v.w * d4.w;
    }
    #pragma unroll
    for (int m = 32; m; m >>= 1) {
        ss += __shfl_xor(ss, m, 64);
        sd += __shfl_xor(sd, m, 64);
    }
    if (lane == 0) { a_s[n] = ss; a_d[n] = sd; }
}

// ---------------------------------------------------------------------------
// bf16 row-dot (for layer-2 h2) — one wave per node
// ---------------------------------------------------------------------------
__global__ __launch_bounds__(256)
void k_rowdot2(const u16* h, int ld, int H, const float* vs, const float* vd,
               float* a_s, float* a_d, int N)
{
    int wave = threadIdx.x >> 6, lane = threadIdx.x & 63;
    int n = blockIdx.x * 4 + wave;
    if (n >= N) return;
    const u16* hr = h + (size_t)n * ld;
    float ss = 0.f, sd = 0.f;
    for (int i = lane; i < H; i += 64) {
        float v = b2f(hr[i]);
        ss += v * vs[i];
        sd += v * vd[i];
    }
    #pragma unroll
    for (int m = 32; m; m >>= 1) {
        ss += __shfl_xor(ss, m, 64);
        sd += __shfl_xor(sd, m, 64);
    }
    if (lane == 0) { a_s[n] = ss; a_d[n] = sd; }
}

// ---------------------------------------------------------------------------
// per-dst softmax: exact online max/sum (1 pass) + alpha write (1 pass)
// ---------------------------------------------------------------------------
__global__ __launch_bounds__(256)
void k_alpha(const int* __restrict__ off, const int* __restrict__ srcs,
             const float* __restrict__ a_s, const float* __restrict__ a_d,
             float* __restrict__ alpha, int N)
{
    int wave = threadIdx.x >> 6, lane = threadIdx.x & 63;
    int n = blockIdx.x * 4 + wave;
    if (n >= N) return;
    int base = off[n], end = off[n + 1];
    float adn = a_d[n];
    float m = -1e30f, s = 0.f;
    for (int p = base + lane; p < end; p += 64) {
        int sx = srcs[p];
        sx = ((unsigned)sx < (unsigned)N) ? sx : 0;
        float z = a_s[sx] + adn;
        z = fmaxf(z, NEG_SLOPE * z);          // leaky_relu (slope<1)
        float mn = fmaxf(m, z);
        s = s * __expf(m - mn) + __expf(z - mn);
        m = mn;
    }
    #pragma unroll
    for (int msk = 32; msk; msk >>= 1) {
        float mo = __shfl_xor(m, msk, 64);
        float so = __shfl_xor(s, msk, 64);
        float mn = fmaxf(m, mo);
        s = s * __expf(m - mn) + so * __expf(mo - mn);
        m = mn;
    }
    float inv = 1.f / (s + 1e-16f);
    for (int p = base + lane; p < end; p += 64) {
        int sx = srcs[p];
        sx = ((unsigned)sx < (unsigned)N) ? sx : 0;
        float z = a_s[sx] + adn;
        z = fmaxf(z, NEG_SLOPE * z);
        alpha[p] = __expf(z - m) * inv;
    }
}

// ---------------------------------------------------------------------------
// weighted gather-aggregate, half-wave split: lanes 0-31 edge p, 32-63 edge
// p+1; 16B row loads; 4 edges in flight; one shfl(32) reduce per node.
// out[n] = sum_e alpha[e] * rows[srcs[e]]  (+ add[n])
// ---------------------------------------------------------------------------
__global__ __launch_bounds__(256)
void k_aggw(const u16* __restrict__ rows, const int* __restrict__ off,
            const int* __restrict__ srcs, const float* __restrict__ alpha,
            const u16* __restrict__ add, u16* __restrict__ out, int N)
{
    int wave = threadIdx.x >> 6, lane = threadIdx.x & 63;
    int n = blockIdx.x * 4 + wave;
    if (n >= N) return;
    int base = off[n], end = off[n + 1];
    int half = lane >> 5;
    int c8 = (lane & 31) * 8;
    float acc[8] = {};
    int p = base;
    for (; p + 3 < end; p += 4) {
        int sA = srcs[p + half];
        int sB = srcs[p + 2 + half];
        sA = ((unsigned)sA < (unsigned)N) ? sA : 0;
        sB = ((unsigned)sB < (unsigned)N) ? sB : 0;
        float wA = alpha[p + half];
        float wB = alpha[p + 2 + half];
        u16x8 vA = *(const u16x8*)(rows + (size_t)sA * 256 + c8);
        u16x8 vB = *(const u16x8*)(rows + (size_t)sB * 256 + c8);
        #pragma unroll
        for (int j = 0; j < 8; ++j)
            acc[j] += wA * b2f(vA[j]) + wB * b2f(vB[j]);
    }
    for (; p + 1 < end; p += 2) {
        int sA = srcs[p + half];
        sA = ((unsigned)sA < (unsigned)N) ? sA : 0;
        float wA = alpha[p + half];
        u16x8 vA = *(const u16x8*)(rows + (size_t)sA * 256 + c8);
        #pragma unroll
        for (int j = 0; j < 8; ++j)
            acc[j] += wA * b2f(vA[j]);
    }
    if (p < end) {
        int sA = srcs[p];
        sA = ((unsigned)sA < (unsigned)N) ? sA : 0;
        float wA = half ? 0.f : alpha[p];
        u16x8 vA = *(const u16x8*)(rows + (size_t)sA * 256 + c8);
        #pragma unroll
        for (int j = 0; j < 8; ++j)
            acc[j] += wA * b2f(vA[j]);
    }
    #pragma unroll
    for (int j = 0; j < 8; ++j)
        acc[j] += __shfl_xor(acc[j], 32, 64);
    if (half == 0) {
        size_t ob = (size_t)n * 256 + c8;
        if (add) {
            u16x8 ad8 = *(const u16x8*)(add + ob);
            #pragma unroll
            for (int j = 0; j < 8; ++j) acc[j] += b2f(ad8[j]);
        }
        u16x8 o;
        #pragma unroll
        for (int j = 0; j < 8; ++j) o[j] = f2b(acc[j]);
        *(u16x8*)(out + ob) = o;
    }
}

// ---------------------------------------------------------------------------
// full-width fused MFMA GEMM: BM=64, K=512 (two bf16 A halves of 256 each),
// NC=512 from fragment-major pre-packed WTf. Output split at col 256 into
// (C1, C2) with per-half fp32 bias pairs and relu flags. A read ONCE from HBM.
// 8 waves, each owns a 64x64 tile; all LDS reads base + lane*16.
// ---------------------------------------------------------------------------
__global__ __launch_bounds__(512)
void bigfull(const u16* __restrict__ A1, int lda1,
             const u16* __restrict__ A2, int lda2,
             const u16* __restrict__ WTf,
             const float* b0a, const float* b0b,
             const float* b1a, const float* b1b,
             u16* C1, int ldc1, u16* C2, int ldc2,
             int M, int relu0, int relu1)
{
    __shared__ u16 As[64 * 32];      // frag-major: [rf][lane][8]   (4 KB)
    __shared__ u16 Bs[512 * 32];     // frag-major: [cf][lane][8]  (32 KB)

    const int tid = threadIdx.x;
    const int w = tid >> 6, lane = tid & 63;
    const int m16 = lane & 15, q = lane >> 4;
    const int rowBase = blockIdx.x * 64;

    float4v acc[16] = {};

    for (int k0 = 0; k0 < 512; k0 += 32) {
        const int kt = k0 >> 5;
        __syncthreads();
        if (tid < 256) {   // stage A 64x32 into fragment order
            int rf = tid >> 6, al = tid & 63;
            int grow = rowBase + rf * 16 + (al & 15);
            if (grow >= M) grow = M - 1;          // clamp; value unused
            int kk = k0 + (al >> 4) * 8;
            const u16* src = (kk < 256)
                ? A1 + (size_t)grow * lda1 + kk
                : A2 + (size_t)grow * lda2 + (kk - 256);
            *(int4*)&As[tid * 8] = *(const int4*)src;
        }
        {   // stage B 512x32: pure linear copy of pre-packed fragments
            const u16* wsrc = WTf + (size_t)kt * 16384;
            #pragma unroll
            for (int p = 0; p < 4; ++p) {
                int ch = p * 512 + tid;
                *(int4*)&Bs[ch * 8] = *(const int4*)(wsrc + (size_t)ch * 8);
            }
        }
        __syncthreads();

        short8 a[4], b[4];
        #pragma unroll
        for (int r = 0; r < 4; ++r)
            a[r] = *(const short8*)&As[r * 512 + lane * 8];
        #pragma unroll
        for (int c = 0; c < 4; ++c)
            b[c] = *(const short8*)&Bs[(w * 4 + c) * 512 + lane * 8];
        #pragma unroll
        for (int r = 0; r < 4; ++r)
            #pragma unroll
            for (int c = 0; c < 4; ++c)
                acc[r * 4 + c] = __builtin_amdgcn_mfma_f32_16x16x32_bf16(
                    a[r], b[c], acc[r * 4 + c], 0, 0, 0);
    }

    const int colgrp = w >> 2;
    const float* ba = colgrp ? b1a : b0a;
    const float* bb = colgrp ? b1b : b0b;
    u16* C  = colgrp ? C2 : C1;
    const int ldc  = colgrp ? ldc2 : ldc1;
    const int relu = colgrp ? relu1 : relu0;
    #pragma unroll
    for (int c = 0; c < 4; ++c) {
        int lc = ((w & 3) * 4 + c) * 16 + m16;
        float bv = (ba ? ba[lc] : 0.f) + (bb ? bb[lc] : 0.f);
        #pragma unroll
        for (int r = 0; r < 4; ++r)
            #pragma unroll
            for (int i = 0; i < 4; ++i) {
                int grow = rowBase + r * 16 + q * 4 + i;
                if (grow < M) {
                    float v = acc[r * 4 + c][i] + bv;
                    if (relu) v = fmaxf(v, 0.f);
                    C[(size_t)grow * ldc + lc] = f2b(v);
                }
            }
    }
}

// ---------------------------------------------------------------------------
// fused 3-layer MLP [256->256] relu, in-place: block owns 64 rows kept in a
// fragment-major LDS panel across layers; 4 waves each own 64x64.
// ---------------------------------------------------------------------------
__global__ __launch_bounds__(256)
void k_mlp3(const u16* __restrict__ WTHf,
            const float* Hb1, const float* Hb2, const float* Hb3,
            u16* H, int M)
{
    __shared__ u16 P[64 * 256];     // frag-major activation panel (32 KB)
    __shared__ u16 Bs[256 * 32];    // frag-major B K-slice        (16 KB)

    const int tid = threadIdx.x;
    const int w = tid >> 6, lane = tid & 63;
    const int m16 = lane & 15, q = lane >> 4;
    const int rowBase = blockIdx.x * 64;

    // load panel (global row-major -> fragment-major)
    #pragma unroll
    for (int p = 0; p < 8; ++p) {
        int ch = p * 256 + tid;          // 0..2047 16B-chunks
        int f = ch >> 6, l = ch & 63;    // frag f = kt*4+rf, lane-slot l
        int kt = f >> 2, rf = f & 3;
        int grow = rowBase + rf * 16 + (l & 15);
        if (grow >= M) grow = M - 1;
        int col = kt * 32 + (l >> 4) * 8;
        *(int4*)&P[ch * 8] = *(const int4*)(H + (size_t)grow * 256 + col);
    }

    const float* biases[3] = {Hb1, Hb2, Hb3};
    for (int L = 0; L < 3; ++L) {
        const u16* WTf = WTHf + (size_t)L * 65536;
        float4v acc[16] = {};
        for (int kt = 0; kt < 8; ++kt) {
            __syncthreads();
            {   // stage B 256x32: linear copy
                const u16* wsrc = WTf + (size_t)kt * 8192;
                #pragma unroll
                for (int p = 0; p < 4; ++p) {
                    int ch = p * 256 + tid;
                    *(int4*)&Bs[ch * 8] = *(const int4*)(wsrc + (size_t)ch * 8);
                }
            }
            __syncthreads();
            short8 a[4], b[4];
            #pragma unroll
            for (int r = 0; r < 4; ++r)
                a[r] = *(const short8*)&P[(kt * 4 + r) * 512 + lane * 8];
            #pragma unroll
            for (int c = 0; c < 4; ++c)
                b[c] = *(const short8*)&Bs[(w * 4 + c) * 512 + lane * 8];
            #pragma unroll
            for (int r = 0; r < 4; ++r)
                #pragma unroll
                for (int c = 0; c < 4; ++c)
                    acc[r * 4 + c] = __builtin_amdgcn_mfma_f32_16x16x32_bf16(
                        a[r], b[c], acc[r * 4 + c], 0, 0, 0);
        }
        const float* bias = biases[L];
        __syncthreads();    // all panel reads done before overwrite
        if (L < 2) {
            // writeback into fragment-major panel (out col -> next-layer k)
            #pragma unroll
            for (int c = 0; c < 4; ++c) {
                int col = w * 64 + c * 16 + m16;
                float bv = bias[col];
                int kt2 = col >> 5;
                int l2h = 16 * ((col & 31) >> 3);
                int j2 = col & 7;
                #pragma unroll
                for (int r = 0; r < 4; ++r)
                    #pragma unroll
                    for (int i = 0; i < 4; ++i) {
                        int l2 = (q * 4 + i) + l2h;
                        P[(size_t)(kt2 * 4 + r) * 512 + l2 * 8 + j2] =
                            f2b(fmaxf(acc[r * 4 + c][i] + bv, 0.f));
                    }
            }
        } else {
            #pragma unroll
            for (int c = 0; c < 4; ++c) {
                int col = w * 64 + c * 16 + m16;
                float bv = bias[col];
                #pragma unroll
                for (int r = 0; r < 4; ++r)
                    #pragma unroll
                    for (int i = 0; i < 4; ++i) {
                        int grow = rowBase + r * 16 + q * 4 + i;
                        if (grow < M)
                            H[(size_t)grow * 256 + col] =
                                f2b(fmaxf(acc[r * 4 + c][i] + bv, 0.f));
                    }
            }
        }
    }
}

// ---------------------------------------------------------------------------
// classifier + softmax: one wave per node (4 nodes/block), 256 -> 5, fp32 out
// ---------------------------------------------------------------------------
__global__ __launch_bounds__(256)
void k_fc_softmax(const u16* hin, const float* fcw, const float* fcb,
                  float* out, int N)
{
    int wave = threadIdx.x >> 6, lane = threadIdx.x & 63;
    int n = blockIdx.x * 4 + wave;
    if (n >= N) return;
    const u16* hr = hin + (size_t)n * 256;
    int k0 = lane * 4;
    float hv[4];
    float p[5] = {0.f, 0.f, 0.f, 0.f, 0.f};
    #pragma unroll
    for (int j = 0; j < 4; ++j) hv[j] = b2f(hr[k0 + j]);
    #pragma unroll
    for (int j = 0; j < 4; ++j) {
        const float* wr = fcw + (size_t)(k0 + j) * 5;
        #pragma unroll
        for (int c = 0; c < 5; ++c) p[c] += hv[j] * wr[c];
    }
    #pragma unroll
    for (int c = 0; c < 5; ++c) {
        #pragma unroll
        for (int s = 32; s; s >>= 1) p[c] += __shfl_xor(p[c], s, 64);
    }
    if (lane == 0) {
        float m = -1e30f;
        #pragma unroll
        for (int c = 0; c < 5; ++c) { p[c] += fcb[c]; m = fmaxf(m, p[c]); }
        float s = 0.f, e[5];
        #pragma unroll
        for (int c = 0; c < 5; ++c) { e[c] = __expf(p[c] - m); s += e[c]; }
        float inv = 1.f / s;
        #pragma unroll
        for (int c = 0; c < 5; ++c) out[(size_t)n * 5 + c] = e[c] * inv;
    }
}

// ---------------------------------------------------------------------------
extern "C" void kernel_launch(void* const* d_in, const int* in_sizes, int n_in,
                              void* d_out, int out_size, void* d_ws, size_t ws_size,
                              hipStream_t stream)
{
    const float* x    = (const float*)d_in[0];
    const int*   ei   = (const int*)  d_in[1];
    const float* W1   = (const float*)d_in[2];
    const float* as1  = (const float*)d_in[3];
    const float* ad1  = (const float*)d_in[4];
    const float* bc1  = (const float*)d_in[5];
    const float* A1w  = (const float*)d_in[6];
    const float* b1   = (const float*)d_in[7];
    const float* W2   = (const float*)d_in[8];
    const float* as2  = (const float*)d_in[9];
    const float* ad2  = (const float*)d_in[10];
    const float* bc2  = (const float*)d_in[11];
    const float* A2w  = (const float*)d_in[12];
    const float* b2   = (const float*)d_in[13];
    const float* Hw1  = (const float*)d_in[14];
    const float* Hb1  = (const float*)d_in[15];
    const float* Hw2  = (const float*)d_in[16];
    const float* Hb2  = (const float*)d_in[17];
    const float* Hw3  = (const float*)d_in[18];
    const float* Hb3  = (const float*)d_in[19];
    const float* fcw  = (const float*)d_in[20];
    const float* fcb  = (const float*)d_in[21];
    float* out = (float*)d_out;

    const int D = 256;
    const int N = in_sizes[0] / D;
    const int E = in_sizes[1] / 2;

    char* w = (char*)d_ws;
    auto alloc = [&](size_t bytes) {
        char* p = w;
        w += (bytes + 255) & ~(size_t)255;
        return p;
    };
    int*   flag   = (int*)  alloc(256);
    int*   flag64 = (int*)  alloc(256);
    float* a_s    = (float*)alloc((size_t)N * 4);
    float* a_d    = (float*)alloc((size_t)N * 4);
    float* vs1    = (float*)alloc(1024);                 // W1 @ att_src1  [256]
    float* vd1    = (float*)alloc(1024);                 // W1 @ att_dst1  [256]
    int*   deg    = (int*)  alloc((size_t)N * 4);
    int*   cursor = (int*)  alloc((size_t)N * 4);
    int*   offA   = (int*)  alloc((size_t)(N + 1) * 4);
    int*   part   = (int*)  alloc((size_t)((N + 1023) / 1024 + 1) * 4);
    int*   srcs   = (int*)  alloc((size_t)E * 4);
    float* alpha  = (float*)alloc((size_t)E * 4);        // normalized edge weights
    u16*   WT1    = (u16*)  alloc(512 * 512 * 2);        // frag-major [A1w;W1]
    u16*   WT2    = (u16*)  alloc(512 * 512 * 2);        // frag-major [W2|A2w]
    u16*   WTH    = (u16*)  alloc(3 * 256 * 256 * 2);    // frag-major MLP weights
    u16*   BUF1   = (u16*)  alloc((size_t)N * 512 * 2);  // xb|aggx -> h2|res2
    u16*   BUF2   = (u16*)  alloc((size_t)N * 512 * 2);  // hl1 -> out2/MLP

    // src32/dst32 alias BUF1 (dead before xb is written)
    int* src32 = (int*)BUF1;
    int* dst32 = src32 + E;

    size_t need = (size_t)(w - (char*)d_ws);             // ~112 MB
    if (ws_size < need) {
        float code = 1000.0f + (float)(ws_size >> 20);
        k_diag<<<(out_size + 255) / 256, 256, 0, stream>>>(out, out_size, code);
        return;
    }

    const int EB  = (E + 255) / 256;
    const int NB4 = (N + 3) / 4;
    const int OB  = (out_size + 255) / 256;
    const int NE  = (N > E ? N : E);
    const int RB64 = (N + 63) / 64;
    const int NBLK = (N + 1023) / 1024;
    const size_t NH2 = (size_t)N * 256;
    u16* XB   = BUF1;            // bf16 cast of x      [N,256]
    u16* AGGX = BUF1 + NH2;      // alpha-aggregated x  [N,256]

    hipMemsetAsync(flag, 0, 4, stream);
    hipMemsetAsync(deg, 0, (size_t)N * 4, stream);

    // ---- edge extraction (+degree count) + CSR by destination ----
    k_detect <<<1, 256, 0, stream>>>(ei, E, flag64);
    k_extract<<<EB, 256, 0, stream>>>(ei, E, flag64, src32, dst32, deg, N);
    k_scan_a <<<NBLK, 256, 0, stream>>>(deg, offA, part, N);
    k_scan_b <<<1, 1024, 0, stream>>>(part, NBLK);
    k_scan_c <<<(N + 255) / 256, 256, 0, stream>>>(offA, cursor, part, N, E);
    k_scatter<<<EB, 256, 0, stream>>>(src32, dst32, cursor, srcs, E, N);
    scan_csr <<<(NE + 255) / 256, 256, 0, stream>>>(offA, srcs, N, E, flag, 1);

    // ---- weight pre-pack (fragment-major bf16, single launch) ----
    k_packAll<<<dim3(32, 16, 5), 64, 0, stream>>>(A1w, W1, W2, A2w,
                                                  Hw1, Hw2, Hw3, WT1, WT2, WTH);

    // ---- attention vectors, then fused cast+dot over x ----
    k_rowdot2f<<<64, 256, 0, stream>>>(W1, 512, 512, as1, ad1, vs1, vd1, 256);
    k_castdot<<<(N + 7) / 8, 256, 0, stream>>>(x, vs1, vd1, XB, a_s, a_d, N);
    k_alpha<<<NB4, 256, 0, stream>>>(offA, srcs, a_s, a_d, alpha, N);

    // ---- aggx = sum_e alpha_e * xb[src_e]  (GAT linearity: agg before W1) ----
    k_aggw<<<NB4, 256, 0, stream>>>(XB, offA, srcs, alpha, nullptr, AGGX, N);

    // ---- layer 1 fused: hl1 = relu([XB|AGGX] @ [A1w;W1] + b1 + bc1) ----
    bigfull<<<RB64, 512, 0, stream>>>(XB, 256, AGGX, 256, WT1,
                                      b1, bc1, b1 + 256, bc1 + 256,
                                      BUF2, 512, BUF2 + 256, 512, N, 1, 1);

    // ---- layer 2 fused: [h2 | res2] = hl1 @ [W2 | A2w] (+b2+bc2 on res2) ----
    bigfull<<<RB64, 512, 0, stream>>>(BUF2, 512, BUF2 + 256, 512, WT2,
                                      nullptr, nullptr, b2, bc2,
                                      BUF1, 256, BUF1 + NH2, 256, N, 0, 0);

    k_rowdot2<<<NB4, 256, 0, stream>>>(BUF1, 256, 256, as2, ad2, a_s, a_d, N);
    k_alpha<<<NB4, 256, 0, stream>>>(offA, srcs, a_s, a_d, alpha, N);
    k_aggw<<<NB4, 256, 0, stream>>>(BUF1, offA, srcs, alpha, BUF1 + NH2, BUF2, N);

    // ---- fused 3-layer MLP (in-place in BUF2) ----
    k_mlp3<<<RB64, 256, 0, stream>>>(WTH, Hb1, Hb2, Hb3, BUF2, N);

    // ---- classifier + softmax (fp32 out) ----
    k_fc_softmax<<<NB4, 256, 0, stream>>>(BUF2, fcw, fcb, out, N);

    k_final_diag<<<OB, 256, 0, stream>>>(flag, out, out_size);
}

// Round 6
// 572.395 us; speedup vs baseline: 2.1139x; 1.0256x over previous
//
#include <hip/hip_runtime.h>

typedef unsigned short u16;
typedef short short8 __attribute__((ext_vector_type(8)));
typedef u16 u16x4 __attribute__((ext_vector_type(4)));
typedef u16 u16x8 __attribute__((ext_vector_type(8)));
typedef float float4v __attribute__((ext_vector_type(4)));

#define NEG_SLOPE 0.2f

static __device__ __forceinline__ float b2f(u16 u) {
    union { unsigned int i; float f; } x; x.i = ((unsigned int)u) << 16; return x.f;
}
static __device__ __forceinline__ u16 f2b(float f) {
    unsigned int u = __float_as_uint(f);
    unsigned int r = (u + 0x7fffu + ((u >> 16) & 1u)) >> 16;
    return (u16)r;
}

// ---------------------------------------------------------------------------
// diagnostics: code 32 = CSR inconsistent; 1000+ = ws too small
// ---------------------------------------------------------------------------
__global__ void k_diag(float* out, int n, float val)
{
    int i = blockIdx.x * 256 + threadIdx.x;
    if (i < n) out[i] = val;
}

__global__ void scan_csr(const int* off, const int* srcs, int N, int E,
                         int* flag, int bit)
{
    int i = blockIdx.x * 256 + threadIdx.x;
    if (i < N) {
        int a = off[i], b = off[i + 1];
        if (a < 0 || b < a || b > E) atomicOr(flag, bit);
    }
    if (i == 0 && off[N] != E) atomicOr(flag, bit);
    if (i < E) {
        if ((unsigned)srcs[i] >= (unsigned)N) atomicOr(flag, bit);
    }
}

__global__ void k_final_diag(const int* flag, float* out, int n)
{
    int f = *flag;
    if (f == 0) return;
    int b = __ffs(f) - 1;
    float val = 32.0f * (b + 1);
    int i = blockIdx.x * 256 + threadIdx.x;
    if (i < n) out[i] = val;
}

// ---------------------------------------------------------------------------
// edge_index dtype probe + canonical int32 extraction (+ degree count fused)
// ---------------------------------------------------------------------------
__global__ void k_detect(const int* ei, int E, int* flag64)
{
    __shared__ int zc;
    if (threadIdx.x == 0) zc = 0;
    __syncthreads();
    int idx = 1 + 2 * (int)threadIdx.x;
    int z = (idx < 2 * E && ei[idx] == 0) ? 1 : 0;
    atomicAdd(&zc, z);
    __syncthreads();
    if (threadIdx.x == 0) *flag64 = (zc >= 200) ? 1 : 0;
}

__global__ void k_extract(const int* ei, int E, const int* flag64,
                          int* src, int* dst, int* deg, int N)
{
    int e = blockIdx.x * 256 + threadIdx.x;
    if (e >= E) return;
    int s, d;
    if (*flag64) {
        s = ei[2 * e];
        d = ei[2 * E + 2 * e];
    } else {
        s = ei[e];
        d = ei[E + e];
    }
    src[e] = s; dst[e] = d;
    if ((unsigned)d < (unsigned)N) atomicAdd(&deg[d], 1);
}

// ---------------------------------------------------------------------------
// device-wide exclusive scan, 3-phase (1024 elems per block in phase A)
// ---------------------------------------------------------------------------
__global__ __launch_bounds__(256)
void k_scan_a(const int* __restrict__ deg, int* __restrict__ off,
              int* __restrict__ partial, int N)
{
    __shared__ int sd[256];
    int tid = threadIdx.x;
    int base = blockIdx.x * 1024;
    int i0 = base + tid * 4;
    int v0 = 0, v1 = 0, v2 = 0, v3 = 0;
    if (i0 < N)     v0 = deg[i0];
    if (i0 + 1 < N) v1 = deg[i0 + 1];
    if (i0 + 2 < N) v2 = deg[i0 + 2];
    if (i0 + 3 < N) v3 = deg[i0 + 3];
    int t = v0 + v1 + v2 + v3;
    sd[tid] = t;
    __syncthreads();
    #pragma unroll
    for (int s = 1; s < 256; s <<= 1) {
        int u = (tid >= s) ? sd[tid - s] : 0;
        __syncthreads();
        sd[tid] += u;
        __syncthreads();
    }
    int excl = sd[tid] - t;                 // exclusive within block
    if (i0 < N)     off[i0]     = excl;
    if (i0 + 1 < N) off[i0 + 1] = excl + v0;
    if (i0 + 2 < N) off[i0 + 2] = excl + v0 + v1;
    if (i0 + 3 < N) off[i0 + 3] = excl + v0 + v1 + v2;
    if (tid == 255) partial[blockIdx.x] = sd[255];
}

__global__ __launch_bounds__(1024)
void k_scan_b(int* partial, int nblk)
{
    __shared__ int sd[1024];
    __shared__ int running;
    int tid = threadIdx.x;
    if (tid == 0) running = 0;
    __syncthreads();
    for (int base = 0; base < nblk; base += 1024) {
        int i = base + tid;
        int v = (i < nblk) ? partial[i] : 0;
        sd[tid] = v;
        __syncthreads();
        for (int s = 1; s < 1024; s <<= 1) {
            int u = (tid >= s) ? sd[tid - s] : 0;
            __syncthreads();
            sd[tid] += u;
            __syncthreads();
        }
        if (i < nblk) partial[i] = sd[tid] - v + running;   // exclusive
        int total = sd[1023];
        __syncthreads();
        if (tid == 0) running += total;
        __syncthreads();
    }
}

__global__ __launch_bounds__(256)
void k_scan_c(int* __restrict__ off, int* __restrict__ cursor,
              const int* __restrict__ partial, int N, int E)
{
    int i = blockIdx.x * 256 + threadIdx.x;
    if (i < N) {
        int v = off[i] + partial[i >> 10];
        off[i] = v;
        cursor[i] = v;
    }
    if (i == 0) off[N] = E;
}

__global__ void k_scatter(const int* src, const int* dst, int* cursor,
                          int* srcs, int E, int N)
{
    int e = blockIdx.x * 256 + threadIdx.x;
    if (e < E) {
        int d = dst[e];
        if ((unsigned)d < (unsigned)N) {
            int p = atomicAdd(&cursor[d], 1);
            if ((unsigned)p < (unsigned)E) srcs[p] = src[e];
        }
    }
}

// ---------------------------------------------------------------------------
// fused fp32->bf16 cast + row dots vs (vs,vd): 8 rows/block, 32 lanes/row.
// ---------------------------------------------------------------------------
__global__ __launch_bounds__(256)
void k_castdot(const float* __restrict__ x, const float* __restrict__ vs,
               const float* __restrict__ vd, u16* __restrict__ xb,
               float* __restrict__ a_s, float* __restrict__ a_d, int N)
{
    int tid = threadIdx.x;
    int rowb = tid >> 5;                // 0..7
    int col8 = (tid & 31) * 8;
    int n = blockIdx.x * 8 + rowb;
    if (n >= N) return;
    const float* xr = x + (size_t)n * 256 + col8;
    float4 v0 = *(const float4*)xr;
    float4 v1 = *(const float4*)(xr + 4);
    int4 w;
    w.x = (int)f2b(v0.x) | ((int)f2b(v0.y) << 16);
    w.y = (int)f2b(v0.z) | ((int)f2b(v0.w) << 16);
    w.z = (int)f2b(v1.x) | ((int)f2b(v1.y) << 16);
    w.w = (int)f2b(v1.z) | ((int)f2b(v1.w) << 16);
    *(int4*)(xb + (size_t)n * 256 + col8) = w;

    float4 s0 = *(const float4*)(vs + col8);
    float4 s1 = *(const float4*)(vs + col8 + 4);
    float4 d0 = *(const float4*)(vd + col8);
    float4 d1 = *(const float4*)(vd + col8 + 4);
    float ss = v0.x*s0.x + v0.y*s0.y + v0.z*s0.z + v0.w*s0.w
             + v1.x*s1.x + v1.y*s1.y + v1.z*s1.z + v1.w*s1.w;
    float sd = v0.x*d0.x + v0.y*d0.y + v0.z*d0.z + v0.w*d0.w
             + v1.x*d1.x + v1.y*d1.y + v1.z*d1.z + v1.w*d1.w;
    #pragma unroll
    for (int m = 16; m; m >>= 1) {
        ss += __shfl_xor(ss, m, 64);
        sd += __shfl_xor(sd, m, 64);
    }
    if ((tid & 31) == 0) { a_s[n] = ss; a_d[n] = sd; }
}

// ---------------------------------------------------------------------------
// fragment-major weight pack, all weights in one launch (blockIdx.z selects)
// out[(kt*NC16 + cf)*512 + l*8 + j] = bf16( W[kt*32+(l>>4)*8+j][cf*16+(l&15)] )
// ---------------------------------------------------------------------------
__global__ __launch_bounds__(64)
void k_packAll(const float* A1w, const float* W1, const float* W2, const float* A2w,
               const float* Hw1, const float* Hw2, const float* Hw3,
               u16* WT1, u16* WT2, u16* WTH)
{
    int z = blockIdx.z;
    const float *in1, *in2; int ksplit, csplit, in_ld, NC16; u16* out;
    if (z == 0)      { in1 = A1w; in2 = W1;  ksplit = 256; csplit = 0;   in_ld = 512; out = WT1; NC16 = 32; }
    else if (z == 1) { in1 = W2;  in2 = A2w; ksplit = 0;   csplit = 256; in_ld = 256; out = WT2; NC16 = 32; }
    else {
        if (blockIdx.x >= 16 || blockIdx.y >= 8) return;
        in1 = (z == 2) ? Hw1 : (z == 3) ? Hw2 : Hw3;
        in2 = nullptr; ksplit = 0; csplit = 0; in_ld = 256; NC16 = 16;
        out = WTH + (size_t)(z - 2) * 65536;
    }
    int l = threadIdx.x;
    int cf = blockIdx.x, kt = blockIdx.y;
    int col = cf * 16 + (l & 15);
    int kbase = kt * 32 + (l >> 4) * 8;
    const float* src = in1;
    int cc = col, koff = 0;
    if (ksplit > 0 && kbase >= ksplit) { src = in2; koff = ksplit; }
    if (csplit > 0 && col >= csplit)   { src = in2; cc = col - csplit; }
    u16* o = out + ((size_t)(kt * NC16 + cf) * 512) + l * 8;
    #pragma unroll
    for (int j = 0; j < 8; ++j)
        o[j] = f2b(src[(size_t)(kbase - koff + j) * in_ld + cc]);
}

// ---------------------------------------------------------------------------
// fp32 row-dot against two fp32 vectors — one wave per row, float4 lanes
// ---------------------------------------------------------------------------
__global__ __launch_bounds__(256)
void k_rowdot2f(const float* __restrict__ A, int ld, int H,
                const float* __restrict__ vs, const float* __restrict__ vd,
                float* a_s, float* a_d, int N)
{
    int wave = threadIdx.x >> 6, lane = threadIdx.x & 63;
    int n = blockIdx.x * 4 + wave;
    if (n >= N) return;
    const float* ar = A + (size_t)n * ld;
    float ss = 0.f, sd = 0.f;
    for (int i = lane * 4; i < H; i += 256) {
        float4 v  = *(const float4*)(ar + i);
        float4 s4 = *(const float4*)(vs + i);
        float4 d4 = *(const float4*)(vd + i);
        ss += v.x * s4.x + v.y * s4.y + v.z * s4.z + v.w * s4.w;
        sd += v.x * d4.x + v.y * d4.y + v.z * d4.z + v.w * d4.w;
    }
    #pragma unroll
    for (int m = 32; m; m >>= 1) {
        ss += __shfl_xor(ss, m, 64);
        sd += __shfl_xor(sd, m, 64);
    }
    if (lane == 0) { a_s[n] = ss; a_d[n] = sd; }
}

// ---------------------------------------------------------------------------
// bf16 row-dot (for layer-2 h2) — one wave per node
// ---------------------------------------------------------------------------
__global__ __launch_bounds__(256)
void k_rowdot2(const u16* h, int ld, int H, const float* vs, const float* vd,
               float* a_s, float* a_d, int N)
{
    int wave = threadIdx.x >> 6, lane = threadIdx.x & 63;
    int n = blockIdx.x * 4 + wave;
    if (n >= N) return;
    const u16* hr = h + (size_t)n * ld;
    float ss = 0.f, sd = 0.f;
    for (int i = lane; i < H; i += 64) {
        float v = b2f(hr[i]);
        ss += v * vs[i];
        sd += v * vd[i];
    }
    #pragma unroll
    for (int m = 32; m; m >>= 1) {
        ss += __shfl_xor(ss, m, 64);
        sd += __shfl_xor(sd, m, 64);
    }
    if (lane == 0) { a_s[n] = ss; a_d[n] = sd; }
}

// ---------------------------------------------------------------------------
// per-dst softmax: exact online max/sum (1 pass) + alpha write (1 pass)
// ---------------------------------------------------------------------------
__global__ __launch_bounds__(256)
void k_alpha(const int* __restrict__ off, const int* __restrict__ srcs,
             const float* __restrict__ a_s, const float* __restrict__ a_d,
             float* __restrict__ alpha, int N)
{
    int wave = threadIdx.x >> 6, lane = threadIdx.x & 63;
    int n = blockIdx.x * 4 + wave;
    if (n >= N) return;
    int base = off[n], end = off[n + 1];
    float adn = a_d[n];
    float m = -1e30f, s = 0.f;
    for (int p = base + lane; p < end; p += 64) {
        int sx = srcs[p];
        sx = ((unsigned)sx < (unsigned)N) ? sx : 0;
        float z = a_s[sx] + adn;
        z = fmaxf(z, NEG_SLOPE * z);          // leaky_relu (slope<1)
        float mn = fmaxf(m, z);
        s = s * __expf(m - mn) + __expf(z - mn);
        m = mn;
    }
    #pragma unroll
    for (int msk = 32; msk; msk >>= 1) {
        float mo = __shfl_xor(m, msk, 64);
        float so = __shfl_xor(s, msk, 64);
        float mn = fmaxf(m, mo);
        s = s * __expf(m - mn) + so * __expf(mo - mn);
        m = mn;
    }
    float inv = 1.f / (s + 1e-16f);
    for (int p = base + lane; p < end; p += 64) {
        int sx = srcs[p];
        sx = ((unsigned)sx < (unsigned)N) ? sx : 0;
        float z = a_s[sx] + adn;
        z = fmaxf(z, NEG_SLOPE * z);
        alpha[p] = __expf(z - m) * inv;
    }
}

// ---------------------------------------------------------------------------
// weighted gather-aggregate, half-wave split: lanes 0-31 edge p, 32-63 edge
// p+1; 16B row loads; 4 edges in flight; one shfl(32) reduce per node.
// ---------------------------------------------------------------------------
__global__ __launch_bounds__(256)
void k_aggw(const u16* __restrict__ rows, const int* __restrict__ off,
            const int* __restrict__ srcs, const float* __restrict__ alpha,
            const u16* __restrict__ add, u16* __restrict__ out, int N)
{
    int wave = threadIdx.x >> 6, lane = threadIdx.x & 63;
    int n = blockIdx.x * 4 + wave;
    if (n >= N) return;
    int base = off[n], end = off[n + 1];
    int half = lane >> 5;
    int c8 = (lane & 31) * 8;
    float acc[8] = {};
    int p = base;
    for (; p + 3 < end; p += 4) {
        int sA = srcs[p + half];
        int sB = srcs[p + 2 + half];
        sA = ((unsigned)sA < (unsigned)N) ? sA : 0;
        sB = ((unsigned)sB < (unsigned)N) ? sB : 0;
        float wA = alpha[p + half];
        float wB = alpha[p + 2 + half];
        u16x8 vA = *(const u16x8*)(rows + (size_t)sA * 256 + c8);
        u16x8 vB = *(const u16x8*)(rows + (size_t)sB * 256 + c8);
        #pragma unroll
        for (int j = 0; j < 8; ++j)
            acc[j] += wA * b2f(vA[j]) + wB * b2f(vB[j]);
    }
    for (; p + 1 < end; p += 2) {
        int sA = srcs[p + half];
        sA = ((unsigned)sA < (unsigned)N) ? sA : 0;
        float wA = alpha[p + half];
        u16x8 vA = *(const u16x8*)(rows + (size_t)sA * 256 + c8);
        #pragma unroll
        for (int j = 0; j < 8; ++j)
            acc[j] += wA * b2f(vA[j]);
    }
    if (p < end) {
        int sA = srcs[p];
        sA = ((unsigned)sA < (unsigned)N) ? sA : 0;
        float wA = half ? 0.f : alpha[p];
        u16x8 vA = *(const u16x8*)(rows + (size_t)sA * 256 + c8);
        #pragma unroll
        for (int j = 0; j < 8; ++j)
            acc[j] += wA * b2f(vA[j]);
    }
    #pragma unroll
    for (int j = 0; j < 8; ++j)
        acc[j] += __shfl_xor(acc[j], 32, 64);
    if (half == 0) {
        size_t ob = (size_t)n * 256 + c8;
        if (add) {
            u16x8 ad8 = *(const u16x8*)(add + ob);
            #pragma unroll
            for (int j = 0; j < 8; ++j) acc[j] += b2f(ad8[j]);
        }
        u16x8 o;
        #pragma unroll
        for (int j = 0; j < 8; ++j) o[j] = f2b(acc[j]);
        *(u16x8*)(out + ob) = o;
    }
}

// ---------------------------------------------------------------------------
// full-width fused MFMA GEMM: BM=64, K=512 (two bf16 A halves of 256 each),
// NC=512, fragment-major WTf. B read DIRECTLY per-wave from L2 (no LDS, no
// B barriers) — wave w consumes exactly frags cf = w*4..w*4+3 per kt.
// Only A is LDS-staged (cross-wave, 2 barriers/kt, 4 KB).
// ---------------------------------------------------------------------------
__global__ __launch_bounds__(512)
void bigfull(const u16* __restrict__ A1, int lda1,
             const u16* __restrict__ A2, int lda2,
             const u16* __restrict__ WTf,
             const float* b0a, const float* b0b,
             const float* b1a, const float* b1b,
             u16* C1, int ldc1, u16* C2, int ldc2,
             int M, int relu0, int relu1)
{
    __shared__ u16 As[64 * 32];      // frag-major A K-slice (4 KB)

    const int tid = threadIdx.x;
    const int w = tid >> 6, lane = tid & 63;
    const int m16 = lane & 15, q = lane >> 4;
    const int rowBase = blockIdx.x * 64;

    float4v acc[16] = {};

    for (int k0 = 0; k0 < 512; k0 += 32) {
        const int kt = k0 >> 5;
        __syncthreads();
        if (tid < 256) {   // stage A 64x32 into fragment order
            int rf = tid >> 6, al = tid & 63;
            int grow = rowBase + rf * 16 + (al & 15);
            if (grow >= M) grow = M - 1;          // clamp; value unused
            int kk = k0 + (al >> 4) * 8;
            const u16* src = (kk < 256)
                ? A1 + (size_t)grow * lda1 + kk
                : A2 + (size_t)grow * lda2 + (kk - 256);
            *(int4*)&As[tid * 8] = *(const int4*)src;
        }
        __syncthreads();

        short8 a[4], b[4];
        #pragma unroll
        for (int c = 0; c < 4; ++c) {
            int4 bv = *(const int4*)(WTf + (size_t)kt * 16384
                                     + (size_t)(w * 4 + c) * 512 + lane * 8);
            b[c] = *(short8*)&bv;
        }
        #pragma unroll
        for (int r = 0; r < 4; ++r)
            a[r] = *(const short8*)&As[r * 512 + lane * 8];
        #pragma unroll
        for (int r = 0; r < 4; ++r)
            #pragma unroll
            for (int c = 0; c < 4; ++c)
                acc[r * 4 + c] = __builtin_amdgcn_mfma_f32_16x16x32_bf16(
                    a[r], b[c], acc[r * 4 + c], 0, 0, 0);
    }

    const int colgrp = w >> 2;
    const float* ba = colgrp ? b1a : b0a;
    const float* bb = colgrp ? b1b : b0b;
    u16* C  = colgrp ? C2 : C1;
    const int ldc  = colgrp ? ldc2 : ldc1;
    const int relu = colgrp ? relu1 : relu0;
    #pragma unroll
    for (int c = 0; c < 4; ++c) {
        int lc = ((w & 3) * 4 + c) * 16 + m16;
        float bv = (ba ? ba[lc] : 0.f) + (bb ? bb[lc] : 0.f);
        #pragma unroll
        for (int r = 0; r < 4; ++r)
            #pragma unroll
            for (int i = 0; i < 4; ++i) {
                int grow = rowBase + r * 16 + q * 4 + i;
                if (grow < M) {
                    float v = acc[r * 4 + c][i] + bv;
                    if (relu) v = fmaxf(v, 0.f);
                    C[(size_t)grow * ldc + lc] = f2b(v);
                }
            }
    }
}

// ---------------------------------------------------------------------------
// fused 3-layer MLP [256->256] relu + classifier + softmax. Block owns 64
// rows in a frag-major LDS panel; 4 waves each own 64 rows x 64 cols.
// B read directly per-wave from L2 (no LDS, no intra-layer barriers —
// only 2 barriers per layer boundary for the panel writeback).
// Final layer stays in the panel; fc 256->5 + softmax computed from it,
// writing only `out` (saves the H write + re-read and a kernel launch).
// ---------------------------------------------------------------------------
__global__ __launch_bounds__(256)
void k_mlp3fc(const u16* __restrict__ WTHf,
              const float* Hb1, const float* Hb2, const float* Hb3,
              const float* __restrict__ fcw, const float* __restrict__ fcb,
              const u16* __restrict__ Hin, float* __restrict__ out, int M)
{
    __shared__ u16 P[64 * 256];     // frag-major activation panel (32 KB)

    const int tid = threadIdx.x;
    const int w = tid >> 6, lane = tid & 63;
    const int m16 = lane & 15, q = lane >> 4;
    const int rowBase = blockIdx.x * 64;

    // load panel (global row-major -> fragment-major)
    #pragma unroll
    for (int p = 0; p < 8; ++p) {
        int ch = p * 256 + tid;          // 0..2047 16B-chunks
        int f = ch >> 6, l = ch & 63;    // frag f = kt*4+rf, lane-slot l
        int kt = f >> 2, rf = f & 3;
        int grow = rowBase + rf * 16 + (l & 15);
        if (grow >= M) grow = M - 1;
        int col = kt * 32 + (l >> 4) * 8;
        *(int4*)&P[ch * 8] = *(const int4*)(Hin + (size_t)grow * 256 + col);
    }
    __syncthreads();

    const float* biases[3] = {Hb1, Hb2, Hb3};
    for (int L = 0; L < 3; ++L) {
        const u16* WTf = WTHf + (size_t)L * 65536;
        float4v acc[16] = {};
        #pragma unroll 2
        for (int kt = 0; kt < 8; ++kt) {
            short8 a[4], b[4];
            #pragma unroll
            for (int c = 0; c < 4; ++c) {
                int4 bv = *(const int4*)(WTf + (size_t)(kt * 16 + w * 4 + c) * 512
                                         + lane * 8);
                b[c] = *(short8*)&bv;
            }
            #pragma unroll
            for (int r = 0; r < 4; ++r)
                a[r] = *(const short8*)&P[(kt * 4 + r) * 512 + lane * 8];
            #pragma unroll
            for (int r = 0; r < 4; ++r)
                #pragma unroll
                for (int c = 0; c < 4; ++c)
                    acc[r * 4 + c] = __builtin_amdgcn_mfma_f32_16x16x32_bf16(
                        a[r], b[c], acc[r * 4 + c], 0, 0, 0);
        }
        const float* bias = biases[L];
        __syncthreads();    // all panel reads done before overwrite
        // writeback into fragment-major panel (out col -> next-layer k)
        #pragma unroll
        for (int c = 0; c < 4; ++c) {
            int col = w * 64 + c * 16 + m16;
            float bv = bias[col];
            int kt2 = col >> 5;
            int l2h = 16 * ((col & 31) >> 3);
            int j2 = col & 7;
            #pragma unroll
            for (int r = 0; r < 4; ++r)
                #pragma unroll
                for (int i = 0; i < 4; ++i) {
                    int l2 = (q * 4 + i) + l2h;
                    P[(size_t)(kt2 * 4 + r) * 512 + l2 * 8 + j2] =
                        f2b(fmaxf(acc[r * 4 + c][i] + bv, 0.f));
                }
        }
        __syncthreads();
    }

    // classifier + softmax from the panel.
    // wave w reads frags rf=w: row = rowBase + w*16 + m16, cols kt*32 + q*8 + j
    float p5[5] = {0.f, 0.f, 0.f, 0.f, 0.f};
    #pragma unroll
    for (int kt = 0; kt < 8; ++kt) {
        u16x8 v = *(const u16x8*)&P[(kt * 4 + w) * 512 + lane * 8];
        int colb = kt * 32 + q * 8;
        #pragma unroll
        for (int j = 0; j < 8; ++j) {
            float hv = b2f(v[j]);
            const float* wr = fcw + (size_t)(colb + j) * 5;
            #pragma unroll
            for (int c = 0; c < 5; ++c) p5[c] += hv * wr[c];
        }
    }
    #pragma unroll
    for (int c = 0; c < 5; ++c) {
        p5[c] += __shfl_xor(p5[c], 16, 64);
        p5[c] += __shfl_xor(p5[c], 32, 64);
    }
    int grow = rowBase + w * 16 + m16;
    if (q == 0 && grow < M) {
        float mx = -1e30f;
        #pragma unroll
        for (int c = 0; c < 5; ++c) { p5[c] += fcb[c]; mx = fmaxf(mx, p5[c]); }
        float s = 0.f, e[5];
        #pragma unroll
        for (int c = 0; c < 5; ++c) { e[c] = __expf(p5[c] - mx); s += e[c]; }
        float inv = 1.f / s;
        #pragma unroll
        for (int c = 0; c < 5; ++c) out[(size_t)grow * 5 + c] = e[c] * inv;
    }
}

// ---------------------------------------------------------------------------
extern "C" void kernel_launch(void* const* d_in, const int* in_sizes, int n_in,
                              void* d_out, int out_size, void* d_ws, size_t ws_size,
                              hipStream_t stream)
{
    const float* x    = (const float*)d_in[0];
    const int*   ei   = (const int*)  d_in[1];
    const float* W1   = (const float*)d_in[2];
    const float* as1  = (const float*)d_in[3];
    const float* ad1  = (const float*)d_in[4];
    const float* bc1  = (const float*)d_in[5];
    const float* A1w  = (const float*)d_in[6];
    const float* b1   = (const float*)d_in[7];
    const float* W2   = (const float*)d_in[8];
    const float* as2  = (const float*)d_in[9];
    const float* ad2  = (const float*)d_in[10];
    const float* bc2  = (const float*)d_in[11];
    const float* A2w  = (const float*)d_in[12];
    const float* b2   = (const float*)d_in[13];
    const float* Hw1  = (const float*)d_in[14];
    const float* Hb1  = (const float*)d_in[15];
    const float* Hw2  = (const float*)d_in[16];
    const float* Hb2  = (const float*)d_in[17];
    const float* Hw3  = (const float*)d_in[18];
    const float* Hb3  = (const float*)d_in[19];
    const float* fcw  = (const float*)d_in[20];
    const float* fcb  = (const float*)d_in[21];
    float* out = (float*)d_out;

    const int D = 256;
    const int N = in_sizes[0] / D;
    const int E = in_sizes[1] / 2;

    char* w = (char*)d_ws;
    auto alloc = [&](size_t bytes) {
        char* p = w;
        w += (bytes + 255) & ~(size_t)255;
        return p;
    };
    int*   flag   = (int*)  alloc(256);
    int*   flag64 = (int*)  alloc(256);
    float* a_s    = (float*)alloc((size_t)N * 4);
    float* a_d    = (float*)alloc((size_t)N * 4);
    float* vs1    = (float*)alloc(1024);                 // W1 @ att_src1  [256]
    float* vd1    = (float*)alloc(1024);                 // W1 @ att_dst1  [256]
    int*   deg    = (int*)  alloc((size_t)N * 4);
    int*   cursor = (int*)  alloc((size_t)N * 4);
    int*   offA   = (int*)  alloc((size_t)(N + 1) * 4);
    int*   part   = (int*)  alloc((size_t)((N + 1023) / 1024 + 1) * 4);
    int*   srcs   = (int*)  alloc((size_t)E * 4);
    float* alpha  = (float*)alloc((size_t)E * 4);        // normalized edge weights
    u16*   WT1    = (u16*)  alloc(512 * 512 * 2);        // frag-major [A1w;W1]
    u16*   WT2    = (u16*)  alloc(512 * 512 * 2);        // frag-major [W2|A2w]
    u16*   WTH    = (u16*)  alloc(3 * 256 * 256 * 2);    // frag-major MLP weights
    u16*   BUF1   = (u16*)  alloc((size_t)N * 512 * 2);  // xb|aggx -> h2|res2
    u16*   BUF2   = (u16*)  alloc((size_t)N * 512 * 2);  // hl1 -> out2

    // src32/dst32 alias BUF1 (dead before xb is written)
    int* src32 = (int*)BUF1;
    int* dst32 = src32 + E;

    size_t need = (size_t)(w - (char*)d_ws);             // ~112 MB
    if (ws_size < need) {
        float code = 1000.0f + (float)(ws_size >> 20);
        k_diag<<<(out_size + 255) / 256, 256, 0, stream>>>(out, out_size, code);
        return;
    }

    const int EB  = (E + 255) / 256;
    const int NB4 = (N + 3) / 4;
    const int OB  = (out_size + 255) / 256;
    const int NE  = (N > E ? N : E);
    const int RB64 = (N + 63) / 64;
    const int NBLK = (N + 1023) / 1024;
    const size_t NH2 = (size_t)N * 256;
    u16* XB   = BUF1;            // bf16 cast of x      [N,256]
    u16* AGGX = BUF1 + NH2;      // alpha-aggregated x  [N,256]

    hipMemsetAsync(flag, 0, 4, stream);
    hipMemsetAsync(deg, 0, (size_t)N * 4, stream);

    // ---- edge extraction (+degree count) + CSR by destination ----
    k_detect <<<1, 256, 0, stream>>>(ei, E, flag64);
    k_extract<<<EB, 256, 0, stream>>>(ei, E, flag64, src32, dst32, deg, N);
    k_scan_a <<<NBLK, 256, 0, stream>>>(deg, offA, part, N);
    k_scan_b <<<1, 1024, 0, stream>>>(part, NBLK);
    k_scan_c <<<(N + 255) / 256, 256, 0, stream>>>(offA, cursor, part, N, E);
    k_scatter<<<EB, 256, 0, stream>>>(src32, dst32, cursor, srcs, E, N);
    scan_csr <<<(NE + 255) / 256, 256, 0, stream>>>(offA, srcs, N, E, flag, 1);

    // ---- weight pre-pack (fragment-major bf16, single launch) ----
    k_packAll<<<dim3(32, 16, 5), 64, 0, stream>>>(A1w, W1, W2, A2w,
                                                  Hw1, Hw2, Hw3, WT1, WT2, WTH);

    // ---- attention vectors, then fused cast+dot over x ----
    k_rowdot2f<<<64, 256, 0, stream>>>(W1, 512, 512, as1, ad1, vs1, vd1, 256);
    k_castdot<<<(N + 7) / 8, 256, 0, stream>>>(x, vs1, vd1, XB, a_s, a_d, N);
    k_alpha<<<NB4, 256, 0, stream>>>(offA, srcs, a_s, a_d, alpha, N);

    // ---- aggx = sum_e alpha_e * xb[src_e]  (GAT linearity: agg before W1) ----
    k_aggw<<<NB4, 256, 0, stream>>>(XB, offA, srcs, alpha, nullptr, AGGX, N);

    // ---- layer 1 fused: hl1 = relu([XB|AGGX] @ [A1w;W1] + b1 + bc1) ----
    bigfull<<<RB64, 512, 0, stream>>>(XB, 256, AGGX, 256, WT1,
                                      b1, bc1, b1 + 256, bc1 + 256,
                                      BUF2, 512, BUF2 + 256, 512, N, 1, 1);

    // ---- layer 2 fused: [h2 | res2] = hl1 @ [W2 | A2w] (+b2+bc2 on res2) ----
    bigfull<<<RB64, 512, 0, stream>>>(BUF2, 512, BUF2 + 256, 512, WT2,
                                      nullptr, nullptr, b2, bc2,
                                      BUF1, 256, BUF1 + NH2, 256, N, 0, 0);

    k_rowdot2<<<NB4, 256, 0, stream>>>(BUF1, 256, 256, as2, ad2, a_s, a_d, N);
    k_alpha<<<NB4, 256, 0, stream>>>(offA, srcs, a_s, a_d, alpha, N);
    k_aggw<<<NB4, 256, 0, stream>>>(BUF1, offA, srcs, alpha, BUF1 + NH2, BUF2, N);

    // ---- fused 3-layer MLP + classifier + softmax (reads BUF2, writes out) ----
    k_mlp3fc<<<RB64, 256, 0, stream>>>(WTH, Hb1, Hb2, Hb3, fcw, fcb,
                                       BUF2, out, N);

    k_final_diag<<<OB, 256, 0, stream>>>(flag, out, out_size);
}

// Round 7
// 543.646 us; speedup vs baseline: 2.2257x; 1.0529x over previous
//
#include <hip/hip_runtime.h>

typedef unsigned short u16;
typedef short short8 __attribute__((ext_vector_type(8)));
typedef u16 u16x4 __attribute__((ext_vector_type(4)));
typedef u16 u16x8 __attribute__((ext_vector_type(8)));
typedef float float4v __attribute__((ext_vector_type(4)));

#define NEG_SLOPE 0.2f

static __device__ __forceinline__ float b2f(u16 u) {
    union { unsigned int i; float f; } x; x.i = ((unsigned int)u) << 16; return x.f;
}
static __device__ __forceinline__ u16 f2b(float f) {
    unsigned int u = __float_as_uint(f);
    unsigned int r = (u + 0x7fffu + ((u >> 16) & 1u)) >> 16;
    return (u16)r;
}

// ---------------------------------------------------------------------------
// diagnostics: code 32 = CSR inconsistent; 1000+ = ws too small
// ---------------------------------------------------------------------------
__global__ void k_diag(float* out, int n, float val)
{
    int i = blockIdx.x * 256 + threadIdx.x;
    if (i < n) out[i] = val;
}

__global__ void scan_csr(const int* off, const int* srcs, int N, int E,
                         int* flag, int bit)
{
    int i = blockIdx.x * 256 + threadIdx.x;
    if (i < N) {
        int a = off[i], b = off[i + 1];
        if (a < 0 || b < a || b > E) atomicOr(flag, bit);
    }
    if (i == 0 && off[N] != E) atomicOr(flag, bit);
    if (i < E) {
        if ((unsigned)srcs[i] >= (unsigned)N) atomicOr(flag, bit);
    }
}

__global__ void k_final_diag(const int* flag, float* out, int n)
{
    int f = *flag;
    if (f == 0) return;
    int b = __ffs(f) - 1;
    float val = 32.0f * (b + 1);
    int i = blockIdx.x * 256 + threadIdx.x;
    if (i < n) out[i] = val;
}

// ---------------------------------------------------------------------------
// edge_index dtype probe + canonical int32 extraction (+ degree count fused)
// ---------------------------------------------------------------------------
__global__ void k_detect(const int* ei, int E, int* flag64)
{
    __shared__ int zc;
    if (threadIdx.x == 0) zc = 0;
    __syncthreads();
    int idx = 1 + 2 * (int)threadIdx.x;
    int z = (idx < 2 * E && ei[idx] == 0) ? 1 : 0;
    atomicAdd(&zc, z);
    __syncthreads();
    if (threadIdx.x == 0) *flag64 = (zc >= 200) ? 1 : 0;
}

__global__ void k_extract(const int* ei, int E, const int* flag64,
                          int* src, int* dst, int* deg, int N)
{
    int e = blockIdx.x * 256 + threadIdx.x;
    if (e >= E) return;
    int s, d;
    if (*flag64) {
        s = ei[2 * e];
        d = ei[2 * E + 2 * e];
    } else {
        s = ei[e];
        d = ei[E + e];
    }
    src[e] = s; dst[e] = d;
    if ((unsigned)d < (unsigned)N) atomicAdd(&deg[d], 1);
}

// ---------------------------------------------------------------------------
// device-wide exclusive scan, 3-phase (1024 elems per block in phase A)
// ---------------------------------------------------------------------------
__global__ __launch_bounds__(256)
void k_scan_a(const int* __restrict__ deg, int* __restrict__ off,
              int* __restrict__ partial, int N)
{
    __shared__ int sd[256];
    int tid = threadIdx.x;
    int base = blockIdx.x * 1024;
    int i0 = base + tid * 4;
    int v0 = 0, v1 = 0, v2 = 0, v3 = 0;
    if (i0 < N)     v0 = deg[i0];
    if (i0 + 1 < N) v1 = deg[i0 + 1];
    if (i0 + 2 < N) v2 = deg[i0 + 2];
    if (i0 + 3 < N) v3 = deg[i0 + 3];
    int t = v0 + v1 + v2 + v3;
    sd[tid] = t;
    __syncthreads();
    #pragma unroll
    for (int s = 1; s < 256; s <<= 1) {
        int u = (tid >= s) ? sd[tid - s] : 0;
        __syncthreads();
        sd[tid] += u;
        __syncthreads();
    }
    int excl = sd[tid] - t;                 // exclusive within block
    if (i0 < N)     off[i0]     = excl;
    if (i0 + 1 < N) off[i0 + 1] = excl + v0;
    if (i0 + 2 < N) off[i0 + 2] = excl + v0 + v1;
    if (i0 + 3 < N) off[i0 + 3] = excl + v0 + v1 + v2;
    if (tid == 255) partial[blockIdx.x] = sd[255];
}

__global__ __launch_bounds__(1024)
void k_scan_b(int* partial, int nblk)
{
    __shared__ int sd[1024];
    __shared__ int running;
    int tid = threadIdx.x;
    if (tid == 0) running = 0;
    __syncthreads();
    for (int base = 0; base < nblk; base += 1024) {
        int i = base + tid;
        int v = (i < nblk) ? partial[i] : 0;
        sd[tid] = v;
        __syncthreads();
        for (int s = 1; s < 1024; s <<= 1) {
            int u = (tid >= s) ? sd[tid - s] : 0;
            __syncthreads();
            sd[tid] += u;
            __syncthreads();
        }
        if (i < nblk) partial[i] = sd[tid] - v + running;   // exclusive
        int total = sd[1023];
        __syncthreads();
        if (tid == 0) running += total;
        __syncthreads();
    }
}

__global__ __launch_bounds__(256)
void k_scan_c(int* __restrict__ off, int* __restrict__ cursor,
              const int* __restrict__ partial, int N, int E)
{
    int i = blockIdx.x * 256 + threadIdx.x;
    if (i < N) {
        int v = off[i] + partial[i >> 10];
        off[i] = v;
        cursor[i] = v;
    }
    if (i == 0) off[N] = E;
}

__global__ void k_scatter(const int* src, const int* dst, int* cursor,
                          int* srcs, int E, int N)
{
    int e = blockIdx.x * 256 + threadIdx.x;
    if (e < E) {
        int d = dst[e];
        if ((unsigned)d < (unsigned)N) {
            int p = atomicAdd(&cursor[d], 1);
            if ((unsigned)p < (unsigned)E) srcs[p] = src[e];
        }
    }
}

// ---------------------------------------------------------------------------
// fused fp32->bf16 cast + row dots vs (vs,vd): 8 rows/block, 32 lanes/row.
// ---------------------------------------------------------------------------
__global__ __launch_bounds__(256)
void k_castdot(const float* __restrict__ x, const float* __restrict__ vs,
               const float* __restrict__ vd, u16* __restrict__ xb,
               float* __restrict__ a_s, float* __restrict__ a_d, int N)
{
    int tid = threadIdx.x;
    int rowb = tid >> 5;                // 0..7
    int col8 = (tid & 31) * 8;
    int n = blockIdx.x * 8 + rowb;
    if (n >= N) return;
    const float* xr = x + (size_t)n * 256 + col8;
    float4 v0 = *(const float4*)xr;
    float4 v1 = *(const float4*)(xr + 4);
    int4 w;
    w.x = (int)f2b(v0.x) | ((int)f2b(v0.y) << 16);
    w.y = (int)f2b(v0.z) | ((int)f2b(v0.w) << 16);
    w.z = (int)f2b(v1.x) | ((int)f2b(v1.y) << 16);
    w.w = (int)f2b(v1.z) | ((int)f2b(v1.w) << 16);
    *(int4*)(xb + (size_t)n * 256 + col8) = w;

    float4 s0 = *(const float4*)(vs + col8);
    float4 s1 = *(const float4*)(vs + col8 + 4);
    float4 d0 = *(const float4*)(vd + col8);
    float4 d1 = *(const float4*)(vd + col8 + 4);
    float ss = v0.x*s0.x + v0.y*s0.y + v0.z*s0.z + v0.w*s0.w
             + v1.x*s1.x + v1.y*s1.y + v1.z*s1.z + v1.w*s1.w;
    float sd = v0.x*d0.x + v0.y*d0.y + v0.z*d0.z + v0.w*d0.w
             + v1.x*d1.x + v1.y*d1.y + v1.z*d1.z + v1.w*d1.w;
    #pragma unroll
    for (int m = 16; m; m >>= 1) {
        ss += __shfl_xor(ss, m, 64);
        sd += __shfl_xor(sd, m, 64);
    }
    if ((tid & 31) == 0) { a_s[n] = ss; a_d[n] = sd; }
}

// ---------------------------------------------------------------------------
// fragment-major weight pack, all weights in one launch (blockIdx.z selects)
// out[(kt*NC16 + cf)*512 + l*8 + j] = bf16( W[kt*32+(l>>4)*8+j][cf*16+(l&15)] )
// ---------------------------------------------------------------------------
__global__ __launch_bounds__(64)
void k_packAll(const float* A1w, const float* W1, const float* W2, const float* A2w,
               const float* Hw1, const float* Hw2, const float* Hw3,
               u16* WT1, u16* WT2, u16* WTH)
{
    int z = blockIdx.z;
    const float *in1, *in2; int ksplit, csplit, in_ld, NC16; u16* out;
    if (z == 0)      { in1 = A1w; in2 = W1;  ksplit = 256; csplit = 0;   in_ld = 512; out = WT1; NC16 = 32; }
    else if (z == 1) { in1 = W2;  in2 = A2w; ksplit = 0;   csplit = 256; in_ld = 256; out = WT2; NC16 = 32; }
    else {
        if (blockIdx.x >= 16 || blockIdx.y >= 8) return;
        in1 = (z == 2) ? Hw1 : (z == 3) ? Hw2 : Hw3;
        in2 = nullptr; ksplit = 0; csplit = 0; in_ld = 256; NC16 = 16;
        out = WTH + (size_t)(z - 2) * 65536;
    }
    int l = threadIdx.x;
    int cf = blockIdx.x, kt = blockIdx.y;
    int col = cf * 16 + (l & 15);
    int kbase = kt * 32 + (l >> 4) * 8;
    const float* src = in1;
    int cc = col, koff = 0;
    if (ksplit > 0 && kbase >= ksplit) { src = in2; koff = ksplit; }
    if (csplit > 0 && col >= csplit)   { src = in2; cc = col - csplit; }
    u16* o = out + ((size_t)(kt * NC16 + cf) * 512) + l * 8;
    #pragma unroll
    for (int j = 0; j < 8; ++j)
        o[j] = f2b(src[(size_t)(kbase - koff + j) * in_ld + cc]);
}

// ---------------------------------------------------------------------------
// fp32 row-dot against two fp32 vectors — one wave per row, float4 lanes
// ---------------------------------------------------------------------------
__global__ __launch_bounds__(256)
void k_rowdot2f(const float* __restrict__ A, int ld, int H,
                const float* __restrict__ vs, const float* __restrict__ vd,
                float* a_s, float* a_d, int N)
{
    int wave = threadIdx.x >> 6, lane = threadIdx.x & 63;
    int n = blockIdx.x * 4 + wave;
    if (n >= N) return;
    const float* ar = A + (size_t)n * ld;
    float ss = 0.f, sd = 0.f;
    for (int i = lane * 4; i < H; i += 256) {
        float4 v  = *(const float4*)(ar + i);
        float4 s4 = *(const float4*)(vs + i);
        float4 d4 = *(const float4*)(vd + i);
        ss += v.x * s4.x + v.y * s4.y + v.z * s4.z + v.w * s4.w;
        sd += v.x * d4.x + v.y * d4.y + v.z * d4.z + v.w * d4.w;
    }
    #pragma unroll
    for (int m = 32; m; m >>= 1) {
        ss += __shfl_xor(ss, m, 64);
        sd += __shfl_xor(sd, m, 64);
    }
    if (lane == 0) { a_s[n] = ss; a_d[n] = sd; }
}

// ---------------------------------------------------------------------------
// per-dst softmax: exact online max/sum (1 pass) + alpha write (1 pass)
// ---------------------------------------------------------------------------
__global__ __launch_bounds__(256)
void k_alpha(const int* __restrict__ off, const int* __restrict__ srcs,
             const float* __restrict__ a_s, const float* __restrict__ a_d,
             float* __restrict__ alpha, int N)
{
    int wave = threadIdx.x >> 6, lane = threadIdx.x & 63;
    int n = blockIdx.x * 4 + wave;
    if (n >= N) return;
    int base = off[n], end = off[n + 1];
    float adn = a_d[n];
    float m = -1e30f, s = 0.f;
    for (int p = base + lane; p < end; p += 64) {
        int sx = srcs[p];
        sx = ((unsigned)sx < (unsigned)N) ? sx : 0;
        float z = a_s[sx] + adn;
        z = fmaxf(z, NEG_SLOPE * z);          // leaky_relu (slope<1)
        float mn = fmaxf(m, z);
        s = s * __expf(m - mn) + __expf(z - mn);
        m = mn;
    }
    #pragma unroll
    for (int msk = 32; msk; msk >>= 1) {
        float mo = __shfl_xor(m, msk, 64);
        float so = __shfl_xor(s, msk, 64);
        float mn = fmaxf(m, mo);
        s = s * __expf(m - mn) + so * __expf(mo - mn);
        m = mn;
    }
    float inv = 1.f / (s + 1e-16f);
    for (int p = base + lane; p < end; p += 64) {
        int sx = srcs[p];
        sx = ((unsigned)sx < (unsigned)N) ? sx : 0;
        float z = a_s[sx] + adn;
        z = fmaxf(z, NEG_SLOPE * z);
        alpha[p] = __expf(z - m) * inv;
    }
}

// ---------------------------------------------------------------------------
// weighted gather-aggregate, half-wave split: lanes 0-31 edge p, 32-63 edge
// p+1; 16B row loads; 4 edges in flight; one shfl(32) reduce per node.
// ---------------------------------------------------------------------------
__global__ __launch_bounds__(256)
void k_aggw(const u16* __restrict__ rows, const int* __restrict__ off,
            const int* __restrict__ srcs, const float* __restrict__ alpha,
            const u16* __restrict__ add, u16* __restrict__ out, int N)
{
    int wave = threadIdx.x >> 6, lane = threadIdx.x & 63;
    int n = blockIdx.x * 4 + wave;
    if (n >= N) return;
    int base = off[n], end = off[n + 1];
    int half = lane >> 5;
    int c8 = (lane & 31) * 8;
    float acc[8] = {};
    int p = base;
    for (; p + 3 < end; p += 4) {
        int sA = srcs[p + half];
        int sB = srcs[p + 2 + half];
        sA = ((unsigned)sA < (unsigned)N) ? sA : 0;
        sB = ((unsigned)sB < (unsigned)N) ? sB : 0;
        float wA = alpha[p + half];
        float wB = alpha[p + 2 + half];
        u16x8 vA = *(const u16x8*)(rows + (size_t)sA * 256 + c8);
        u16x8 vB = *(const u16x8*)(rows + (size_t)sB * 256 + c8);
        #pragma unroll
        for (int j = 0; j < 8; ++j)
            acc[j] += wA * b2f(vA[j]) + wB * b2f(vB[j]);
    }
    for (; p + 1 < end; p += 2) {
        int sA = srcs[p + half];
        sA = ((unsigned)sA < (unsigned)N) ? sA : 0;
        float wA = alpha[p + half];
        u16x8 vA = *(const u16x8*)(rows + (size_t)sA * 256 + c8);
        #pragma unroll
        for (int j = 0; j < 8; ++j)
            acc[j] += wA * b2f(vA[j]);
    }
    if (p < end) {
        int sA = srcs[p];
        sA = ((unsigned)sA < (unsigned)N) ? sA : 0;
        float wA = half ? 0.f : alpha[p];
        u16x8 vA = *(const u16x8*)(rows + (size_t)sA * 256 + c8);
        #pragma unroll
        for (int j = 0; j < 8; ++j)
            acc[j] += wA * b2f(vA[j]);
    }
    #pragma unroll
    for (int j = 0; j < 8; ++j)
        acc[j] += __shfl_xor(acc[j], 32, 64);
    if (half == 0) {
        size_t ob = (size_t)n * 256 + c8;
        if (add) {
            u16x8 ad8 = *(const u16x8*)(add + ob);
            #pragma unroll
            for (int j = 0; j < 8; ++j) acc[j] += b2f(ad8[j]);
        }
        u16x8 o;
        #pragma unroll
        for (int j = 0; j < 8; ++j) o[j] = f2b(acc[j]);
        *(u16x8*)(out + ob) = o;
    }
}

// ---------------------------------------------------------------------------
// full-width fused MFMA GEMM: BM=64, K=512 (two bf16 A halves of 256 each),
// NC=512, fragment-major WTf. B read DIRECTLY per-wave from L2 (no LDS for
// B). Only A is LDS-staged (cross-wave, 2 barriers/kt, 4 KB).
// Optional fused row-dots on the C1 half (bf16-rounded acc · dotS/dotD,
// atomicAdd into oaS/oaD) — used to produce layer-2 attention coefficients
// without a separate pass over h2.
// ---------------------------------------------------------------------------
__global__ __launch_bounds__(512)
void bigfull(const u16* __restrict__ A1, int lda1,
             const u16* __restrict__ A2, int lda2,
             const u16* __restrict__ WTf,
             const float* b0a, const float* b0b,
             const float* b1a, const float* b1b,
             u16* C1, int ldc1, u16* C2, int ldc2,
             const float* __restrict__ dotS, const float* __restrict__ dotD,
             float* oaS, float* oaD,
             int M, int relu0, int relu1)
{
    __shared__ u16 As[64 * 32];      // frag-major A K-slice (4 KB)

    const int tid = threadIdx.x;
    const int w = tid >> 6, lane = tid & 63;
    const int m16 = lane & 15, q = lane >> 4;
    const int rowBase = blockIdx.x * 64;

    float4v acc[16] = {};

    for (int k0 = 0; k0 < 512; k0 += 32) {
        const int kt = k0 >> 5;
        __syncthreads();
        if (tid < 256) {   // stage A 64x32 into fragment order
            int rf = tid >> 6, al = tid & 63;
            int grow = rowBase + rf * 16 + (al & 15);
            if (grow >= M) grow = M - 1;          // clamp; value unused
            int kk = k0 + (al >> 4) * 8;
            const u16* src = (kk < 256)
                ? A1 + (size_t)grow * lda1 + kk
                : A2 + (size_t)grow * lda2 + (kk - 256);
            *(int4*)&As[tid * 8] = *(const int4*)src;
        }
        __syncthreads();

        short8 a[4], b[4];
        #pragma unroll
        for (int c = 0; c < 4; ++c) {
            int4 bv = *(const int4*)(WTf + (size_t)kt * 16384
                                     + (size_t)(w * 4 + c) * 512 + lane * 8);
            b[c] = *(short8*)&bv;
        }
        #pragma unroll
        for (int r = 0; r < 4; ++r)
            a[r] = *(const short8*)&As[r * 512 + lane * 8];
        #pragma unroll
        for (int r = 0; r < 4; ++r)
            #pragma unroll
            for (int c = 0; c < 4; ++c)
                acc[r * 4 + c] = __builtin_amdgcn_mfma_f32_16x16x32_bf16(
                    a[r], b[c], acc[r * 4 + c], 0, 0, 0);
    }

    const int colgrp = w >> 2;
    const float* ba = colgrp ? b1a : b0a;
    const float* bb = colgrp ? b1b : b0b;
    u16* C  = colgrp ? C2 : C1;
    const int ldc  = colgrp ? ldc2 : ldc1;
    const int relu = colgrp ? relu1 : relu0;
    #pragma unroll
    for (int c = 0; c < 4; ++c) {
        int lc = ((w & 3) * 4 + c) * 16 + m16;
        float bv = (ba ? ba[lc] : 0.f) + (bb ? bb[lc] : 0.f);
        #pragma unroll
        for (int r = 0; r < 4; ++r)
            #pragma unroll
            for (int i = 0; i < 4; ++i) {
                int grow = rowBase + r * 16 + q * 4 + i;
                if (grow < M) {
                    float v = acc[r * 4 + c][i] + bv;
                    if (relu) v = fmaxf(v, 0.f);
                    C[(size_t)grow * ldc + lc] = f2b(v);
                }
            }
    }

    // fused attention row-dots on the C1 half (no bias / no relu path)
    if (dotS && colgrp == 0) {
        #pragma unroll
        for (int r = 0; r < 4; ++r)
            #pragma unroll
            for (int i = 0; i < 4; ++i) {
                float ss = 0.f, sd = 0.f;
                #pragma unroll
                for (int c = 0; c < 4; ++c) {
                    int lc = ((w & 3) * 4 + c) * 16 + m16;
                    float v = b2f(f2b(acc[r * 4 + c][i]));  // match stored bf16
                    ss += v * dotS[lc];
                    sd += v * dotD[lc];
                }
                #pragma unroll
                for (int msk = 1; msk < 16; msk <<= 1) {
                    ss += __shfl_xor(ss, msk, 64);
                    sd += __shfl_xor(sd, msk, 64);
                }
                int grow = rowBase + r * 16 + q * 4 + i;
                if (m16 == 0 && grow < M) {
                    atomicAdd(&oaS[grow], ss);
                    atomicAdd(&oaD[grow], sd);
                }
            }
    }
}

// ---------------------------------------------------------------------------
// fused 3-layer MLP [256->256] relu + classifier + softmax. 512 threads =
// 8 waves sharing a 64-row frag-major LDS panel (32 KB); each wave owns
// 64 rows x 32 cols (8 acc frags -> low VGPR -> high occupancy). B read
// directly per-wave from L2. Final layer stays in the panel; fc 256->5 +
// softmax computed from it (waves 0-3), writing only `out`.
// ---------------------------------------------------------------------------
__global__ __launch_bounds__(512)
void k_mlp3fc(const u16* __restrict__ WTHf,
              const float* Hb1, const float* Hb2, const float* Hb3,
              const float* __restrict__ fcw, const float* __restrict__ fcb,
              const u16* __restrict__ Hin, float* __restrict__ out, int M)
{
    __shared__ u16 P[64 * 256];     // frag-major activation panel (32 KB)

    const int tid = threadIdx.x;
    const int w = tid >> 6, lane = tid & 63;
    const int m16 = lane & 15, q = lane >> 4;
    const int rowBase = blockIdx.x * 64;

    // load panel (global row-major -> fragment-major), 4 chunks/thread
    #pragma unroll
    for (int p = 0; p < 4; ++p) {
        int ch = p * 512 + tid;          // 0..2047 16B-chunks
        int f = ch >> 6, l = ch & 63;    // frag f = kt*4+rf, lane-slot l
        int kt = f >> 2, rf = f & 3;
        int grow = rowBase + rf * 16 + (l & 15);
        if (grow >= M) grow = M - 1;
        int col = kt * 32 + (l >> 4) * 8;
        *(int4*)&P[ch * 8] = *(const int4*)(Hin + (size_t)grow * 256 + col);
    }
    __syncthreads();

    const float* biases[3] = {Hb1, Hb2, Hb3};
    for (int L = 0; L < 3; ++L) {
        const u16* WTf = WTHf + (size_t)L * 65536;
        float4v acc[8] = {};
        #pragma unroll 2
        for (int kt = 0; kt < 8; ++kt) {
            short8 a[4], b[2];
            #pragma unroll
            for (int c = 0; c < 2; ++c) {
                int4 bv = *(const int4*)(WTf + (size_t)(kt * 16 + w * 2 + c) * 512
                                         + lane * 8);
                b[c] = *(short8*)&bv;
            }
            #pragma unroll
            for (int r = 0; r < 4; ++r)
                a[r] = *(const short8*)&P[(kt * 4 + r) * 512 + lane * 8];
            #pragma unroll
            for (int r = 0; r < 4; ++r)
                #pragma unroll
                for (int c = 0; c < 2; ++c)
                    acc[r * 2 + c] = __builtin_amdgcn_mfma_f32_16x16x32_bf16(
                        a[r], b[c], acc[r * 2 + c], 0, 0, 0);
        }
        const float* bias = biases[L];
        __syncthreads();    // all panel reads done before overwrite
        // writeback into fragment-major panel (out col -> next-layer k)
        #pragma unroll
        for (int c = 0; c < 2; ++c) {
            int col = w * 32 + c * 16 + m16;
            float bv = bias[col];
            int kt2 = col >> 5;               // == w
            int l2h = 16 * ((col & 31) >> 3);
            int j2 = col & 7;
            #pragma unroll
            for (int r = 0; r < 4; ++r)
                #pragma unroll
                for (int i = 0; i < 4; ++i) {
                    int l2 = (q * 4 + i) + l2h;
                    P[(size_t)(kt2 * 4 + r) * 512 + l2 * 8 + j2] =
                        f2b(fmaxf(acc[r * 2 + c][i] + bv, 0.f));
                }
        }
        __syncthreads();
    }

    // classifier + softmax from the panel (waves 0-3, rf = w).
    if (w < 4) {
        float p5[5] = {0.f, 0.f, 0.f, 0.f, 0.f};
        #pragma unroll
        for (int kt = 0; kt < 8; ++kt) {
            u16x8 v = *(const u16x8*)&P[(kt * 4 + w) * 512 + lane * 8];
            int colb = kt * 32 + q * 8;
            #pragma unroll
            for (int j = 0; j < 8; ++j) {
                float hv = b2f(v[j]);
                const float* wr = fcw + (size_t)(colb + j) * 5;
                #pragma unroll
                for (int c = 0; c < 5; ++c) p5[c] += hv * wr[c];
            }
        }
        #pragma unroll
        for (int c = 0; c < 5; ++c) {
            p5[c] += __shfl_xor(p5[c], 16, 64);
            p5[c] += __shfl_xor(p5[c], 32, 64);
        }
        int grow = rowBase + w * 16 + m16;
        if (q == 0 && grow < M) {
            float mx = -1e30f;
            #pragma unroll
            for (int c = 0; c < 5; ++c) { p5[c] += fcb[c]; mx = fmaxf(mx, p5[c]); }
            float s = 0.f, e[5];
            #pragma unroll
            for (int c = 0; c < 5; ++c) { e[c] = __expf(p5[c] - mx); s += e[c]; }
            float inv = 1.f / s;
            #pragma unroll
            for (int c = 0; c < 5; ++c) out[(size_t)grow * 5 + c] = e[c] * inv;
        }
    }
}

// ---------------------------------------------------------------------------
extern "C" void kernel_launch(void* const* d_in, const int* in_sizes, int n_in,
                              void* d_out, int out_size, void* d_ws, size_t ws_size,
                              hipStream_t stream)
{
    const float* x    = (const float*)d_in[0];
    const int*   ei   = (const int*)  d_in[1];
    const float* W1   = (const float*)d_in[2];
    const float* as1  = (const float*)d_in[3];
    const float* ad1  = (const float*)d_in[4];
    const float* bc1  = (const float*)d_in[5];
    const float* A1w  = (const float*)d_in[6];
    const float* b1   = (const float*)d_in[7];
    const float* W2   = (const float*)d_in[8];
    const float* as2  = (const float*)d_in[9];
    const float* ad2  = (const float*)d_in[10];
    const float* bc2  = (const float*)d_in[11];
    const float* A2w  = (const float*)d_in[12];
    const float* b2   = (const float*)d_in[13];
    const float* Hw1  = (const float*)d_in[14];
    const float* Hb1  = (const float*)d_in[15];
    const float* Hw2  = (const float*)d_in[16];
    const float* Hb2  = (const float*)d_in[17];
    const float* Hw3  = (const float*)d_in[18];
    const float* Hb3  = (const float*)d_in[19];
    const float* fcw  = (const float*)d_in[20];
    const float* fcb  = (const float*)d_in[21];
    float* out = (float*)d_out;

    const int D = 256;
    const int N = in_sizes[0] / D;
    const int E = in_sizes[1] / 2;

    char* w = (char*)d_ws;
    auto alloc = [&](size_t bytes) {
        char* p = w;
        w += (bytes + 255) & ~(size_t)255;
        return p;
    };
    int*   flag   = (int*)  alloc(256);
    int*   flag64 = (int*)  alloc(256);
    float* a_s    = (float*)alloc((size_t)N * 4);
    float* a_d    = (float*)alloc((size_t)N * 4);
    float* vs1    = (float*)alloc(1024);                 // W1 @ att_src1  [256]
    float* vd1    = (float*)alloc(1024);                 // W1 @ att_dst1  [256]
    int*   deg    = (int*)  alloc((size_t)N * 4);
    int*   cursor = (int*)  alloc((size_t)N * 4);
    int*   offA   = (int*)  alloc((size_t)(N + 1) * 4);
    int*   part   = (int*)  alloc((size_t)((N + 1023) / 1024 + 1) * 4);
    int*   srcs   = (int*)  alloc((size_t)E * 4);
    float* alpha  = (float*)alloc((size_t)E * 4);        // normalized edge weights
    u16*   WT1    = (u16*)  alloc(512 * 512 * 2);        // frag-major [A1w;W1]
    u16*   WT2    = (u16*)  alloc(512 * 512 * 2);        // frag-major [W2|A2w]
    u16*   WTH    = (u16*)  alloc(3 * 256 * 256 * 2);    // frag-major MLP weights
    u16*   BUF1   = (u16*)  alloc((size_t)N * 512 * 2);  // xb|aggx -> h2|res2
    u16*   BUF2   = (u16*)  alloc((size_t)N * 512 * 2);  // hl1 -> out2

    // src32/dst32 alias BUF1 (dead before xb is written)
    int* src32 = (int*)BUF1;
    int* dst32 = src32 + E;

    size_t need = (size_t)(w - (char*)d_ws);             // ~112 MB
    if (ws_size < need) {
        float code = 1000.0f + (float)(ws_size >> 20);
        k_diag<<<(out_size + 255) / 256, 256, 0, stream>>>(out, out_size, code);
        return;
    }

    const int EB  = (E + 255) / 256;
    const int NB4 = (N + 3) / 4;
    const int OB  = (out_size + 255) / 256;
    const int NE  = (N > E ? N : E);
    const int RB64 = (N + 63) / 64;
    const int NBLK = (N + 1023) / 1024;
    const size_t NH2 = (size_t)N * 256;
    u16* XB   = BUF1;            // bf16 cast of x      [N,256]
    u16* AGGX = BUF1 + NH2;      // alpha-aggregated x  [N,256]

    hipMemsetAsync(flag, 0, 4, stream);
    hipMemsetAsync(deg, 0, (size_t)N * 4, stream);

    // ---- edge extraction (+degree count) + CSR by destination ----
    k_detect <<<1, 256, 0, stream>>>(ei, E, flag64);
    k_extract<<<EB, 256, 0, stream>>>(ei, E, flag64, src32, dst32, deg, N);
    k_scan_a <<<NBLK, 256, 0, stream>>>(deg, offA, part, N);
    k_scan_b <<<1, 1024, 0, stream>>>(part, NBLK);
    k_scan_c <<<(N + 255) / 256, 256, 0, stream>>>(offA, cursor, part, N, E);
    k_scatter<<<EB, 256, 0, stream>>>(src32, dst32, cursor, srcs, E, N);
    scan_csr <<<(NE + 255) / 256, 256, 0, stream>>>(offA, srcs, N, E, flag, 1);

    // ---- weight pre-pack (fragment-major bf16, single launch) ----
    k_packAll<<<dim3(32, 16, 5), 64, 0, stream>>>(A1w, W1, W2, A2w,
                                                  Hw1, Hw2, Hw3, WT1, WT2, WTH);

    // ---- attention vectors, then fused cast+dot over x ----
    k_rowdot2f<<<64, 256, 0, stream>>>(W1, 512, 512, as1, ad1, vs1, vd1, 256);
    k_castdot<<<(N + 7) / 8, 256, 0, stream>>>(x, vs1, vd1, XB, a_s, a_d, N);
    k_alpha<<<NB4, 256, 0, stream>>>(offA, srcs, a_s, a_d, alpha, N);

    // a_s/a_d consumed by k_alpha above; zero them for bigfull-2's fused
    // atomic row-dot accumulation (stream order guarantees safety)
    hipMemsetAsync(a_s, 0, (size_t)N * 4, stream);
    hipMemsetAsync(a_d, 0, (size_t)N * 4, stream);

    // ---- aggx = sum_e alpha_e * xb[src_e]  (GAT linearity: agg before W1) ----
    k_aggw<<<NB4, 256, 0, stream>>>(XB, offA, srcs, alpha, nullptr, AGGX, N);

    // ---- layer 1 fused: hl1 = relu([XB|AGGX] @ [A1w;W1] + b1 + bc1) ----
    bigfull<<<RB64, 512, 0, stream>>>(XB, 256, AGGX, 256, WT1,
                                      b1, bc1, b1 + 256, bc1 + 256,
                                      BUF2, 512, BUF2 + 256, 512,
                                      nullptr, nullptr, nullptr, nullptr,
                                      N, 1, 1);

    // ---- layer 2 fused: [h2 | res2] = hl1 @ [W2 | A2w] (+b2+bc2 on res2),
    //      with a_s2/a_d2 = h2·att2 accumulated in the epilogue ----
    bigfull<<<RB64, 512, 0, stream>>>(BUF2, 512, BUF2 + 256, 512, WT2,
                                      nullptr, nullptr, b2, bc2,
                                      BUF1, 256, BUF1 + NH2, 256,
                                      as2, ad2, a_s, a_d,
                                      N, 0, 0);

    k_alpha<<<NB4, 256, 0, stream>>>(offA, srcs, a_s, a_d, alpha, N);
    k_aggw<<<NB4, 256, 0, stream>>>(BUF1, offA, srcs, alpha, BUF1 + NH2, BUF2, N);

    // ---- fused 3-layer MLP + classifier + softmax (reads BUF2, writes out) ----
    k_mlp3fc<<<RB64, 512, 0, stream>>>(WTH, Hb1, Hb2, Hb3, fcw, fcb,
                                       BUF2, out, N);

    k_final_diag<<<OB, 256, 0, stream>>>(flag, out, out_size);
}